// Round 1
// 2392.738 us; speedup vs baseline: 1.5267x; 1.5267x over previous
//
#include <hip/hip_runtime.h>
#include <math.h>

#define S_LEN   2048
#define HIDDEN  4096
#define N_HEADS 32
#define N_KV    8
#define HEAD_DIM 128
#define NCAND   1844      // S - RECENT
#define HEAVY_K 819
#define MASK_LEN 2049     // S + 1

typedef _Float16 f16;
using bf16x8 = __attribute__((ext_vector_type(8))) short;
using f32x4  = __attribute__((ext_vector_type(4))) float;
using f32x16 = __attribute__((ext_vector_type(16))) float;
using f16x8  = __attribute__((ext_vector_type(8))) _Float16;
using f16x4  = __attribute__((ext_vector_type(4))) _Float16;
using f16x2  = __attribute__((ext_vector_type(2))) _Float16;
using uint4v = __attribute__((ext_vector_type(4))) unsigned int;

// exp(s*SCALE) == exp2(s*C2); single fused constant, used identically in all
// three attention passes so L, w, cs stay mutually consistent.
#define C2EXP 0.12751879523486166f   // (1/sqrt(128)) * log2(e)

__device__ inline unsigned short f2bf(float x) {
  unsigned u = __builtin_bit_cast(unsigned, x);
  unsigned r = (u + 0x7FFFu + ((u >> 16) & 1u)) >> 16;
  return (unsigned short)r;
}

// ---------------------------------------------------------------------------
// f32 GEMM, 128x64 tile, BK=32, 8x4 micro-tile.  Mask-critical (Wq/Wk).
// (unchanged from best-known version)
// ---------------------------------------------------------------------------
__global__ __launch_bounds__(256) void gemm_f32_128x64(
    const float* __restrict__ A, const float* __restrict__ B,
    float* __restrict__ C, int M, int N, int K)
{
  __shared__ float As[32][132];
  __shared__ float Bs[32][68];
  const int t  = threadIdx.x;
  const int tx = t & 15;
  const int ty = t >> 4;
  const int bm = blockIdx.y << 7;
  const int bn = blockIdx.x << 6;
  const int am  = t >> 3;
  const int ac4 = t & 7;
  const int br = t >> 4;
  const int bc = t & 15;
  const float4* A4 = (const float4*)A;
  const float4* B4 = (const float4*)B;
  const int K4 = K >> 2;
  const int N4 = N >> 2;

  float acc[8][4];
#pragma unroll
  for (int i = 0; i < 8; i++)
#pragma unroll
    for (int j = 0; j < 4; j++) acc[i][j] = 0.f;

  for (int k0 = 0; k0 < K; k0 += 32) {
    float4 areg[4];
#pragma unroll
    for (int p = 0; p < 4; p++)
      areg[p] = A4[(size_t)(bm + am + p * 32) * K4 + (k0 >> 2) + ac4];
    float4 b0 = B4[(size_t)(k0 + br)      * N4 + (bn >> 2) + bc];
    float4 b1 = B4[(size_t)(k0 + br + 16) * N4 + (bn >> 2) + bc];
    __syncthreads();
#pragma unroll
    for (int p = 0; p < 4; p++) {
      int m = am + p * 32;
      As[ac4 * 4 + 0][m] = areg[p].x;
      As[ac4 * 4 + 1][m] = areg[p].y;
      As[ac4 * 4 + 2][m] = areg[p].z;
      As[ac4 * 4 + 3][m] = areg[p].w;
    }
    *(float4*)&Bs[br][bc * 4]      = b0;
    *(float4*)&Bs[br + 16][bc * 4] = b1;
    __syncthreads();
#pragma unroll
    for (int kk = 0; kk < 32; kk++) {
      float4 a0 = *(const float4*)&As[kk][ty * 8];
      float4 a1 = *(const float4*)&As[kk][ty * 8 + 4];
      float4 bv4 = *(const float4*)&Bs[kk][tx * 4];
      float av[8] = {a0.x, a0.y, a0.z, a0.w, a1.x, a1.y, a1.z, a1.w};
      float bv[4] = {bv4.x, bv4.y, bv4.z, bv4.w};
#pragma unroll
      for (int i = 0; i < 8; i++)
#pragma unroll
        for (int j = 0; j < 4; j++) acc[i][j] += av[i] * bv[j];
    }
  }

#pragma unroll
  for (int i = 0; i < 8; i++) {
    float4 o;
    o.x = acc[i][0]; o.y = acc[i][1]; o.z = acc[i][2]; o.w = acc[i][3];
    *(float4*)&C[(size_t)(bm + ty * 8 + i) * N + bn + tx * 4] = o;
  }
}

// ---------------------------------------------------------------------------
// bf16 MFMA GEMM (unchanged): C(f32)[M,N] = A(bf16)[M,K] * BT(bf16)[N,K]^T.
// ---------------------------------------------------------------------------
__global__ __launch_bounds__(256) void gemm_bf16(
    const unsigned short* __restrict__ A, const unsigned short* __restrict__ BT,
    float* __restrict__ C, int M, int N, int K)
{
  __shared__ unsigned short As[64 * 40];
  __shared__ unsigned short Bs[64 * 40];
  const int t    = threadIdx.x;
  const int lane = t & 63;
  const int wave = t >> 6;
  const int mbase = (wave >> 1) * 32;
  const int nbase = (wave & 1) * 32;
  const int bm = blockIdx.y << 6;
  const int bn = blockIdx.x << 6;
  const int srow = t >> 2;
  const int scol = (t & 3) * 8;
  const int l16 = lane & 15;
  const int lk  = (lane >> 4) * 8;

  f32x4 acc00 = {0.f,0.f,0.f,0.f}, acc01 = {0.f,0.f,0.f,0.f};
  f32x4 acc10 = {0.f,0.f,0.f,0.f}, acc11 = {0.f,0.f,0.f,0.f};

  for (int k0 = 0; k0 < K; k0 += 32) {
    float4 av = *(const float4*)(A  + (size_t)(bm + srow) * K + k0 + scol);
    float4 bv = *(const float4*)(BT + (size_t)(bn + srow) * K + k0 + scol);
    __syncthreads();
    *(float4*)(As + srow * 40 + scol) = av;
    *(float4*)(Bs + srow * 40 + scol) = bv;
    __syncthreads();
    bf16x8 a0 = *(const bf16x8*)(As + (mbase + l16)      * 40 + lk);
    bf16x8 a1 = *(const bf16x8*)(As + (mbase + 16 + l16) * 40 + lk);
    bf16x8 b0 = *(const bf16x8*)(Bs + (nbase + l16)      * 40 + lk);
    bf16x8 b1 = *(const bf16x8*)(Bs + (nbase + 16 + l16) * 40 + lk);
    acc00 = __builtin_amdgcn_mfma_f32_16x16x32_bf16(a0, b0, acc00, 0, 0, 0);
    acc01 = __builtin_amdgcn_mfma_f32_16x16x32_bf16(a0, b1, acc01, 0, 0, 0);
    acc10 = __builtin_amdgcn_mfma_f32_16x16x32_bf16(a1, b0, acc10, 0, 0, 0);
    acc11 = __builtin_amdgcn_mfma_f32_16x16x32_bf16(a1, b1, acc11, 0, 0, 0);
  }

  const int rr = (lane >> 4) * 4;
#pragma unroll
  for (int r = 0; r < 4; r++) {
    C[(size_t)(bm + mbase +      rr + r) * N + bn + nbase +      l16] = acc00[r];
    C[(size_t)(bm + mbase +      rr + r) * N + bn + nbase + 16 + l16] = acc01[r];
    C[(size_t)(bm + mbase + 16 + rr + r) * N + bn + nbase +      l16] = acc10[r];
    C[(size_t)(bm + mbase + 16 + rr + r) * N + bn + nbase + 16 + l16] = acc11[r];
  }
}

// ---------------------------------------------------------------------------
// f32 -> bf16 row-major convert.
// ---------------------------------------------------------------------------
__global__ __launch_bounds__(256) void conv_rm(
    const float* __restrict__ src, unsigned short* __restrict__ dst, int n4)
{
  int i = blockIdx.x * 256 + threadIdx.x;
  if (i >= n4) return;
  float4 v = ((const float4*)src)[i];
  ushort4 o;
  o.x = f2bf(v.x); o.y = f2bf(v.y); o.z = f2bf(v.z); o.w = f2bf(v.w);
  ((ushort4*)dst)[i] = o;
}

// ---------------------------------------------------------------------------
// f32 [K][N] -> bf16 [N][K] transpose-convert, 32x32 tiles through LDS.
// ---------------------------------------------------------------------------
__global__ __launch_bounds__(256) void conv_T(
    const float* __restrict__ src, unsigned short* __restrict__ dst,
    int K, int N)
{
  __shared__ float tile[32][33];
  const int tj = blockIdx.x;
  const int ti = blockIdx.y;
  const int t = threadIdx.x;
  for (int idx = t; idx < 1024; idx += 256) {
    int r = idx >> 5, c = idx & 31;
    tile[r][c] = src[(size_t)(ti * 32 + r) * N + tj * 32 + c];
  }
  __syncthreads();
  for (int idx = t; idx < 1024; idx += 256) {
    int r = idx >> 5, c = idx & 31;
    dst[(size_t)(tj * 32 + r) * K + ti * 32 + c] = f2bf(tile[c][r]);
  }
}

// ---------------------------------------------------------------------------
// f32 [K][N] -> f16 [N][K] transpose-convert (for V^T).
// ---------------------------------------------------------------------------
__global__ __launch_bounds__(256) void conv_T_f16(
    const float* __restrict__ src, f16* __restrict__ dst, int K, int N)
{
  __shared__ float tile[32][33];
  const int tj = blockIdx.x;
  const int ti = blockIdx.y;
  const int t = threadIdx.x;
  for (int idx = t; idx < 1024; idx += 256) {
    int r = idx >> 5, c = idx & 31;
    tile[r][c] = src[(size_t)(ti * 32 + r) * N + tj * 32 + c];
  }
  __syncthreads();
  for (int idx = t; idx < 1024; idx += 256) {
    int r = idx >> 5, c = idx & 31;
    dst[(size_t)(tj * 32 + r) * K + ti * 32 + c] = (f16)tile[c][r];
  }
}

// ---------------------------------------------------------------------------
// f32 -> (f16 hi, f16 lo) split.  hi = rne(x); lo = rne(x - hi).
// x ~= hi + lo with residual <= 2^-22*|x|  ->  QK^T via 3 f16 MFMAs carries
// f32-equivalent precision (mask-critical path).
// ---------------------------------------------------------------------------
__global__ __launch_bounds__(256) void split_f16(
    const float* __restrict__ src, f16* __restrict__ hi, f16* __restrict__ lo,
    int n4)
{
  int i = blockIdx.x * 256 + threadIdx.x;
  if (i >= n4) return;
  float4 v = ((const float4*)src)[i];
  float vv[4] = {v.x, v.y, v.z, v.w};
  f16x4 h, l;
#pragma unroll
  for (int j = 0; j < 4; j++) {
    f16 hh = (f16)vv[j];
    h[j] = hh;
    l[j] = (f16)(vv[j] - (float)hh);
  }
  ((f16x4*)hi)[i] = h;
  ((f16x4*)lo)[i] = l;
}

// ---------------------------------------------------------------------------
// Attention pass 1: softmax denominators L[q] via split-f16 32x32x16 MFMA.
// Swapped operands: acc = mfma(A=K, B=Q) -> C[key][q], col(q)=lane&31,
// row(key)=(r&3)+8*(r>>2)+4*(lane>>5).  q is lane-resident, so L accumulates
// per-lane with zero cross-lane traffic until one final shfl_xor(32).
// Block = 4 waves x 32 q = 128 q-rows, one head.  K tiles (hi+lo) staged in
// LDS at stride 136 halfs (272B: 16B-aligned, bank-uniform -> conflict-free).
// ---------------------------------------------------------------------------
__global__ __launch_bounds__(256) void attn_l(
    const f16* __restrict__ Qh, const f16* __restrict__ Ql,
    const f16* __restrict__ Kh, const f16* __restrict__ Kl,
    float* __restrict__ Lrow)
{
  __shared__ __align__(16) f16 Khs[32 * 136];
  __shared__ __align__(16) f16 Kls[32 * 136];
  const int t    = threadIdx.x;
  const int lane = t & 63;
  const int wave = t >> 6;
  const int l31  = lane & 31;
  const int gp   = lane >> 5;
  const int h    = blockIdx.y;
  const int kvh  = h >> 2;
  const int q0   = (int)(gridDim.x - 1 - blockIdx.x) << 7;   // big blocks first
  const int qw   = q0 + wave * 32;
  const int qg   = qw + l31;

  // hoist Q fragments (hi+lo) for this wave's 32 q-rows
  f16x8 qhf[8], qlf[8];
  {
    const f16* qp  = Qh + (size_t)qg * HIDDEN + h * HEAD_DIM + 8 * gp;
    const f16* qp2 = Ql + (size_t)qg * HIDDEN + h * HEAD_DIM + 8 * gp;
#pragma unroll
    for (int c = 0; c < 8; c++) {
      qhf[c] = *(const f16x8*)(qp  + c * 16);
      qlf[c] = *(const f16x8*)(qp2 + c * 16);
    }
  }

  float Lacc = 0.f;
  const int ntiles = (q0 >> 5) + 4;
  for (int kt = 0; kt < ntiles; kt++) {
    const int k0 = kt << 5;
    __syncthreads();
    for (int i = t; i < 512; i += 256) {
      int r = i >> 4, c = i & 15;
      size_t g = (size_t)(k0 + r) * (N_KV * HEAD_DIM) + kvh * HEAD_DIM + c * 8;
      *(f16x8*)(Khs + r * 136 + c * 8) = *(const f16x8*)(Kh + g);
      *(f16x8*)(Kls + r * 136 + c * 8) = *(const f16x8*)(Kl + g);
    }
    __syncthreads();
    if (k0 > qw + 31) continue;   // after both barriers: barrier counts uniform

    f32x16 acc;
#pragma unroll
    for (int i = 0; i < 16; i++) acc[i] = 0.f;
#pragma unroll
    for (int c = 0; c < 8; c++) {
      f16x8 ah = *(const f16x8*)(Khs + l31 * 136 + c * 16 + 8 * gp);
      f16x8 al = *(const f16x8*)(Kls + l31 * 136 + c * 16 + 8 * gp);
      acc = __builtin_amdgcn_mfma_f32_32x32x16_f16(ah, qhf[c], acc, 0, 0, 0);
      acc = __builtin_amdgcn_mfma_f32_32x32x16_f16(ah, qlf[c], acc, 0, 0, 0);
      acc = __builtin_amdgcn_mfma_f32_32x32x16_f16(al, qhf[c], acc, 0, 0, 0);
    }
    float ws = 0.f;
#pragma unroll
    for (int r = 0; r < 16; r++) {
      int kg = k0 + (r & 3) + 8 * (r >> 2) + 4 * gp;
      float e = exp2f(acc[r] * C2EXP);
      ws += (kg <= qg) ? e : 0.f;
    }
    Lacc += ws;
  }

  float tot = Lacc + __shfl_xor(Lacc, 32);
  if (lane < 32) Lrow[h * S_LEN + qw + lane] = tot;
}

// ---------------------------------------------------------------------------
// Attention pass 2: O = softmax(QK^T) V via MFMA.  Output-tolerance path:
// plain-f16 QK^T (8 mfma), P packed to f16 (cvt_pkrtz) and redistributed into
// the PV B-fragment with 8 shfl_xor(32) -- the 32x32 C-layout's two lane
// halves hold exactly complementary key quadruples, so no LDS round-trip.
// PV: oacc[d][q] += mfma(A=Vt, B=P).  Vt fragments straight from global (L2).
// ---------------------------------------------------------------------------
__global__ __launch_bounds__(256) void attn_o(
    const f16* __restrict__ Qh, const f16* __restrict__ Kh,
    const f16* __restrict__ Vt, const float* __restrict__ Lrow,
    unsigned short* __restrict__ attnb)
{
  __shared__ __align__(16) f16 Khs[32 * 136];
  const int t    = threadIdx.x;
  const int lane = t & 63;
  const int wave = t >> 6;
  const int l31  = lane & 31;
  const int gp   = lane >> 5;
  const int h    = blockIdx.y;
  const int kvh  = h >> 2;
  const int q0   = (int)(gridDim.x - 1 - blockIdx.x) << 7;
  const int qw   = q0 + wave * 32;
  const int qg   = qw + l31;

  f16x8 qhf[8];
  {
    const f16* qp = Qh + (size_t)qg * HIDDEN + h * HEAD_DIM + 8 * gp;
#pragma unroll
    for (int c = 0; c < 8; c++) qhf[c] = *(const f16x8*)(qp + c * 16);
  }
  const float iL = 1.0f / Lrow[h * S_LEN + qg];

  f32x16 oacc[4];
#pragma unroll
  for (int m = 0; m < 4; m++)
#pragma unroll
    for (int i = 0; i < 16; i++) oacc[m][i] = 0.f;

  const int ntiles = (q0 >> 5) + 4;
  for (int kt = 0; kt < ntiles; kt++) {
    const int k0 = kt << 5;
    __syncthreads();
    for (int i = t; i < 512; i += 256) {
      int r = i >> 4, c = i & 15;
      size_t g = (size_t)(k0 + r) * (N_KV * HEAD_DIM) + kvh * HEAD_DIM + c * 8;
      *(f16x8*)(Khs + r * 136 + c * 8) = *(const f16x8*)(Kh + g);
    }
    __syncthreads();
    if (k0 > qw + 31) continue;

    f32x16 acc;
#pragma unroll
    for (int i = 0; i < 16; i++) acc[i] = 0.f;
#pragma unroll
    for (int c = 0; c < 8; c++) {
      f16x8 ah = *(const f16x8*)(Khs + l31 * 136 + c * 16 + 8 * gp);
      acc = __builtin_amdgcn_mfma_f32_32x32x16_f16(ah, qhf[c], acc, 0, 0, 0);
    }

    float wv[16];
#pragma unroll
    for (int r = 0; r < 16; r++) {
      int kg = k0 + (r & 3) + 8 * (r >> 2) + 4 * gp;
      wv[r] = (kg <= qg) ? exp2f(acc[r] * C2EXP) * iL : 0.f;
    }

    // pack pairs -> f16x2; lane l holds keys {4gp..}+{8..}+{16..}+{24..}
    unsigned p[8], x[8];
#pragma unroll
    for (int j = 0; j < 8; j++)
      p[j] = __builtin_bit_cast(unsigned,
               __builtin_amdgcn_cvt_pkrtz(wv[2 * j], wv[2 * j + 1]));
#pragma unroll
    for (int j = 0; j < 8; j++)
      x[j] = (unsigned)__shfl_xor((int)p[j], 32);

    uint4v cc0, cc1;   // B-frag: row(q)=lane&31, k = gp*8 + j
    cc0[0] = gp ? x[2] : p[0]; cc0[1] = gp ? x[3] : p[1];
    cc0[2] = gp ? p[2] : x[0]; cc0[3] = gp ? p[3] : x[1];
    cc1[0] = gp ? x[6] : p[4]; cc1[1] = gp ? x[7] : p[5];
    cc1[2] = gp ? p[6] : x[4]; cc1[3] = gp ? p[7] : x[5];
    f16x8 pf0 = __builtin_bit_cast(f16x8, cc0);   // keys k0+0..15
    f16x8 pf1 = __builtin_bit_cast(f16x8, cc1);   // keys k0+16..31

#pragma unroll
    for (int mt = 0; mt < 4; mt++) {
      const f16* vp = Vt + (size_t)(kvh * HEAD_DIM + mt * 32 + l31) * S_LEN
                         + k0 + 8 * gp;
      f16x8 v0 = *(const f16x8*)(vp);
      f16x8 v1 = *(const f16x8*)(vp + 16);
      oacc[mt] = __builtin_amdgcn_mfma_f32_32x32x16_f16(v0, pf0, oacc[mt], 0, 0, 0);
      oacc[mt] = __builtin_amdgcn_mfma_f32_32x32x16_f16(v1, pf1, oacc[mt], 0, 0, 0);
    }
  }

  // store: oacc[mt] is C[d][q]: q = lane&31, d = mt*32 + (r&3) + 8*(r>>2) + 4*gp
  unsigned short* ob = attnb + (size_t)qg * HIDDEN + h * HEAD_DIM;
#pragma unroll
  for (int mt = 0; mt < 4; mt++)
#pragma unroll
    for (int rq = 0; rq < 4; rq++) {
      int d = mt * 32 + 8 * rq + 4 * gp;
      ushort4 o;
      o.x = f2bf(oacc[mt][rq * 4 + 0]);
      o.y = f2bf(oacc[mt][rq * 4 + 1]);
      o.z = f2bf(oacc[mt][rq * 4 + 2]);
      o.w = f2bf(oacc[mt][rq * 4 + 3]);
      *(ushort4*)(ob + d) = o;
    }
}

// ---------------------------------------------------------------------------
// Attention pass 3: cs[h][key] = sum_q w[q,key]  (mask-critical, split-exact).
// KEY-major: block owns 32 keys x head; K frags (hi+lo) hoisted in registers
// for the whole q loop; cs partials live in 16 registers per lane and are
// reduced ONCE per block (butterfly over lane&31) -> 32 atomics/wave.
// No LDS, no barriers.
// ---------------------------------------------------------------------------
__global__ __launch_bounds__(256) void attn_cs(
    const f16* __restrict__ Qh, const f16* __restrict__ Ql,
    const f16* __restrict__ Kh, const f16* __restrict__ Kl,
    const float* __restrict__ Lrow, float* __restrict__ cs)
{
  const int t    = threadIdx.x;
  const int lane = t & 63;
  const int wave = t >> 6;
  const int l31  = lane & 31;
  const int gp   = lane >> 5;
  const int h    = blockIdx.y;
  const int kvh  = h >> 2;
  const int kb   = blockIdx.x << 5;

  f16x8 kah[8], kal[8];
  {
    const f16* kp  = Kh + (size_t)(kb + l31) * (N_KV * HEAD_DIM) + kvh * HEAD_DIM + 8 * gp;
    const f16* kp2 = Kl + (size_t)(kb + l31) * (N_KV * HEAD_DIM) + kvh * HEAD_DIM + 8 * gp;
#pragma unroll
    for (int c = 0; c < 8; c++) {
      kah[c] = *(const f16x8*)(kp  + c * 16);
      kal[c] = *(const f16x8*)(kp2 + c * 16);
    }
  }

  float csa[16];
#pragma unroll
  for (int r = 0; r < 16; r++) csa[r] = 0.f;

  for (int q0 = kb & ~127; q0 < S_LEN; q0 += 128) {
    const int qw = q0 + wave * 32;
    if (qw + 31 < kb) continue;          // wave-uniform, no barriers in kernel
    const int qg = qw + l31;
    const float iL = 1.0f / Lrow[h * S_LEN + qg];
    const f16* qp  = Qh + (size_t)qg * HIDDEN + h * HEAD_DIM + 8 * gp;
    const f16* qp2 = Ql + (size_t)qg * HIDDEN + h * HEAD_DIM + 8 * gp;

    f32x16 acc;
#pragma unroll
    for (int i = 0; i < 16; i++) acc[i] = 0.f;
#pragma unroll
    for (int c = 0; c < 8; c++) {
      f16x8 bh = *(const f16x8*)(qp  + c * 16);
      f16x8 bl = *(const f16x8*)(qp2 + c * 16);
      acc = __builtin_amdgcn_mfma_f32_32x32x16_f16(kah[c], bh, acc, 0, 0, 0);
      acc = __builtin_amdgcn_mfma_f32_32x32x16_f16(kah[c], bl, acc, 0, 0, 0);
      acc = __builtin_amdgcn_mfma_f32_32x32x16_f16(kal[c], bh, acc, 0, 0, 0);
    }
#pragma unroll
    for (int r = 0; r < 16; r++) {
      int kg = kb + (r & 3) + 8 * (r >> 2) + 4 * gp;
      csa[r] += (kg <= qg) ? exp2f(acc[r] * C2EXP) * iL : 0.f;
    }
  }

#pragma unroll
  for (int st = 1; st < 32; st <<= 1)
#pragma unroll
    for (int r = 0; r < 16; r++) csa[r] += __shfl_xor(csa[r], st);

  if (l31 == 0) {
#pragma unroll
    for (int r = 0; r < 16; r++)
      atomicAdd(&cs[h * S_LEN + kb + (r & 3) + 8 * (r >> 2) + 4 * gp], csa[r]);
  }
}

// ---------------------------------------------------------------------------
// Exact top-HEAVY_K of the first NCAND scores per head via O(n^2) ranking.
// ---------------------------------------------------------------------------
__global__ __launch_bounds__(256) void topk_mask_kernel(
    const float* __restrict__ cs, float* __restrict__ maskout)
{
  const int h = blockIdx.x;
  __shared__ float sv[NCAND];
  const float* s = cs + h * S_LEN;
  const int t = threadIdx.x;
  for (int i = t; i < NCAND; i += 256) sv[i] = s[i];
  __syncthreads();

  float v[8];
  int cnt[8];
#pragma unroll
  for (int j = 0; j < 8; j++) {
    int i = t + j * 256;
    v[j] = (i < NCAND) ? sv[i] : INFINITY;
    cnt[j] = 0;
  }
  for (int jj = 0; jj < NCAND; jj++) {
    float x = sv[jj];
#pragma unroll
    for (int j = 0; j < 8; j++) {
      int i = t + j * 256;
      cnt[j] += ((x > v[j]) || (x == v[j] && jj < i)) ? 1 : 0;
    }
  }

  float* mrow = maskout + h * MASK_LEN;
  for (int i = t; i < MASK_LEN; i += 256)
    mrow[i] = (i >= NCAND + 1) ? 1.0f : 0.0f;
#pragma unroll
  for (int j = 0; j < 8; j++) {
    int i = t + j * 256;
    if (i < NCAND && cnt[j] < HEAVY_K) mrow[i] = 1.0f;
  }
}

__global__ __launch_bounds__(256) void zero_kernel(float* __restrict__ p, int n)
{
  int i = blockIdx.x * 256 + threadIdx.x;
  if (i < n) p[i] = 0.f;
}

// ---------------------------------------------------------------------------
// In-place RoPE.
// ---------------------------------------------------------------------------
__global__ __launch_bounds__(256) void rope_kernel(
    float* __restrict__ buf, const int* __restrict__ pos_ids, int ncols)
{
  __shared__ float invf_s[64];
  if (threadIdx.x < 64)
    invf_s[threadIdx.x] =
        (float)(1.0 / pow(10000.0, (double)threadIdx.x * (1.0 / 64.0)));
  __syncthreads();

  int i = blockIdx.x * 256 + threadIdx.x;
  int half = ncols >> 1;
  int total = S_LEN * half;
  if (i >= total) return;
  int row = i / half;
  int rem = i - row * half;
  int hh = rem >> 6;
  int d  = rem & 63;
  float p = (float)pos_ids[row];
  float ang = p * invf_s[d];
  float c = cosf(ang);
  float s = sinf(ang);
  float* base = buf + (size_t)row * ncols + hh * HEAD_DIM;
  float x0 = base[d];
  float x1 = base[d + 64];
  base[d]      = x0 * c - x1 * s;
  base[d + 64] = x1 * c + x0 * s;
}

// ---------------------------------------------------------------------------
// Workspace layout (109,576,192 B total -- identical to previous version):
//   0         Qraw f32 (32MB)
//   33554432  Kraw f32 (8MB)  -> Vt f16 [1024][2048] (4MB) after K split
//   41943040  Vraw f32 (8MB)
//   50331648  Lrow (0.25MB)
//   50593792  cs   (0.25MB)
//   50855936  WvT bf16 (8MB)  -> Kh f16 (4MB) + Kl f16 (4MB) after Wv gemm
//   59244544  hsb bf16 (16MB) -> attnb (overlay, hsb dead after Wv gemm)
//   76021760  Qh f16 (16MB) \
//   92798976  Ql f16 (16MB) /-> WoT bf16 (32MB) after pass3 (Qh/Ql dead)
// ---------------------------------------------------------------------------
extern "C" void kernel_launch(void* const* d_in, const int* in_sizes, int n_in,
                              void* d_out, int out_size, void* d_ws, size_t ws_size,
                              hipStream_t stream)
{
  (void)in_sizes; (void)n_in; (void)out_size; (void)ws_size;
  const float* hs = (const float*)d_in[0];
  const int*  pos = (const int*)d_in[1];
  const float* Wq = (const float*)d_in[2];
  const float* Wk = (const float*)d_in[3];
  const float* Wv = (const float*)d_in[4];
  const float* Wo = (const float*)d_in[5];
  float* out = (float*)d_out;

  char* w = (char*)d_ws;
  float* Qraw          = (float*)(w);
  float* Kraw          = (float*)(w + 33554432);
  f16*   Vt            = (f16*)  (w + 33554432);   // overlays Kraw
  float* Vraw          = (float*)(w + 41943040);
  float* Lrow          = (float*)(w + 50331648);
  float* cs            = (float*)(w + 50593792);
  unsigned short* WvT  = (unsigned short*)(w + 50855936);
  f16*   Kh            = (f16*)  (w + 50855936);   // overlays WvT
  f16*   Kl            = (f16*)  (w + 55050240);
  unsigned short* hsb  = (unsigned short*)(w + 59244544);
  unsigned short* attnb = hsb;                     // hsb dead after Wv gemm
  f16*   Qh            = (f16*)  (w + 76021760);
  f16*   Ql            = (f16*)  (w + 92798976);
  unsigned short* WoT  = (unsigned short*)(w + 76021760); // overlays Qh+Ql

  dim3 blk(256);

  conv_rm<<<(S_LEN * HIDDEN / 4 + 255) / 256, blk, 0, stream>>>(
      hs, hsb, S_LEN * HIDDEN / 4);
  conv_T<<<dim3((N_KV * HEAD_DIM) / 32, HIDDEN / 32), blk, 0, stream>>>(
      Wv, WvT, HIDDEN, N_KV * HEAD_DIM);

  gemm_f32_128x64<<<dim3(HIDDEN / 64, S_LEN / 128), blk, 0, stream>>>(
      hs, Wq, Qraw, S_LEN, HIDDEN, HIDDEN);
  gemm_f32_128x64<<<dim3((N_KV * HEAD_DIM) / 64, S_LEN / 128), blk, 0, stream>>>(
      hs, Wk, Kraw, S_LEN, N_KV * HEAD_DIM, HIDDEN);
  gemm_bf16<<<dim3((N_KV * HEAD_DIM) / 64, S_LEN / 64), blk, 0, stream>>>(
      hsb, WvT, Vraw, S_LEN, N_KV * HEAD_DIM, HIDDEN);

  rope_kernel<<<(S_LEN * (HIDDEN / 2) + 255) / 256, blk, 0, stream>>>(
      Qraw, pos, HIDDEN);
  rope_kernel<<<(S_LEN * (N_KV * HEAD_DIM / 2) + 255) / 256, blk, 0, stream>>>(
      Kraw, pos, N_KV * HEAD_DIM);

  split_f16<<<(S_LEN * HIDDEN / 4 + 255) / 256, blk, 0, stream>>>(
      Qraw, Qh, Ql, S_LEN * HIDDEN / 4);
  split_f16<<<(S_LEN * N_KV * HEAD_DIM / 4 + 255) / 256, blk, 0, stream>>>(
      Kraw, Kh, Kl, S_LEN * N_KV * HEAD_DIM / 4);
  conv_T_f16<<<dim3((N_KV * HEAD_DIM) / 32, S_LEN / 32), blk, 0, stream>>>(
      Vraw, Vt, S_LEN, N_KV * HEAD_DIM);

  attn_l<<<dim3(S_LEN / 128, N_HEADS), blk, 0, stream>>>(
      Qh, Ql, Kh, Kl, Lrow);

  attn_o<<<dim3(S_LEN / 128, N_HEADS), blk, 0, stream>>>(
      Qh, Kh, Vt, Lrow, attnb);

  zero_kernel<<<(N_HEADS * S_LEN + 255) / 256, blk, 0, stream>>>(
      cs, N_HEADS * S_LEN);
  attn_cs<<<dim3((NCAND + 31) / 32, N_HEADS), blk, 0, stream>>>(
      Qh, Ql, Kh, Kl, Lrow, cs);

  topk_mask_kernel<<<N_HEADS, blk, 0, stream>>>(
      cs, out + (size_t)S_LEN * HIDDEN);

  conv_T<<<dim3(HIDDEN / 32, HIDDEN / 32), blk, 0, stream>>>(
      Wo, WoT, HIDDEN, HIDDEN);
  gemm_bf16<<<dim3(HIDDEN / 64, S_LEN / 64), blk, 0, stream>>>(
      attnb, WoT, out, S_LEN, HIDDEN, HIDDEN);
}

// Round 2
// 1759.411 us; speedup vs baseline: 2.0763x; 1.3600x over previous
//
#include <hip/hip_runtime.h>
#include <math.h>

#define S_LEN   2048
#define HIDDEN  4096
#define N_HEADS 32
#define N_KV    8
#define HEAD_DIM 128
#define NCAND   1844      // S - RECENT
#define HEAVY_K 819
#define MASK_LEN 2049     // S + 1

typedef _Float16 f16;
using f32x4  = __attribute__((ext_vector_type(4))) float;
using f32x16 = __attribute__((ext_vector_type(16))) float;
using f16x8  = __attribute__((ext_vector_type(8))) _Float16;
using f16x4  = __attribute__((ext_vector_type(4))) _Float16;
using f16x2  = __attribute__((ext_vector_type(2))) _Float16;
using uint4v = __attribute__((ext_vector_type(4))) unsigned int;

// exp(s*SCALE) == exp2(s*C2); single fused constant, used identically in all
// three attention passes so L, w, cs stay mutually consistent.
#define C2EXP 0.12751879523486166f   // (1/sqrt(128)) * log2(e)

// ---------------------------------------------------------------------------
// Split-f16 MFMA GEMM (mask-critical path, replaces the f32 VALU GEMM):
// C(f32)[M][ldc] = (Ah+Al)[M][K] * (Bh+Bl)[N][K]^T  via 3-term f16 MFMA
//   C ~= Ah*Bh + Ah*Bl + Al*Bh   (dropped Al*Bl term <= 2^-44 relative)
// Per-product residual ~2e-7 -- f32-summation-order-noise level.
// Tile 128x128, BK=32, 4 waves x (4x4 of 16x16x32) = 48 MFMA : 16 ds_read
// per k-step.  LDS stride 40 halfs (80B: 16B-aligned rows, 2-way banks max).
// ---------------------------------------------------------------------------
__global__ __launch_bounds__(256) void gemm_split(
    const f16* __restrict__ Ah, const f16* __restrict__ Al,
    const f16* __restrict__ Bh, const f16* __restrict__ Bl,
    float* __restrict__ C, int K, int ldc)
{
  __shared__ __align__(16) f16 Ash[128 * 40];
  __shared__ __align__(16) f16 Asl[128 * 40];
  __shared__ __align__(16) f16 Bsh[128 * 40];
  __shared__ __align__(16) f16 Bsl[128 * 40];
  const int t    = threadIdx.x;
  const int lane = t & 63;
  const int wave = t >> 6;
  const int mbase = (wave >> 1) * 64;
  const int nbase = (wave & 1) * 64;
  const int bm = blockIdx.y << 7;
  const int bn = blockIdx.x << 7;
  const int srow = t >> 1;          // 0..127
  const int scol = (t & 1) * 16;    // 0 | 16
  const int l16 = lane & 15;
  const int lk  = (lane >> 4) * 8;

  f32x4 acc[4][4];
#pragma unroll
  for (int i = 0; i < 4; i++)
#pragma unroll
    for (int j = 0; j < 4; j++) acc[i][j] = (f32x4){0.f, 0.f, 0.f, 0.f};

  for (int k0 = 0; k0 < K; k0 += 32) {
    const f16* gah = Ah + (size_t)(bm + srow) * K + k0 + scol;
    const f16* gal = Al + (size_t)(bm + srow) * K + k0 + scol;
    const f16* gbh = Bh + (size_t)(bn + srow) * K + k0 + scol;
    const f16* gbl = Bl + (size_t)(bn + srow) * K + k0 + scol;
    f16x8 vah0 = *(const f16x8*)(gah);
    f16x8 vah1 = *(const f16x8*)(gah + 8);
    f16x8 val0 = *(const f16x8*)(gal);
    f16x8 val1 = *(const f16x8*)(gal + 8);
    f16x8 vbh0 = *(const f16x8*)(gbh);
    f16x8 vbh1 = *(const f16x8*)(gbh + 8);
    f16x8 vbl0 = *(const f16x8*)(gbl);
    f16x8 vbl1 = *(const f16x8*)(gbl + 8);
    __syncthreads();
    *(f16x8*)(Ash + srow * 40 + scol)     = vah0;
    *(f16x8*)(Ash + srow * 40 + scol + 8) = vah1;
    *(f16x8*)(Asl + srow * 40 + scol)     = val0;
    *(f16x8*)(Asl + srow * 40 + scol + 8) = val1;
    *(f16x8*)(Bsh + srow * 40 + scol)     = vbh0;
    *(f16x8*)(Bsh + srow * 40 + scol + 8) = vbh1;
    *(f16x8*)(Bsl + srow * 40 + scol)     = vbl0;
    *(f16x8*)(Bsl + srow * 40 + scol + 8) = vbl1;
    __syncthreads();

    f16x8 afh[4], afl[4], bfh[4], bfl[4];
#pragma unroll
    for (int i = 0; i < 4; i++) {
      afh[i] = *(const f16x8*)(Ash + (mbase + i * 16 + l16) * 40 + lk);
      afl[i] = *(const f16x8*)(Asl + (mbase + i * 16 + l16) * 40 + lk);
      bfh[i] = *(const f16x8*)(Bsh + (nbase + i * 16 + l16) * 40 + lk);
      bfl[i] = *(const f16x8*)(Bsl + (nbase + i * 16 + l16) * 40 + lk);
    }
#pragma unroll
    for (int i = 0; i < 4; i++)
#pragma unroll
      for (int j = 0; j < 4; j++) {
        acc[i][j] = __builtin_amdgcn_mfma_f32_16x16x32_f16(afh[i], bfh[j], acc[i][j], 0, 0, 0);
        acc[i][j] = __builtin_amdgcn_mfma_f32_16x16x32_f16(afh[i], bfl[j], acc[i][j], 0, 0, 0);
        acc[i][j] = __builtin_amdgcn_mfma_f32_16x16x32_f16(afl[i], bfh[j], acc[i][j], 0, 0, 0);
      }
  }

  const int rr = (lane >> 4) * 4;
#pragma unroll
  for (int i = 0; i < 4; i++)
#pragma unroll
    for (int j = 0; j < 4; j++)
#pragma unroll
      for (int r = 0; r < 4; r++)
        C[(size_t)(bm + mbase + i * 16 + rr + r) * ldc + bn + nbase + j * 16 + l16]
            = acc[i][j][r];
}

// ---------------------------------------------------------------------------
// f16 MFMA GEMM (tolerance path: V and Wo): C(f32)[M,N] = A[M,K] * BT[N,K]^T.
// Same structure as the verified bf16 version, f16 operands.
// ---------------------------------------------------------------------------
__global__ __launch_bounds__(256) void gemm_f16(
    const f16* __restrict__ A, const f16* __restrict__ BT,
    float* __restrict__ C, int M, int N, int K)
{
  __shared__ __align__(16) f16 As[64 * 40];
  __shared__ __align__(16) f16 Bs[64 * 40];
  const int t    = threadIdx.x;
  const int lane = t & 63;
  const int wave = t >> 6;
  const int mbase = (wave >> 1) * 32;
  const int nbase = (wave & 1) * 32;
  const int bm = blockIdx.y << 6;
  const int bn = blockIdx.x << 6;
  const int srow = t >> 2;
  const int scol = (t & 3) * 8;
  const int l16 = lane & 15;
  const int lk  = (lane >> 4) * 8;

  f32x4 acc00 = {0.f,0.f,0.f,0.f}, acc01 = {0.f,0.f,0.f,0.f};
  f32x4 acc10 = {0.f,0.f,0.f,0.f}, acc11 = {0.f,0.f,0.f,0.f};

  for (int k0 = 0; k0 < K; k0 += 32) {
    f16x8 av = *(const f16x8*)(A  + (size_t)(bm + srow) * K + k0 + scol);
    f16x8 bv = *(const f16x8*)(BT + (size_t)(bn + srow) * K + k0 + scol);
    __syncthreads();
    *(f16x8*)(As + srow * 40 + scol) = av;
    *(f16x8*)(Bs + srow * 40 + scol) = bv;
    __syncthreads();
    f16x8 a0 = *(const f16x8*)(As + (mbase + l16)      * 40 + lk);
    f16x8 a1 = *(const f16x8*)(As + (mbase + 16 + l16) * 40 + lk);
    f16x8 b0 = *(const f16x8*)(Bs + (nbase + l16)      * 40 + lk);
    f16x8 b1 = *(const f16x8*)(Bs + (nbase + 16 + l16) * 40 + lk);
    acc00 = __builtin_amdgcn_mfma_f32_16x16x32_f16(a0, b0, acc00, 0, 0, 0);
    acc01 = __builtin_amdgcn_mfma_f32_16x16x32_f16(a0, b1, acc01, 0, 0, 0);
    acc10 = __builtin_amdgcn_mfma_f32_16x16x32_f16(a1, b0, acc10, 0, 0, 0);
    acc11 = __builtin_amdgcn_mfma_f32_16x16x32_f16(a1, b1, acc11, 0, 0, 0);
  }

  const int rr = (lane >> 4) * 4;
#pragma unroll
  for (int r = 0; r < 4; r++) {
    C[(size_t)(bm + mbase +      rr + r) * N + bn + nbase +      l16] = acc00[r];
    C[(size_t)(bm + mbase +      rr + r) * N + bn + nbase + 16 + l16] = acc01[r];
    C[(size_t)(bm + mbase + 16 + rr + r) * N + bn + nbase +      l16] = acc10[r];
    C[(size_t)(bm + mbase + 16 + rr + r) * N + bn + nbase + 16 + l16] = acc11[r];
  }
}

// ---------------------------------------------------------------------------
// f32 [K][N] -> f16 [N][K] transpose-convert.
// ---------------------------------------------------------------------------
__global__ __launch_bounds__(256) void conv_T_f16(
    const float* __restrict__ src, f16* __restrict__ dst, int K, int N)
{
  __shared__ float tile[32][33];
  const int tj = blockIdx.x;
  const int ti = blockIdx.y;
  const int t = threadIdx.x;
  for (int idx = t; idx < 1024; idx += 256) {
    int r = idx >> 5, c = idx & 31;
    tile[r][c] = src[(size_t)(ti * 32 + r) * N + tj * 32 + c];
  }
  __syncthreads();
  for (int idx = t; idx < 1024; idx += 256) {
    int r = idx >> 5, c = idx & 31;
    dst[(size_t)(tj * 32 + r) * K + ti * 32 + c] = (f16)tile[c][r];
  }
}

// ---------------------------------------------------------------------------
// f32 [K][N] cols [n0,n0+32*gridDim.x) -> split f16 hi/lo [NC][K] transpose.
// ---------------------------------------------------------------------------
__global__ __launch_bounds__(256) void conv_T_split(
    const float* __restrict__ src, f16* __restrict__ hi, f16* __restrict__ lo,
    int K, int N, int n0)
{
  __shared__ float tile[32][33];
  const int tj = blockIdx.x;
  const int ti = blockIdx.y;
  const int t = threadIdx.x;
  for (int idx = t; idx < 1024; idx += 256) {
    int r = idx >> 5, c = idx & 31;
    tile[r][c] = src[(size_t)(ti * 32 + r) * N + n0 + tj * 32 + c];
  }
  __syncthreads();
  for (int idx = t; idx < 1024; idx += 256) {
    int r = idx >> 5, c = idx & 31;
    float x = tile[c][r];
    f16 h = (f16)x;
    hi[(size_t)(tj * 32 + r) * K + ti * 32 + c] = h;
    lo[(size_t)(tj * 32 + r) * K + ti * 32 + c] = (f16)(x - (float)h);
  }
}

// ---------------------------------------------------------------------------
// f32 -> (f16 hi, f16 lo) split, row-major.  hi = rne(x); lo = rne(x - hi).
// ---------------------------------------------------------------------------
__global__ __launch_bounds__(256) void split_f16(
    const float* __restrict__ src, f16* __restrict__ hi, f16* __restrict__ lo,
    int n4)
{
  int i = blockIdx.x * 256 + threadIdx.x;
  if (i >= n4) return;
  float4 v = ((const float4*)src)[i];
  float vv[4] = {v.x, v.y, v.z, v.w};
  f16x4 h, l;
#pragma unroll
  for (int j = 0; j < 4; j++) {
    f16 hh = (f16)vv[j];
    h[j] = hh;
    l[j] = (f16)(vv[j] - (float)hh);
  }
  ((f16x4*)hi)[i] = h;
  ((f16x4*)lo)[i] = l;
}

// ---------------------------------------------------------------------------
// Attention pass 1: softmax denominators L[q] via split-f16 32x32x16 MFMA.
// (verified round 1 -- unchanged)
// ---------------------------------------------------------------------------
__global__ __launch_bounds__(256) void attn_l(
    const f16* __restrict__ Qh, const f16* __restrict__ Ql,
    const f16* __restrict__ Kh, const f16* __restrict__ Kl,
    float* __restrict__ Lrow)
{
  __shared__ __align__(16) f16 Khs[32 * 136];
  __shared__ __align__(16) f16 Kls[32 * 136];
  const int t    = threadIdx.x;
  const int lane = t & 63;
  const int wave = t >> 6;
  const int l31  = lane & 31;
  const int gp   = lane >> 5;
  const int h    = blockIdx.y;
  const int kvh  = h >> 2;
  const int q0   = (int)(gridDim.x - 1 - blockIdx.x) << 7;   // big blocks first
  const int qw   = q0 + wave * 32;
  const int qg   = qw + l31;

  f16x8 qhf[8], qlf[8];
  {
    const f16* qp  = Qh + (size_t)qg * HIDDEN + h * HEAD_DIM + 8 * gp;
    const f16* qp2 = Ql + (size_t)qg * HIDDEN + h * HEAD_DIM + 8 * gp;
#pragma unroll
    for (int c = 0; c < 8; c++) {
      qhf[c] = *(const f16x8*)(qp  + c * 16);
      qlf[c] = *(const f16x8*)(qp2 + c * 16);
    }
  }

  float Lacc = 0.f;
  const int ntiles = (q0 >> 5) + 4;
  for (int kt = 0; kt < ntiles; kt++) {
    const int k0 = kt << 5;
    __syncthreads();
    for (int i = t; i < 512; i += 256) {
      int r = i >> 4, c = i & 15;
      size_t g = (size_t)(k0 + r) * (N_KV * HEAD_DIM) + kvh * HEAD_DIM + c * 8;
      *(f16x8*)(Khs + r * 136 + c * 8) = *(const f16x8*)(Kh + g);
      *(f16x8*)(Kls + r * 136 + c * 8) = *(const f16x8*)(Kl + g);
    }
    __syncthreads();
    if (k0 > qw + 31) continue;   // after both barriers: barrier counts uniform

    f32x16 acc;
#pragma unroll
    for (int i = 0; i < 16; i++) acc[i] = 0.f;
#pragma unroll
    for (int c = 0; c < 8; c++) {
      f16x8 ah = *(const f16x8*)(Khs + l31 * 136 + c * 16 + 8 * gp);
      f16x8 al = *(const f16x8*)(Kls + l31 * 136 + c * 16 + 8 * gp);
      acc = __builtin_amdgcn_mfma_f32_32x32x16_f16(ah, qhf[c], acc, 0, 0, 0);
      acc = __builtin_amdgcn_mfma_f32_32x32x16_f16(ah, qlf[c], acc, 0, 0, 0);
      acc = __builtin_amdgcn_mfma_f32_32x32x16_f16(al, qhf[c], acc, 0, 0, 0);
    }
    float ws = 0.f;
#pragma unroll
    for (int r = 0; r < 16; r++) {
      int kg = k0 + (r & 3) + 8 * (r >> 2) + 4 * gp;
      float e = exp2f(acc[r] * C2EXP);
      ws += (kg <= qg) ? e : 0.f;
    }
    Lacc += ws;
  }

  float tot = Lacc + __shfl_xor(Lacc, 32);
  if (lane < 32) Lrow[h * S_LEN + qw + lane] = tot;
}

// ---------------------------------------------------------------------------
// Attention pass 2: O = softmax(QK^T) V via MFMA (verified round 1).
// Only change: attnb output is now f16 (feeds the f16 Wo GEMM).
// ---------------------------------------------------------------------------
__global__ __launch_bounds__(256) void attn_o(
    const f16* __restrict__ Qh, const f16* __restrict__ Kh,
    const f16* __restrict__ Vt, const float* __restrict__ Lrow,
    f16* __restrict__ attnb)
{
  __shared__ __align__(16) f16 Khs[32 * 136];
  const int t    = threadIdx.x;
  const int lane = t & 63;
  const int wave = t >> 6;
  const int l31  = lane & 31;
  const int gp   = lane >> 5;
  const int h    = blockIdx.y;
  const int kvh  = h >> 2;
  const int q0   = (int)(gridDim.x - 1 - blockIdx.x) << 7;
  const int qw   = q0 + wave * 32;
  const int qg   = qw + l31;

  f16x8 qhf[8];
  {
    const f16* qp = Qh + (size_t)qg * HIDDEN + h * HEAD_DIM + 8 * gp;
#pragma unroll
    for (int c = 0; c < 8; c++) qhf[c] = *(const f16x8*)(qp + c * 16);
  }
  const float iL = 1.0f / Lrow[h * S_LEN + qg];

  f32x16 oacc[4];
#pragma unroll
  for (int m = 0; m < 4; m++)
#pragma unroll
    for (int i = 0; i < 16; i++) oacc[m][i] = 0.f;

  const int ntiles = (q0 >> 5) + 4;
  for (int kt = 0; kt < ntiles; kt++) {
    const int k0 = kt << 5;
    __syncthreads();
    for (int i = t; i < 512; i += 256) {
      int r = i >> 4, c = i & 15;
      size_t g = (size_t)(k0 + r) * (N_KV * HEAD_DIM) + kvh * HEAD_DIM + c * 8;
      *(f16x8*)(Khs + r * 136 + c * 8) = *(const f16x8*)(Kh + g);
    }
    __syncthreads();
    if (k0 > qw + 31) continue;

    f32x16 acc;
#pragma unroll
    for (int i = 0; i < 16; i++) acc[i] = 0.f;
#pragma unroll
    for (int c = 0; c < 8; c++) {
      f16x8 ah = *(const f16x8*)(Khs + l31 * 136 + c * 16 + 8 * gp);
      acc = __builtin_amdgcn_mfma_f32_32x32x16_f16(ah, qhf[c], acc, 0, 0, 0);
    }

    float wv[16];
#pragma unroll
    for (int r = 0; r < 16; r++) {
      int kg = k0 + (r & 3) + 8 * (r >> 2) + 4 * gp;
      wv[r] = (kg <= qg) ? exp2f(acc[r] * C2EXP) * iL : 0.f;
    }

    unsigned p[8], x[8];
#pragma unroll
    for (int j = 0; j < 8; j++)
      p[j] = __builtin_bit_cast(unsigned,
               __builtin_amdgcn_cvt_pkrtz(wv[2 * j], wv[2 * j + 1]));
#pragma unroll
    for (int j = 0; j < 8; j++)
      x[j] = (unsigned)__shfl_xor((int)p[j], 32);

    uint4v cc0, cc1;   // B-frag: row(q)=lane&31, k = gp*8 + j
    cc0[0] = gp ? x[2] : p[0]; cc0[1] = gp ? x[3] : p[1];
    cc0[2] = gp ? p[2] : x[0]; cc0[3] = gp ? p[3] : x[1];
    cc1[0] = gp ? x[6] : p[4]; cc1[1] = gp ? x[7] : p[5];
    cc1[2] = gp ? p[6] : x[4]; cc1[3] = gp ? p[7] : x[5];
    f16x8 pf0 = __builtin_bit_cast(f16x8, cc0);   // keys k0+0..15
    f16x8 pf1 = __builtin_bit_cast(f16x8, cc1);   // keys k0+16..31

#pragma unroll
    for (int mt = 0; mt < 4; mt++) {
      const f16* vp = Vt + (size_t)(kvh * HEAD_DIM + mt * 32 + l31) * S_LEN
                         + k0 + 8 * gp;
      f16x8 v0 = *(const f16x8*)(vp);
      f16x8 v1 = *(const f16x8*)(vp + 16);
      oacc[mt] = __builtin_amdgcn_mfma_f32_32x32x16_f16(v0, pf0, oacc[mt], 0, 0, 0);
      oacc[mt] = __builtin_amdgcn_mfma_f32_32x32x16_f16(v1, pf1, oacc[mt], 0, 0, 0);
    }
  }

  f16* ob = attnb + (size_t)qg * HIDDEN + h * HEAD_DIM;
#pragma unroll
  for (int mt = 0; mt < 4; mt++)
#pragma unroll
    for (int rq = 0; rq < 4; rq++) {
      int d = mt * 32 + 8 * rq + 4 * gp;
      f16x4 o;
      o[0] = (f16)oacc[mt][rq * 4 + 0];
      o[1] = (f16)oacc[mt][rq * 4 + 1];
      o[2] = (f16)oacc[mt][rq * 4 + 2];
      o[3] = (f16)oacc[mt][rq * 4 + 3];
      *(f16x4*)(ob + d) = o;
    }
}

// ---------------------------------------------------------------------------
// Attention pass 3: cs[h][key] = sum_q w[q,key] (verified round 1, unchanged).
// ---------------------------------------------------------------------------
__global__ __launch_bounds__(256) void attn_cs(
    const f16* __restrict__ Qh, const f16* __restrict__ Ql,
    const f16* __restrict__ Kh, const f16* __restrict__ Kl,
    const float* __restrict__ Lrow, float* __restrict__ cs)
{
  const int t    = threadIdx.x;
  const int lane = t & 63;
  const int wave = t >> 6;
  const int l31  = lane & 31;
  const int gp   = lane >> 5;
  const int h    = blockIdx.y;
  const int kvh  = h >> 2;
  const int kb   = blockIdx.x << 5;

  f16x8 kah[8], kal[8];
  {
    const f16* kp  = Kh + (size_t)(kb + l31) * (N_KV * HEAD_DIM) + kvh * HEAD_DIM + 8 * gp;
    const f16* kp2 = Kl + (size_t)(kb + l31) * (N_KV * HEAD_DIM) + kvh * HEAD_DIM + 8 * gp;
#pragma unroll
    for (int c = 0; c < 8; c++) {
      kah[c] = *(const f16x8*)(kp  + c * 16);
      kal[c] = *(const f16x8*)(kp2 + c * 16);
    }
  }

  float csa[16];
#pragma unroll
  for (int r = 0; r < 16; r++) csa[r] = 0.f;

  for (int q0 = kb & ~127; q0 < S_LEN; q0 += 128) {
    const int qw = q0 + wave * 32;
    if (qw + 31 < kb) continue;          // wave-uniform, no barriers in kernel
    const int qg = qw + l31;
    const float iL = 1.0f / Lrow[h * S_LEN + qg];
    const f16* qp  = Qh + (size_t)qg * HIDDEN + h * HEAD_DIM + 8 * gp;
    const f16* qp2 = Ql + (size_t)qg * HIDDEN + h * HEAD_DIM + 8 * gp;

    f32x16 acc;
#pragma unroll
    for (int i = 0; i < 16; i++) acc[i] = 0.f;
#pragma unroll
    for (int c = 0; c < 8; c++) {
      f16x8 bh = *(const f16x8*)(qp  + c * 16);
      f16x8 bl = *(const f16x8*)(qp2 + c * 16);
      acc = __builtin_amdgcn_mfma_f32_32x32x16_f16(kah[c], bh, acc, 0, 0, 0);
      acc = __builtin_amdgcn_mfma_f32_32x32x16_f16(kah[c], bl, acc, 0, 0, 0);
      acc = __builtin_amdgcn_mfma_f32_32x32x16_f16(kal[c], bh, acc, 0, 0, 0);
    }
#pragma unroll
    for (int r = 0; r < 16; r++) {
      int kg = kb + (r & 3) + 8 * (r >> 2) + 4 * gp;
      csa[r] += (kg <= qg) ? exp2f(acc[r] * C2EXP) * iL : 0.f;
    }
  }

#pragma unroll
  for (int st = 1; st < 32; st <<= 1)
#pragma unroll
    for (int r = 0; r < 16; r++) csa[r] += __shfl_xor(csa[r], st);

  if (l31 == 0) {
#pragma unroll
    for (int r = 0; r < 16; r++)
      atomicAdd(&cs[h * S_LEN + kb + (r & 3) + 8 * (r >> 2) + 4 * gp], csa[r]);
  }
}

// ---------------------------------------------------------------------------
// Exact top-HEAVY_K of the first NCAND scores per head via O(n^2) ranking.
// ---------------------------------------------------------------------------
__global__ __launch_bounds__(256) void topk_mask_kernel(
    const float* __restrict__ cs, float* __restrict__ maskout)
{
  const int h = blockIdx.x;
  __shared__ float sv[NCAND];
  const float* s = cs + h * S_LEN;
  const int t = threadIdx.x;
  for (int i = t; i < NCAND; i += 256) sv[i] = s[i];
  __syncthreads();

  float v[8];
  int cnt[8];
#pragma unroll
  for (int j = 0; j < 8; j++) {
    int i = t + j * 256;
    v[j] = (i < NCAND) ? sv[i] : INFINITY;
    cnt[j] = 0;
  }
  for (int jj = 0; jj < NCAND; jj++) {
    float x = sv[jj];
#pragma unroll
    for (int j = 0; j < 8; j++) {
      int i = t + j * 256;
      cnt[j] += ((x > v[j]) || (x == v[j] && jj < i)) ? 1 : 0;
    }
  }

  float* mrow = maskout + h * MASK_LEN;
  for (int i = t; i < MASK_LEN; i += 256)
    mrow[i] = (i >= NCAND + 1) ? 1.0f : 0.0f;
#pragma unroll
  for (int j = 0; j < 8; j++) {
    int i = t + j * 256;
    if (i < NCAND && cnt[j] < HEAVY_K) mrow[i] = 1.0f;
  }
}

__global__ __launch_bounds__(256) void zero_kernel(float* __restrict__ p, int n)
{
  int i = blockIdx.x * 256 + threadIdx.x;
  if (i < n) p[i] = 0.f;
}

// ---------------------------------------------------------------------------
// In-place RoPE.
// ---------------------------------------------------------------------------
__global__ __launch_bounds__(256) void rope_kernel(
    float* __restrict__ buf, const int* __restrict__ pos_ids, int ncols)
{
  __shared__ float invf_s[64];
  if (threadIdx.x < 64)
    invf_s[threadIdx.x] =
        (float)(1.0 / pow(10000.0, (double)threadIdx.x * (1.0 / 64.0)));
  __syncthreads();

  int i = blockIdx.x * 256 + threadIdx.x;
  int half = ncols >> 1;
  int total = S_LEN * half;
  if (i >= total) return;
  int row = i / half;
  int rem = i - row * half;
  int hh = rem >> 6;
  int d  = rem & 63;
  float p = (float)pos_ids[row];
  float ang = p * invf_s[d];
  float c = cosf(ang);
  float s = sinf(ang);
  float* base = buf + (size_t)row * ncols + hh * HEAD_DIM;
  float x0 = base[d];
  float x1 = base[d + 64];
  base[d]      = x0 * c - x1 * s;
  base[d + 64] = x1 * c + x0 * s;
}

// ---------------------------------------------------------------------------
// Workspace layout (109,576,192 B total -- identical footprint to round 1).
// Offsets in MiB; overlays annotated with the producer/consumer ordering
// that makes them safe:
//   0      Qraw f32 (32)      -> WoT f16 (32)       [after Q split]
//   32     WqTl chunk f16(16) -> Kraw f32 (8)       [after Wq gemms]
//                             -> Vt f16 (4)         [after K split]
//   40     (WqTl high half)   -> Vraw f32 (8)       [after Wq gemms]
//   48     Lrow (0.25) | cs (0.25)
//   48.5   hsh f16 (16)       -> attnb f16 (16)     [after V gemm]
//   64.5   hsl f16 (16)       -> Qh f16 (16)        [after K gemm]
//   80.5   WqTh chunk f16(16) -> WkTh(8)|WvT(8)     [sequenced]
//                             -> Ql f16 (16)        [after V gemm]
//   96.5   (WkTl f16 8 @88.5 inside the 80.5 region)
//   96.5   Kh f16 (4)
//   100.5  Kl f16 (4)                               [end 104.5 MiB]
// ---------------------------------------------------------------------------
extern "C" void kernel_launch(void* const* d_in, const int* in_sizes, int n_in,
                              void* d_out, int out_size, void* d_ws, size_t ws_size,
                              hipStream_t stream)
{
  (void)in_sizes; (void)n_in; (void)out_size; (void)ws_size;
  const float* hs = (const float*)d_in[0];
  const int*  pos = (const int*)d_in[1];
  const float* Wq = (const float*)d_in[2];
  const float* Wk = (const float*)d_in[3];
  const float* Wv = (const float*)d_in[4];
  const float* Wo = (const float*)d_in[5];
  float* out = (float*)d_out;

  char* w = (char*)d_ws;
  float* Qraw  = (float*)(w);                          // 32 MiB
  f16*   WoT   = (f16*)  (w);                          // overlays Qraw
  f16*   WqTl  = (f16*)  (w + 33554432);               // 16 MiB (32..48)
  float* Kraw  = (float*)(w + 33554432);               // 8 MiB, after Wq gemms
  f16*   Vt    = (f16*)  (w + 33554432);               // 4 MiB, after K split
  float* Vraw  = (float*)(w + 41943040);               // 8 MiB
  float* Lrow  = (float*)(w + 50331648);
  float* cs    = (float*)(w + 50593792);
  f16*   hsh   = (f16*)  (w + 50855936);               // 16 MiB (48.5..64.5)
  f16*   attnb = (f16*)  (w + 50855936);               // overlays hsh
  f16*   hsl   = (f16*)  (w + 67633152);               // 16 MiB (64.5..80.5)
  f16*   Qh    = (f16*)  (w + 67633152);               // overlays hsl
  f16*   WqTh  = (f16*)  (w + 84410368);               // 16 MiB (80.5..96.5)
  f16*   WkTh  = (f16*)  (w + 84410368);               //  8 MiB
  f16*   WvT   = (f16*)  (w + 84410368);               //  8 MiB
  f16*   Ql    = (f16*)  (w + 84410368);               // overlays, after V gemm
  f16*   WkTl  = (f16*)  (w + 92798976);               //  8 MiB (88.5..96.5)
  f16*   Kh    = (f16*)  (w + 101187584);              //  4 MiB
  f16*   Kl    = (f16*)  (w + 105381888);              //  4 MiB -> end 104.5 MiB

  dim3 blk(256);

  // --- split hidden_states once (A-operand for Q, K, V gemms) ---
  split_f16<<<(S_LEN * HIDDEN / 4 + 255) / 256, blk, 0, stream>>>(
      hs, hsh, hsl, S_LEN * HIDDEN / 4);

  // --- Q = hs @ Wq, split-exact, two N=2048 chunks ---
  conv_T_split<<<dim3(2048 / 32, HIDDEN / 32), blk, 0, stream>>>(
      Wq, WqTh, WqTl, HIDDEN, HIDDEN, 0);
  gemm_split<<<dim3(2048 / 128, S_LEN / 128), blk, 0, stream>>>(
      hsh, hsl, WqTh, WqTl, Qraw, HIDDEN, HIDDEN);
  conv_T_split<<<dim3(2048 / 32, HIDDEN / 32), blk, 0, stream>>>(
      Wq, WqTh, WqTl, HIDDEN, HIDDEN, 2048);
  gemm_split<<<dim3(2048 / 128, S_LEN / 128), blk, 0, stream>>>(
      hsh, hsl, WqTh, WqTl, Qraw + 2048, HIDDEN, HIDDEN);

  // --- K = hs @ Wk, split-exact ---
  conv_T_split<<<dim3((N_KV * HEAD_DIM) / 32, HIDDEN / 32), blk, 0, stream>>>(
      Wk, WkTh, WkTl, HIDDEN, N_KV * HEAD_DIM, 0);
  gemm_split<<<dim3((N_KV * HEAD_DIM) / 128, S_LEN / 128), blk, 0, stream>>>(
      hsh, hsl, WkTh, WkTl, Kraw, HIDDEN, N_KV * HEAD_DIM);

  // --- V = hs @ Wv, f16 (tolerance path) ---
  conv_T_f16<<<dim3((N_KV * HEAD_DIM) / 32, HIDDEN / 32), blk, 0, stream>>>(
      Wv, WvT, HIDDEN, N_KV * HEAD_DIM);
  gemm_f16<<<dim3((N_KV * HEAD_DIM) / 64, S_LEN / 64), blk, 0, stream>>>(
      hsh, WvT, Vraw, S_LEN, N_KV * HEAD_DIM, HIDDEN);

  // --- RoPE (f32, in place) ---
  rope_kernel<<<(S_LEN * (HIDDEN / 2) + 255) / 256, blk, 0, stream>>>(
      Qraw, pos, HIDDEN);
  rope_kernel<<<(S_LEN * (N_KV * HEAD_DIM / 2) + 255) / 256, blk, 0, stream>>>(
      Kraw, pos, N_KV * HEAD_DIM);

  // --- splits for attention ---
  split_f16<<<(S_LEN * HIDDEN / 4 + 255) / 256, blk, 0, stream>>>(
      Qraw, Qh, Ql, S_LEN * HIDDEN / 4);
  split_f16<<<(S_LEN * N_KV * HEAD_DIM / 4 + 255) / 256, blk, 0, stream>>>(
      Kraw, Kh, Kl, S_LEN * N_KV * HEAD_DIM / 4);
  conv_T_f16<<<dim3((N_KV * HEAD_DIM) / 32, S_LEN / 32), blk, 0, stream>>>(
      Vraw, Vt, S_LEN, N_KV * HEAD_DIM);
  conv_T_f16<<<dim3(HIDDEN / 32, HIDDEN / 32), blk, 0, stream>>>(
      Wo, WoT, HIDDEN, HIDDEN);   // Qraw dead (split done) -> safe overlay

  // --- attention ---
  attn_l<<<dim3(S_LEN / 128, N_HEADS), blk, 0, stream>>>(
      Qh, Ql, Kh, Kl, Lrow);
  attn_o<<<dim3(S_LEN / 128, N_HEADS), blk, 0, stream>>>(
      Qh, Kh, Vt, Lrow, attnb);
  zero_kernel<<<(N_HEADS * S_LEN + 255) / 256, blk, 0, stream>>>(
      cs, N_HEADS * S_LEN);
  attn_cs<<<dim3((NCAND + 31) / 32, N_HEADS), blk, 0, stream>>>(
      Qh, Ql, Kh, Kl, Lrow, cs);
  topk_mask_kernel<<<N_HEADS, blk, 0, stream>>>(
      cs, out + (size_t)S_LEN * HIDDEN);

  // --- output projection ---
  gemm_f16<<<dim3(HIDDEN / 64, S_LEN / 64), blk, 0, stream>>>(
      attnb, WoT, out, S_LEN, HIDDEN, HIDDEN);
}

// Round 4
// 1536.252 us; speedup vs baseline: 2.3779x; 1.1453x over previous
//
#include <hip/hip_runtime.h>
#include <math.h>

#define S_LEN   2048
#define HIDDEN  4096
#define N_HEADS 32
#define N_KV    8
#define HEAD_DIM 128
#define NCAND   1844      // S - RECENT
#define HEAVY_K 819
#define MASK_LEN 2049     // S + 1

typedef _Float16 f16;
using f32x4  = __attribute__((ext_vector_type(4))) float;
using f32x16 = __attribute__((ext_vector_type(16))) float;
using f16x8  = __attribute__((ext_vector_type(8))) _Float16;
using f16x4  = __attribute__((ext_vector_type(4))) _Float16;
using f16x2  = __attribute__((ext_vector_type(2))) _Float16;
using uint4v = __attribute__((ext_vector_type(4))) unsigned int;

// exp(s*SCALE) == exp2(s*C2); single fused constant, used identically in all
// three attention passes so L, w, cs stay mutually consistent.
#define C2EXP 0.12751879523486166f   // (1/sqrt(128)) * log2(e)

// ---------------------------------------------------------------------------
// Split-f16 MFMA GEMM (mask-critical path):
// C(f32)[M][ldc] = (Ah+Al)[M][K] * (Bh+Bl)[N][K]^T  via 3-term f16 MFMA
//   C ~= Ah*Bh + Ah*Bl + Al*Bh   (dropped Al*Bl term <= 2^-44 relative)
// Tile 128x128, BK=32, 4 waves x (4x4 of 16x16x32) = 48 MFMA : 16 ds_read
// per k-step.  LDS stride 40 halfs (80B: 16B-aligned rows, 2-way banks max).
// (verified rounds 1-2)
// ---------------------------------------------------------------------------
__global__ __launch_bounds__(256) void gemm_split(
    const f16* __restrict__ Ah, const f16* __restrict__ Al,
    const f16* __restrict__ Bh, const f16* __restrict__ Bl,
    float* __restrict__ C, int K, int ldc)
{
  __shared__ __align__(16) f16 Ash[128 * 40];
  __shared__ __align__(16) f16 Asl[128 * 40];
  __shared__ __align__(16) f16 Bsh[128 * 40];
  __shared__ __align__(16) f16 Bsl[128 * 40];
  const int t    = threadIdx.x;
  const int lane = t & 63;
  const int wave = t >> 6;
  const int mbase = (wave >> 1) * 64;
  const int nbase = (wave & 1) * 64;
  const int bm = blockIdx.y << 7;
  const int bn = blockIdx.x << 7;
  const int srow = t >> 1;          // 0..127
  const int scol = (t & 1) * 16;    // 0 | 16
  const int l16 = lane & 15;
  const int lk  = (lane >> 4) * 8;

  f32x4 acc[4][4];
#pragma unroll
  for (int i = 0; i < 4; i++)
#pragma unroll
    for (int j = 0; j < 4; j++) acc[i][j] = (f32x4){0.f, 0.f, 0.f, 0.f};

  for (int k0 = 0; k0 < K; k0 += 32) {
    const f16* gah = Ah + (size_t)(bm + srow) * K + k0 + scol;
    const f16* gal = Al + (size_t)(bm + srow) * K + k0 + scol;
    const f16* gbh = Bh + (size_t)(bn + srow) * K + k0 + scol;
    const f16* gbl = Bl + (size_t)(bn + srow) * K + k0 + scol;
    f16x8 vah0 = *(const f16x8*)(gah);
    f16x8 vah1 = *(const f16x8*)(gah + 8);
    f16x8 val0 = *(const f16x8*)(gal);
    f16x8 val1 = *(const f16x8*)(gal + 8);
    f16x8 vbh0 = *(const f16x8*)(gbh);
    f16x8 vbh1 = *(const f16x8*)(gbh + 8);
    f16x8 vbl0 = *(const f16x8*)(gbl);
    f16x8 vbl1 = *(const f16x8*)(gbl + 8);
    __syncthreads();
    *(f16x8*)(Ash + srow * 40 + scol)     = vah0;
    *(f16x8*)(Ash + srow * 40 + scol + 8) = vah1;
    *(f16x8*)(Asl + srow * 40 + scol)     = val0;
    *(f16x8*)(Asl + srow * 40 + scol + 8) = val1;
    *(f16x8*)(Bsh + srow * 40 + scol)     = vbh0;
    *(f16x8*)(Bsh + srow * 40 + scol + 8) = vbh1;
    *(f16x8*)(Bsl + srow * 40 + scol)     = vbl0;
    *(f16x8*)(Bsl + srow * 40 + scol + 8) = vbl1;
    __syncthreads();

    f16x8 afh[4], afl[4], bfh[4], bfl[4];
#pragma unroll
    for (int i = 0; i < 4; i++) {
      afh[i] = *(const f16x8*)(Ash + (mbase + i * 16 + l16) * 40 + lk);
      afl[i] = *(const f16x8*)(Asl + (mbase + i * 16 + l16) * 40 + lk);
      bfh[i] = *(const f16x8*)(Bsh + (nbase + i * 16 + l16) * 40 + lk);
      bfl[i] = *(const f16x8*)(Bsl + (nbase + i * 16 + l16) * 40 + lk);
    }
#pragma unroll
    for (int i = 0; i < 4; i++)
#pragma unroll
      for (int j = 0; j < 4; j++) {
        acc[i][j] = __builtin_amdgcn_mfma_f32_16x16x32_f16(afh[i], bfh[j], acc[i][j], 0, 0, 0);
        acc[i][j] = __builtin_amdgcn_mfma_f32_16x16x32_f16(afh[i], bfl[j], acc[i][j], 0, 0, 0);
        acc[i][j] = __builtin_amdgcn_mfma_f32_16x16x32_f16(afl[i], bfh[j], acc[i][j], 0, 0, 0);
      }
  }

  const int rr = (lane >> 4) * 4;
#pragma unroll
  for (int i = 0; i < 4; i++)
#pragma unroll
    for (int j = 0; j < 4; j++)
#pragma unroll
      for (int r = 0; r < 4; r++)
        C[(size_t)(bm + mbase + i * 16 + rr + r) * ldc + bn + nbase + j * 16 + l16]
            = acc[i][j][r];
}

// ---------------------------------------------------------------------------
// f16 MFMA GEMM, 128x128 tile (tolerance path, Wo): same skeleton as
// gemm_split with the lo-terms deleted -> 16 MFMA : 8 ds_read per k-step.
// C(f32)[M][ldc] = A[M][K] * BT[N][K]^T.
// ---------------------------------------------------------------------------
__global__ __launch_bounds__(256) void gemm_f16_128(
    const f16* __restrict__ A, const f16* __restrict__ BT,
    float* __restrict__ C, int K, int ldc)
{
  __shared__ __align__(16) f16 As[128 * 40];
  __shared__ __align__(16) f16 Bs[128 * 40];
  const int t    = threadIdx.x;
  const int lane = t & 63;
  const int wave = t >> 6;
  const int mbase = (wave >> 1) * 64;
  const int nbase = (wave & 1) * 64;
  const int bm = blockIdx.y << 7;
  const int bn = blockIdx.x << 7;
  const int srow = t >> 1;
  const int scol = (t & 1) * 16;
  const int l16 = lane & 15;
  const int lk  = (lane >> 4) * 8;

  f32x4 acc[4][4];
#pragma unroll
  for (int i = 0; i < 4; i++)
#pragma unroll
    for (int j = 0; j < 4; j++) acc[i][j] = (f32x4){0.f, 0.f, 0.f, 0.f};

  for (int k0 = 0; k0 < K; k0 += 32) {
    const f16* ga = A  + (size_t)(bm + srow) * K + k0 + scol;
    const f16* gb = BT + (size_t)(bn + srow) * K + k0 + scol;
    f16x8 va0 = *(const f16x8*)(ga);
    f16x8 va1 = *(const f16x8*)(ga + 8);
    f16x8 vb0 = *(const f16x8*)(gb);
    f16x8 vb1 = *(const f16x8*)(gb + 8);
    __syncthreads();
    *(f16x8*)(As + srow * 40 + scol)     = va0;
    *(f16x8*)(As + srow * 40 + scol + 8) = va1;
    *(f16x8*)(Bs + srow * 40 + scol)     = vb0;
    *(f16x8*)(Bs + srow * 40 + scol + 8) = vb1;
    __syncthreads();

    f16x8 af[4], bf[4];
#pragma unroll
    for (int i = 0; i < 4; i++) {
      af[i] = *(const f16x8*)(As + (mbase + i * 16 + l16) * 40 + lk);
      bf[i] = *(const f16x8*)(Bs + (nbase + i * 16 + l16) * 40 + lk);
    }
#pragma unroll
    for (int i = 0; i < 4; i++)
#pragma unroll
      for (int j = 0; j < 4; j++)
        acc[i][j] = __builtin_amdgcn_mfma_f32_16x16x32_f16(af[i], bf[j], acc[i][j], 0, 0, 0);
  }

  const int rr = (lane >> 4) * 4;
#pragma unroll
  for (int i = 0; i < 4; i++)
#pragma unroll
    for (int j = 0; j < 4; j++)
#pragma unroll
      for (int r = 0; r < 4; r++)
        C[(size_t)(bm + mbase + i * 16 + rr + r) * ldc + bn + nbase + j * 16 + l16]
            = acc[i][j][r];
}

// ---------------------------------------------------------------------------
// f16 MFMA GEMM 64x64 (V projection: N=1024 wants block count).
// ---------------------------------------------------------------------------
__global__ __launch_bounds__(256) void gemm_f16(
    const f16* __restrict__ A, const f16* __restrict__ BT,
    float* __restrict__ C, int M, int N, int K)
{
  __shared__ __align__(16) f16 As[64 * 40];
  __shared__ __align__(16) f16 Bs[64 * 40];
  const int t    = threadIdx.x;
  const int lane = t & 63;
  const int wave = t >> 6;
  const int mbase = (wave >> 1) * 32;
  const int nbase = (wave & 1) * 32;
  const int bm = blockIdx.y << 6;
  const int bn = blockIdx.x << 6;
  const int srow = t >> 2;
  const int scol = (t & 3) * 8;
  const int l16 = lane & 15;
  const int lk  = (lane >> 4) * 8;

  f32x4 acc00 = {0.f,0.f,0.f,0.f}, acc01 = {0.f,0.f,0.f,0.f};
  f32x4 acc10 = {0.f,0.f,0.f,0.f}, acc11 = {0.f,0.f,0.f,0.f};

  for (int k0 = 0; k0 < K; k0 += 32) {
    f16x8 av = *(const f16x8*)(A  + (size_t)(bm + srow) * K + k0 + scol);
    f16x8 bv = *(const f16x8*)(BT + (size_t)(bn + srow) * K + k0 + scol);
    __syncthreads();
    *(f16x8*)(As + srow * 40 + scol) = av;
    *(f16x8*)(Bs + srow * 40 + scol) = bv;
    __syncthreads();
    f16x8 a0 = *(const f16x8*)(As + (mbase + l16)      * 40 + lk);
    f16x8 a1 = *(const f16x8*)(As + (mbase + 16 + l16) * 40 + lk);
    f16x8 b0 = *(const f16x8*)(Bs + (nbase + l16)      * 40 + lk);
    f16x8 b1 = *(const f16x8*)(Bs + (nbase + 16 + l16) * 40 + lk);
    acc00 = __builtin_amdgcn_mfma_f32_16x16x32_f16(a0, b0, acc00, 0, 0, 0);
    acc01 = __builtin_amdgcn_mfma_f32_16x16x32_f16(a0, b1, acc01, 0, 0, 0);
    acc10 = __builtin_amdgcn_mfma_f32_16x16x32_f16(a1, b0, acc10, 0, 0, 0);
    acc11 = __builtin_amdgcn_mfma_f32_16x16x32_f16(a1, b1, acc11, 0, 0, 0);
  }

  const int rr = (lane >> 4) * 4;
#pragma unroll
  for (int r = 0; r < 4; r++) {
    C[(size_t)(bm + mbase +      rr + r) * N + bn + nbase +      l16] = acc00[r];
    C[(size_t)(bm + mbase +      rr + r) * N + bn + nbase + 16 + l16] = acc01[r];
    C[(size_t)(bm + mbase + 16 + rr + r) * N + bn + nbase +      l16] = acc10[r];
    C[(size_t)(bm + mbase + 16 + rr + r) * N + bn + nbase + 16 + l16] = acc11[r];
  }
}

// ---------------------------------------------------------------------------
// f32 [K][N] -> f16 [N][K] transpose-convert.
// ---------------------------------------------------------------------------
__global__ __launch_bounds__(256) void conv_T_f16(
    const float* __restrict__ src, f16* __restrict__ dst, int K, int N)
{
  __shared__ float tile[32][33];
  const int tj = blockIdx.x;
  const int ti = blockIdx.y;
  const int t = threadIdx.x;
  for (int idx = t; idx < 1024; idx += 256) {
    int r = idx >> 5, c = idx & 31;
    tile[r][c] = src[(size_t)(ti * 32 + r) * N + tj * 32 + c];
  }
  __syncthreads();
  for (int idx = t; idx < 1024; idx += 256) {
    int r = idx >> 5, c = idx & 31;
    dst[(size_t)(tj * 32 + r) * K + ti * 32 + c] = (f16)tile[c][r];
  }
}

// ---------------------------------------------------------------------------
// f32 [K][N] cols [n0,n0+32*gridDim.x) -> split f16 hi/lo [NC][K] transpose.
// ---------------------------------------------------------------------------
__global__ __launch_bounds__(256) void conv_T_split(
    const float* __restrict__ src, f16* __restrict__ hi, f16* __restrict__ lo,
    int K, int N, int n0)
{
  __shared__ float tile[32][33];
  const int tj = blockIdx.x;
  const int ti = blockIdx.y;
  const int t = threadIdx.x;
  for (int idx = t; idx < 1024; idx += 256) {
    int r = idx >> 5, c = idx & 31;
    tile[r][c] = src[(size_t)(ti * 32 + r) * N + n0 + tj * 32 + c];
  }
  __syncthreads();
  for (int idx = t; idx < 1024; idx += 256) {
    int r = idx >> 5, c = idx & 31;
    float x = tile[c][r];
    f16 h = (f16)x;
    hi[(size_t)(tj * 32 + r) * K + ti * 32 + c] = h;
    lo[(size_t)(tj * 32 + r) * K + ti * 32 + c] = (f16)(x - (float)h);
  }
}

// ---------------------------------------------------------------------------
// f32 -> (f16 hi, f16 lo) split, row-major.  hi = rne(x); lo = rne(x - hi).
// ---------------------------------------------------------------------------
__global__ __launch_bounds__(256) void split_f16(
    const float* __restrict__ src, f16* __restrict__ hi, f16* __restrict__ lo,
    int n4)
{
  int i = blockIdx.x * 256 + threadIdx.x;
  if (i >= n4) return;
  float4 v = ((const float4*)src)[i];
  float vv[4] = {v.x, v.y, v.z, v.w};
  f16x4 h, l;
#pragma unroll
  for (int j = 0; j < 4; j++) {
    f16 hh = (f16)vv[j];
    h[j] = hh;
    l[j] = (f16)(vv[j] - (float)hh);
  }
  ((f16x4*)hi)[i] = h;
  ((f16x4*)lo)[i] = l;
}

// ---------------------------------------------------------------------------
// Attention pass 1: softmax denominators L[q] via split-f16 32x32x16 MFMA.
// (verified round 1 -- unchanged)
// ---------------------------------------------------------------------------
__global__ __launch_bounds__(256) void attn_l(
    const f16* __restrict__ Qh, const f16* __restrict__ Ql,
    const f16* __restrict__ Kh, const f16* __restrict__ Kl,
    float* __restrict__ Lrow)
{
  __shared__ __align__(16) f16 Khs[32 * 136];
  __shared__ __align__(16) f16 Kls[32 * 136];
  const int t    = threadIdx.x;
  const int lane = t & 63;
  const int wave = t >> 6;
  const int l31  = lane & 31;
  const int gp   = lane >> 5;
  const int h    = blockIdx.y;
  const int kvh  = h >> 2;
  const int q0   = (int)(gridDim.x - 1 - blockIdx.x) << 7;   // big blocks first
  const int qw   = q0 + wave * 32;
  const int qg   = qw + l31;

  f16x8 qhf[8], qlf[8];
  {
    const f16* qp  = Qh + (size_t)qg * HIDDEN + h * HEAD_DIM + 8 * gp;
    const f16* qp2 = Ql + (size_t)qg * HIDDEN + h * HEAD_DIM + 8 * gp;
#pragma unroll
    for (int c = 0; c < 8; c++) {
      qhf[c] = *(const f16x8*)(qp  + c * 16);
      qlf[c] = *(const f16x8*)(qp2 + c * 16);
    }
  }

  float Lacc = 0.f;
  const int ntiles = (q0 >> 5) + 4;
  for (int kt = 0; kt < ntiles; kt++) {
    const int k0 = kt << 5;
    __syncthreads();
    for (int i = t; i < 512; i += 256) {
      int r = i >> 4, c = i & 15;
      size_t g = (size_t)(k0 + r) * (N_KV * HEAD_DIM) + kvh * HEAD_DIM + c * 8;
      *(f16x8*)(Khs + r * 136 + c * 8) = *(const f16x8*)(Kh + g);
      *(f16x8*)(Kls + r * 136 + c * 8) = *(const f16x8*)(Kl + g);
    }
    __syncthreads();
    if (k0 > qw + 31) continue;   // after both barriers: barrier counts uniform

    f32x16 acc;
#pragma unroll
    for (int i = 0; i < 16; i++) acc[i] = 0.f;
#pragma unroll
    for (int c = 0; c < 8; c++) {
      f16x8 ah = *(const f16x8*)(Khs + l31 * 136 + c * 16 + 8 * gp);
      f16x8 al = *(const f16x8*)(Kls + l31 * 136 + c * 16 + 8 * gp);
      acc = __builtin_amdgcn_mfma_f32_32x32x16_f16(ah, qhf[c], acc, 0, 0, 0);
      acc = __builtin_amdgcn_mfma_f32_32x32x16_f16(ah, qlf[c], acc, 0, 0, 0);
      acc = __builtin_amdgcn_mfma_f32_32x32x16_f16(al, qhf[c], acc, 0, 0, 0);
    }
    float ws = 0.f;
#pragma unroll
    for (int r = 0; r < 16; r++) {
      int kg = k0 + (r & 3) + 8 * (r >> 2) + 4 * gp;
      float e = exp2f(acc[r] * C2EXP);
      ws += (kg <= qg) ? e : 0.f;
    }
    Lacc += ws;
  }

  float tot = Lacc + __shfl_xor(Lacc, 32);
  if (lane < 32) Lrow[h * S_LEN + qw + lane] = tot;
}

// ---------------------------------------------------------------------------
// Attention pass 2: O = softmax(QK^T) V via MFMA (verified rounds 1-2).
// ---------------------------------------------------------------------------
__global__ __launch_bounds__(256) void attn_o(
    const f16* __restrict__ Qh, const f16* __restrict__ Kh,
    const f16* __restrict__ Vt, const float* __restrict__ Lrow,
    f16* __restrict__ attnb)
{
  __shared__ __align__(16) f16 Khs[32 * 136];
  const int t    = threadIdx.x;
  const int lane = t & 63;
  const int wave = t >> 6;
  const int l31  = lane & 31;
  const int gp   = lane >> 5;
  const int h    = blockIdx.y;
  const int kvh  = h >> 2;
  const int q0   = (int)(gridDim.x - 1 - blockIdx.x) << 7;
  const int qw   = q0 + wave * 32;
  const int qg   = qw + l31;

  f16x8 qhf[8];
  {
    const f16* qp = Qh + (size_t)qg * HIDDEN + h * HEAD_DIM + 8 * gp;
#pragma unroll
    for (int c = 0; c < 8; c++) qhf[c] = *(const f16x8*)(qp + c * 16);
  }
  const float iL = 1.0f / Lrow[h * S_LEN + qg];

  f32x16 oacc[4];
#pragma unroll
  for (int m = 0; m < 4; m++)
#pragma unroll
    for (int i = 0; i < 16; i++) oacc[m][i] = 0.f;

  const int ntiles = (q0 >> 5) + 4;
  for (int kt = 0; kt < ntiles; kt++) {
    const int k0 = kt << 5;
    __syncthreads();
    for (int i = t; i < 512; i += 256) {
      int r = i >> 4, c = i & 15;
      size_t g = (size_t)(k0 + r) * (N_KV * HEAD_DIM) + kvh * HEAD_DIM + c * 8;
      *(f16x8*)(Khs + r * 136 + c * 8) = *(const f16x8*)(Kh + g);
    }
    __syncthreads();
    if (k0 > qw + 31) continue;

    f32x16 acc;
#pragma unroll
    for (int i = 0; i < 16; i++) acc[i] = 0.f;
#pragma unroll
    for (int c = 0; c < 8; c++) {
      f16x8 ah = *(const f16x8*)(Khs + l31 * 136 + c * 16 + 8 * gp);
      acc = __builtin_amdgcn_mfma_f32_32x32x16_f16(ah, qhf[c], acc, 0, 0, 0);
    }

    float wv[16];
#pragma unroll
    for (int r = 0; r < 16; r++) {
      int kg = k0 + (r & 3) + 8 * (r >> 2) + 4 * gp;
      wv[r] = (kg <= qg) ? exp2f(acc[r] * C2EXP) * iL : 0.f;
    }

    unsigned p[8], x[8];
#pragma unroll
    for (int j = 0; j < 8; j++)
      p[j] = __builtin_bit_cast(unsigned,
               __builtin_amdgcn_cvt_pkrtz(wv[2 * j], wv[2 * j + 1]));
#pragma unroll
    for (int j = 0; j < 8; j++)
      x[j] = (unsigned)__shfl_xor((int)p[j], 32);

    uint4v cc0, cc1;   // B-frag: row(q)=lane&31, k = gp*8 + j
    cc0[0] = gp ? x[2] : p[0]; cc0[1] = gp ? x[3] : p[1];
    cc0[2] = gp ? p[2] : x[0]; cc0[3] = gp ? p[3] : x[1];
    cc1[0] = gp ? x[6] : p[4]; cc1[1] = gp ? x[7] : p[5];
    cc1[2] = gp ? p[6] : x[4]; cc1[3] = gp ? p[7] : x[5];
    f16x8 pf0 = __builtin_bit_cast(f16x8, cc0);   // keys k0+0..15
    f16x8 pf1 = __builtin_bit_cast(f16x8, cc1);   // keys k0+16..31

#pragma unroll
    for (int mt = 0; mt < 4; mt++) {
      const f16* vp = Vt + (size_t)(kvh * HEAD_DIM + mt * 32 + l31) * S_LEN
                         + k0 + 8 * gp;
      f16x8 v0 = *(const f16x8*)(vp);
      f16x8 v1 = *(const f16x8*)(vp + 16);
      oacc[mt] = __builtin_amdgcn_mfma_f32_32x32x16_f16(v0, pf0, oacc[mt], 0, 0, 0);
      oacc[mt] = __builtin_amdgcn_mfma_f32_32x32x16_f16(v1, pf1, oacc[mt], 0, 0, 0);
    }
  }

  f16* ob = attnb + (size_t)qg * HIDDEN + h * HEAD_DIM;
#pragma unroll
  for (int mt = 0; mt < 4; mt++)
#pragma unroll
    for (int rq = 0; rq < 4; rq++) {
      int d = mt * 32 + 8 * rq + 4 * gp;
      f16x4 o;
      o[0] = (f16)oacc[mt][rq * 4 + 0];
      o[1] = (f16)oacc[mt][rq * 4 + 1];
      o[2] = (f16)oacc[mt][rq * 4 + 2];
      o[3] = (f16)oacc[mt][rq * 4 + 3];
      *(f16x4*)(ob + d) = o;
    }
}

// ---------------------------------------------------------------------------
// Attention pass 3: cs[h][key] = sum_q w[q,key] (verified rounds 1-2).
// ---------------------------------------------------------------------------
__global__ __launch_bounds__(256) void attn_cs(
    const f16* __restrict__ Qh, const f16* __restrict__ Ql,
    const f16* __restrict__ Kh, const f16* __restrict__ Kl,
    const float* __restrict__ Lrow, float* __restrict__ cs)
{
  const int t    = threadIdx.x;
  const int lane = t & 63;
  const int wave = t >> 6;
  const int l31  = lane & 31;
  const int gp   = lane >> 5;
  const int h    = blockIdx.y;
  const int kvh  = h >> 2;
  const int kb   = blockIdx.x << 5;

  f16x8 kah[8], kal[8];
  {
    const f16* kp  = Kh + (size_t)(kb + l31) * (N_KV * HEAD_DIM) + kvh * HEAD_DIM + 8 * gp;
    const f16* kp2 = Kl + (size_t)(kb + l31) * (N_KV * HEAD_DIM) + kvh * HEAD_DIM + 8 * gp;
#pragma unroll
    for (int c = 0; c < 8; c++) {
      kah[c] = *(const f16x8*)(kp  + c * 16);
      kal[c] = *(const f16x8*)(kp2 + c * 16);
    }
  }

  float csa[16];
#pragma unroll
  for (int r = 0; r < 16; r++) csa[r] = 0.f;

  for (int q0 = kb & ~127; q0 < S_LEN; q0 += 128) {
    const int qw = q0 + wave * 32;
    if (qw + 31 < kb) continue;          // wave-uniform, no barriers in kernel
    const int qg = qw + l31;
    const float iL = 1.0f / Lrow[h * S_LEN + qg];
    const f16* qp  = Qh + (size_t)qg * HIDDEN + h * HEAD_DIM + 8 * gp;
    const f16* qp2 = Ql + (size_t)qg * HIDDEN + h * HEAD_DIM + 8 * gp;

    f32x16 acc;
#pragma unroll
    for (int i = 0; i < 16; i++) acc[i] = 0.f;
#pragma unroll
    for (int c = 0; c < 8; c++) {
      f16x8 bh = *(const f16x8*)(qp  + c * 16);
      f16x8 bl = *(const f16x8*)(qp2 + c * 16);
      acc = __builtin_amdgcn_mfma_f32_32x32x16_f16(kah[c], bh, acc, 0, 0, 0);
      acc = __builtin_amdgcn_mfma_f32_32x32x16_f16(kah[c], bl, acc, 0, 0, 0);
      acc = __builtin_amdgcn_mfma_f32_32x32x16_f16(kal[c], bh, acc, 0, 0, 0);
    }
#pragma unroll
    for (int r = 0; r < 16; r++) {
      int kg = kb + (r & 3) + 8 * (r >> 2) + 4 * gp;
      csa[r] += (kg <= qg) ? exp2f(acc[r] * C2EXP) * iL : 0.f;
    }
  }

#pragma unroll
  for (int st = 1; st < 32; st <<= 1)
#pragma unroll
    for (int r = 0; r < 16; r++) csa[r] += __shfl_xor(csa[r], st);

  if (l31 == 0) {
#pragma unroll
    for (int r = 0; r < 16; r++)
      atomicAdd(&cs[h * S_LEN + kb + (r & 3) + 8 * (r >> 2) + 4 * gp], csa[r]);
  }
}

// ---------------------------------------------------------------------------
// Exact top-HEAVY_K via O(n^2) ranking -- PARALLELIZED: one candidate per
// thread, 9 x 32 blocks (vs 32).  Identical comparison + tie-break (jj < i)
// -> mask bit-identical; just spread over 288 blocks instead of 32.
// ---------------------------------------------------------------------------
__global__ __launch_bounds__(256) void topk_mask_kernel(
    const float* __restrict__ cs, float* __restrict__ maskout)
{
  const int h = blockIdx.y;
  __shared__ float sv[NCAND];
  const float* s = cs + h * S_LEN;
  const int t = threadIdx.x;
  for (int i = t; i < NCAND; i += 256) sv[i] = s[i];
  __syncthreads();

  const int i = blockIdx.x * 256 + t;
  if (i >= MASK_LEN) return;
  float val = (i >= NCAND + 1) ? 1.0f : 0.0f;
  if (i < NCAND) {
    const float v = sv[i];
    int cnt = 0;
#pragma unroll 4
    for (int jj = 0; jj < NCAND; jj++) {
      float x = sv[jj];
      cnt += ((x > v) || (x == v && jj < i)) ? 1 : 0;
    }
    val = (cnt < HEAVY_K) ? 1.0f : 0.0f;
  }
  maskout[h * MASK_LEN + i] = val;
}

__global__ __launch_bounds__(256) void zero_kernel(float* __restrict__ p, int n)
{
  int i = blockIdx.x * 256 + threadIdx.x;
  if (i < n) p[i] = 0.f;
}

// ---------------------------------------------------------------------------
// In-place RoPE.
// ---------------------------------------------------------------------------
__global__ __launch_bounds__(256) void rope_kernel(
    float* __restrict__ buf, const int* __restrict__ pos_ids, int ncols)
{
  __shared__ float invf_s[64];
  if (threadIdx.x < 64)
    invf_s[threadIdx.x] =
        (float)(1.0 / pow(10000.0, (double)threadIdx.x * (1.0 / 64.0)));
  __syncthreads();

  int i = blockIdx.x * 256 + threadIdx.x;
  int half = ncols >> 1;
  int total = S_LEN * half;
  if (i >= total) return;
  int row = i / half;
  int rem = i - row * half;
  int hh = rem >> 6;
  int d  = rem & 63;
  float p = (float)pos_ids[row];
  float ang = p * invf_s[d];
  float c = cosf(ang);
  float s = sinf(ang);
  float* base = buf + (size_t)row * ncols + hh * HEAD_DIM;
  float x0 = base[d];
  float x1 = base[d + 64];
  base[d]      = x0 * c - x1 * s;
  base[d + 64] = x1 * c + x0 * s;
}

// ---------------------------------------------------------------------------
// Workspace layout (109,576,192 B total -- unchanged from round 2).
// ---------------------------------------------------------------------------
extern "C" void kernel_launch(void* const* d_in, const int* in_sizes, int n_in,
                              void* d_out, int out_size, void* d_ws, size_t ws_size,
                              hipStream_t stream)
{
  (void)in_sizes; (void)n_in; (void)out_size; (void)ws_size;
  const float* hs = (const float*)d_in[0];
  const int*  pos = (const int*)d_in[1];
  const float* Wq = (const float*)d_in[2];
  const float* Wk = (const float*)d_in[3];
  const float* Wv = (const float*)d_in[4];
  const float* Wo = (const float*)d_in[5];
  float* out = (float*)d_out;

  char* w = (char*)d_ws;
  float* Qraw  = (float*)(w);                          // 32 MiB
  f16*   WoT   = (f16*)  (w);                          // overlays Qraw
  f16*   WqTl  = (f16*)  (w + 33554432);               // 16 MiB (32..48)
  float* Kraw  = (float*)(w + 33554432);               // 8 MiB, after Wq gemms
  f16*   Vt    = (f16*)  (w + 33554432);               // 4 MiB, after K split
  float* Vraw  = (float*)(w + 41943040);               // 8 MiB
  float* Lrow  = (float*)(w + 50331648);
  float* cs    = (float*)(w + 50593792);
  f16*   hsh   = (f16*)  (w + 50855936);               // 16 MiB (48.5..64.5)
  f16*   attnb = (f16*)  (w + 50855936);               // overlays hsh
  f16*   hsl   = (f16*)  (w + 67633152);               // 16 MiB (64.5..80.5)
  f16*   Qh    = (f16*)  (w + 67633152);               // overlays hsl
  f16*   WqTh  = (f16*)  (w + 84410368);               // 16 MiB (80.5..96.5)
  f16*   WkTh  = (f16*)  (w + 84410368);               //  8 MiB
  f16*   WvT   = (f16*)  (w + 84410368);               //  8 MiB
  f16*   Ql    = (f16*)  (w + 84410368);               // overlays, after V gemm
  f16*   WkTl  = (f16*)  (w + 92798976);               //  8 MiB (88.5..96.5)
  f16*   Kh    = (f16*)  (w + 101187584);              //  4 MiB
  f16*   Kl    = (f16*)  (w + 105381888);              //  4 MiB -> end 104.5 MiB

  dim3 blk(256);

  // --- split hidden_states once (A-operand for Q, K, V gemms) ---
  split_f16<<<(S_LEN * HIDDEN / 4 + 255) / 256, blk, 0, stream>>>(
      hs, hsh, hsl, S_LEN * HIDDEN / 4);

  // --- Q = hs @ Wq, split-exact, two N=2048 chunks ---
  conv_T_split<<<dim3(2048 / 32, HIDDEN / 32), blk, 0, stream>>>(
      Wq, WqTh, WqTl, HIDDEN, HIDDEN, 0);
  gemm_split<<<dim3(2048 / 128, S_LEN / 128), blk, 0, stream>>>(
      hsh, hsl, WqTh, WqTl, Qraw, HIDDEN, HIDDEN);
  conv_T_split<<<dim3(2048 / 32, HIDDEN / 32), blk, 0, stream>>>(
      Wq, WqTh, WqTl, HIDDEN, HIDDEN, 2048);
  gemm_split<<<dim3(2048 / 128, S_LEN / 128), blk, 0, stream>>>(
      hsh, hsl, WqTh, WqTl, Qraw + 2048, HIDDEN, HIDDEN);

  // --- K = hs @ Wk, split-exact ---
  conv_T_split<<<dim3((N_KV * HEAD_DIM) / 32, HIDDEN / 32), blk, 0, stream>>>(
      Wk, WkTh, WkTl, HIDDEN, N_KV * HEAD_DIM, 0);
  gemm_split<<<dim3((N_KV * HEAD_DIM) / 128, S_LEN / 128), blk, 0, stream>>>(
      hsh, hsl, WkTh, WkTl, Kraw, HIDDEN, N_KV * HEAD_DIM);

  // --- V = hs @ Wv, f16 (tolerance path) ---
  conv_T_f16<<<dim3((N_KV * HEAD_DIM) / 32, HIDDEN / 32), blk, 0, stream>>>(
      Wv, WvT, HIDDEN, N_KV * HEAD_DIM);
  gemm_f16<<<dim3((N_KV * HEAD_DIM) / 64, S_LEN / 64), blk, 0, stream>>>(
      hsh, WvT, Vraw, S_LEN, N_KV * HEAD_DIM, HIDDEN);

  // --- RoPE (f32, in place) ---
  rope_kernel<<<(S_LEN * (HIDDEN / 2) + 255) / 256, blk, 0, stream>>>(
      Qraw, pos, HIDDEN);
  rope_kernel<<<(S_LEN * (N_KV * HEAD_DIM / 2) + 255) / 256, blk, 0, stream>>>(
      Kraw, pos, N_KV * HEAD_DIM);

  // --- splits for attention ---
  split_f16<<<(S_LEN * HIDDEN / 4 + 255) / 256, blk, 0, stream>>>(
      Qraw, Qh, Ql, S_LEN * HIDDEN / 4);
  split_f16<<<(S_LEN * N_KV * HEAD_DIM / 4 + 255) / 256, blk, 0, stream>>>(
      Kraw, Kh, Kl, S_LEN * N_KV * HEAD_DIM / 4);
  conv_T_f16<<<dim3((N_KV * HEAD_DIM) / 32, S_LEN / 32), blk, 0, stream>>>(
      Vraw, Vt, S_LEN, N_KV * HEAD_DIM);
  conv_T_f16<<<dim3(HIDDEN / 32, HIDDEN / 32), blk, 0, stream>>>(
      Wo, WoT, HIDDEN, HIDDEN);   // Qraw dead (split done) -> safe overlay

  // --- attention ---
  attn_l<<<dim3(S_LEN / 128, N_HEADS), blk, 0, stream>>>(
      Qh, Ql, Kh, Kl, Lrow);
  attn_o<<<dim3(S_LEN / 128, N_HEADS), blk, 0, stream>>>(
      Qh, Kh, Vt, Lrow, attnb);
  zero_kernel<<<(N_HEADS * S_LEN + 255) / 256, blk, 0, stream>>>(
      cs, N_HEADS * S_LEN);
  attn_cs<<<dim3((NCAND + 31) / 32, N_HEADS), blk, 0, stream>>>(
      Qh, Ql, Kh, Kl, Lrow, cs);
  topk_mask_kernel<<<dim3((MASK_LEN + 255) / 256, N_HEADS), blk, 0, stream>>>(
      cs, out + (size_t)S_LEN * HIDDEN);

  // --- output projection (128x128 tile) ---
  gemm_f16_128<<<dim3(HIDDEN / 128, S_LEN / 128), blk, 0, stream>>>(
      attnb, WoT, out, HIDDEN, HIDDEN);
}

// Round 5
// 1479.519 us; speedup vs baseline: 2.4691x; 1.0383x over previous
//
#include <hip/hip_runtime.h>
#include <math.h>

#define S_LEN   2048
#define HIDDEN  4096
#define N_HEADS 32
#define N_KV    8
#define HEAD_DIM 128
#define NCAND   1844      // S - RECENT
#define HEAVY_K 819
#define MASK_LEN 2049     // S + 1

typedef _Float16 f16;
using f32x4  = __attribute__((ext_vector_type(4))) float;
using f32x16 = __attribute__((ext_vector_type(16))) float;
using f16x8  = __attribute__((ext_vector_type(8))) _Float16;
using f16x4  = __attribute__((ext_vector_type(4))) _Float16;
using f16x2  = __attribute__((ext_vector_type(2))) _Float16;
using uint4v = __attribute__((ext_vector_type(4))) unsigned int;

// exp(s*SCALE) == exp2(s*C2); single fused constant, used identically in all
// three attention passes so L, w, cs stay mutually consistent.
#define C2EXP 0.12751879523486166f   // (1/sqrt(128)) * log2(e)

// ---------------------------------------------------------------------------
// Split-f16 MFMA GEMM (mask-critical path):
// C(f32)[M][ldc] = (Ah+Al)[M][K] * (Bh+Bl)[N][K]^T  via 3-term f16 MFMA
//   C ~= Ah*Bh + Ah*Bl + Al*Bh   (dropped Al*Bl term <= 2^-44 relative)
// Tile 128x128, BK=32, 4 waves x (4x4 of 16x16x32) = 48 MFMA : 16 ds_read
// per k-step.  LDS stride 40 halfs (80B: 16B-aligned rows, 2-way banks max).
// (verified rounds 1-4)
// ---------------------------------------------------------------------------
__global__ __launch_bounds__(256) void gemm_split(
    const f16* __restrict__ Ah, const f16* __restrict__ Al,
    const f16* __restrict__ Bh, const f16* __restrict__ Bl,
    float* __restrict__ C, int K, int ldc)
{
  __shared__ __align__(16) f16 Ash[128 * 40];
  __shared__ __align__(16) f16 Asl[128 * 40];
  __shared__ __align__(16) f16 Bsh[128 * 40];
  __shared__ __align__(16) f16 Bsl[128 * 40];
  const int t    = threadIdx.x;
  const int lane = t & 63;
  const int wave = t >> 6;
  const int mbase = (wave >> 1) * 64;
  const int nbase = (wave & 1) * 64;
  const int bm = blockIdx.y << 7;
  const int bn = blockIdx.x << 7;
  const int srow = t >> 1;          // 0..127
  const int scol = (t & 1) * 16;    // 0 | 16
  const int l16 = lane & 15;
  const int lk  = (lane >> 4) * 8;

  f32x4 acc[4][4];
#pragma unroll
  for (int i = 0; i < 4; i++)
#pragma unroll
    for (int j = 0; j < 4; j++) acc[i][j] = (f32x4){0.f, 0.f, 0.f, 0.f};

  for (int k0 = 0; k0 < K; k0 += 32) {
    const f16* gah = Ah + (size_t)(bm + srow) * K + k0 + scol;
    const f16* gal = Al + (size_t)(bm + srow) * K + k0 + scol;
    const f16* gbh = Bh + (size_t)(bn + srow) * K + k0 + scol;
    const f16* gbl = Bl + (size_t)(bn + srow) * K + k0 + scol;
    f16x8 vah0 = *(const f16x8*)(gah);
    f16x8 vah1 = *(const f16x8*)(gah + 8);
    f16x8 val0 = *(const f16x8*)(gal);
    f16x8 val1 = *(const f16x8*)(gal + 8);
    f16x8 vbh0 = *(const f16x8*)(gbh);
    f16x8 vbh1 = *(const f16x8*)(gbh + 8);
    f16x8 vbl0 = *(const f16x8*)(gbl);
    f16x8 vbl1 = *(const f16x8*)(gbl + 8);
    __syncthreads();
    *(f16x8*)(Ash + srow * 40 + scol)     = vah0;
    *(f16x8*)(Ash + srow * 40 + scol + 8) = vah1;
    *(f16x8*)(Asl + srow * 40 + scol)     = val0;
    *(f16x8*)(Asl + srow * 40 + scol + 8) = val1;
    *(f16x8*)(Bsh + srow * 40 + scol)     = vbh0;
    *(f16x8*)(Bsh + srow * 40 + scol + 8) = vbh1;
    *(f16x8*)(Bsl + srow * 40 + scol)     = vbl0;
    *(f16x8*)(Bsl + srow * 40 + scol + 8) = vbl1;
    __syncthreads();

    f16x8 afh[4], afl[4], bfh[4], bfl[4];
#pragma unroll
    for (int i = 0; i < 4; i++) {
      afh[i] = *(const f16x8*)(Ash + (mbase + i * 16 + l16) * 40 + lk);
      afl[i] = *(const f16x8*)(Asl + (mbase + i * 16 + l16) * 40 + lk);
      bfh[i] = *(const f16x8*)(Bsh + (nbase + i * 16 + l16) * 40 + lk);
      bfl[i] = *(const f16x8*)(Bsl + (nbase + i * 16 + l16) * 40 + lk);
    }
#pragma unroll
    for (int i = 0; i < 4; i++)
#pragma unroll
      for (int j = 0; j < 4; j++) {
        acc[i][j] = __builtin_amdgcn_mfma_f32_16x16x32_f16(afh[i], bfh[j], acc[i][j], 0, 0, 0);
        acc[i][j] = __builtin_amdgcn_mfma_f32_16x16x32_f16(afh[i], bfl[j], acc[i][j], 0, 0, 0);
        acc[i][j] = __builtin_amdgcn_mfma_f32_16x16x32_f16(afl[i], bfh[j], acc[i][j], 0, 0, 0);
      }
  }

  const int rr = (lane >> 4) * 4;
#pragma unroll
  for (int i = 0; i < 4; i++)
#pragma unroll
    for (int j = 0; j < 4; j++)
#pragma unroll
      for (int r = 0; r < 4; r++)
        C[(size_t)(bm + mbase + i * 16 + rr + r) * ldc + bn + nbase + j * 16 + l16]
            = acc[i][j][r];
}

// ---------------------------------------------------------------------------
// f16 MFMA GEMM, 128x128 tile (tolerance path, Wo): same skeleton as
// gemm_split with the lo-terms deleted -> 16 MFMA : 8 ds_read per k-step.
// C(f32)[M][ldc] = A[M][K] * BT[N][K]^T.  (verified round 4)
// ---------------------------------------------------------------------------
__global__ __launch_bounds__(256) void gemm_f16_128(
    const f16* __restrict__ A, const f16* __restrict__ BT,
    float* __restrict__ C, int K, int ldc)
{
  __shared__ __align__(16) f16 As[128 * 40];
  __shared__ __align__(16) f16 Bs[128 * 40];
  const int t    = threadIdx.x;
  const int lane = t & 63;
  const int wave = t >> 6;
  const int mbase = (wave >> 1) * 64;
  const int nbase = (wave & 1) * 64;
  const int bm = blockIdx.y << 7;
  const int bn = blockIdx.x << 7;
  const int srow = t >> 1;
  const int scol = (t & 1) * 16;
  const int l16 = lane & 15;
  const int lk  = (lane >> 4) * 8;

  f32x4 acc[4][4];
#pragma unroll
  for (int i = 0; i < 4; i++)
#pragma unroll
    for (int j = 0; j < 4; j++) acc[i][j] = (f32x4){0.f, 0.f, 0.f, 0.f};

  for (int k0 = 0; k0 < K; k0 += 32) {
    const f16* ga = A  + (size_t)(bm + srow) * K + k0 + scol;
    const f16* gb = BT + (size_t)(bn + srow) * K + k0 + scol;
    f16x8 va0 = *(const f16x8*)(ga);
    f16x8 va1 = *(const f16x8*)(ga + 8);
    f16x8 vb0 = *(const f16x8*)(gb);
    f16x8 vb1 = *(const f16x8*)(gb + 8);
    __syncthreads();
    *(f16x8*)(As + srow * 40 + scol)     = va0;
    *(f16x8*)(As + srow * 40 + scol + 8) = va1;
    *(f16x8*)(Bs + srow * 40 + scol)     = vb0;
    *(f16x8*)(Bs + srow * 40 + scol + 8) = vb1;
    __syncthreads();

    f16x8 af[4], bf[4];
#pragma unroll
    for (int i = 0; i < 4; i++) {
      af[i] = *(const f16x8*)(As + (mbase + i * 16 + l16) * 40 + lk);
      bf[i] = *(const f16x8*)(Bs + (nbase + i * 16 + l16) * 40 + lk);
    }
#pragma unroll
    for (int i = 0; i < 4; i++)
#pragma unroll
      for (int j = 0; j < 4; j++)
        acc[i][j] = __builtin_amdgcn_mfma_f32_16x16x32_f16(af[i], bf[j], acc[i][j], 0, 0, 0);
  }

  const int rr = (lane >> 4) * 4;
#pragma unroll
  for (int i = 0; i < 4; i++)
#pragma unroll
    for (int j = 0; j < 4; j++)
#pragma unroll
      for (int r = 0; r < 4; r++)
        C[(size_t)(bm + mbase + i * 16 + rr + r) * ldc + bn + nbase + j * 16 + l16]
            = acc[i][j][r];
}

// ---------------------------------------------------------------------------
// f16 MFMA GEMM 64x64 (V projection: N=1024 wants block count).
// ---------------------------------------------------------------------------
__global__ __launch_bounds__(256) void gemm_f16(
    const f16* __restrict__ A, const f16* __restrict__ BT,
    float* __restrict__ C, int M, int N, int K)
{
  __shared__ __align__(16) f16 As[64 * 40];
  __shared__ __align__(16) f16 Bs[64 * 40];
  const int t    = threadIdx.x;
  const int lane = t & 63;
  const int wave = t >> 6;
  const int mbase = (wave >> 1) * 32;
  const int nbase = (wave & 1) * 32;
  const int bm = blockIdx.y << 6;
  const int bn = blockIdx.x << 6;
  const int srow = t >> 2;
  const int scol = (t & 3) * 8;
  const int l16 = lane & 15;
  const int lk  = (lane >> 4) * 8;

  f32x4 acc00 = {0.f,0.f,0.f,0.f}, acc01 = {0.f,0.f,0.f,0.f};
  f32x4 acc10 = {0.f,0.f,0.f,0.f}, acc11 = {0.f,0.f,0.f,0.f};

  for (int k0 = 0; k0 < K; k0 += 32) {
    f16x8 av = *(const f16x8*)(A  + (size_t)(bm + srow) * K + k0 + scol);
    f16x8 bv = *(const f16x8*)(BT + (size_t)(bn + srow) * K + k0 + scol);
    __syncthreads();
    *(f16x8*)(As + srow * 40 + scol) = av;
    *(f16x8*)(Bs + srow * 40 + scol) = bv;
    __syncthreads();
    f16x8 a0 = *(const f16x8*)(As + (mbase + l16)      * 40 + lk);
    f16x8 a1 = *(const f16x8*)(As + (mbase + 16 + l16) * 40 + lk);
    f16x8 b0 = *(const f16x8*)(Bs + (nbase + l16)      * 40 + lk);
    f16x8 b1 = *(const f16x8*)(Bs + (nbase + 16 + l16) * 40 + lk);
    acc00 = __builtin_amdgcn_mfma_f32_16x16x32_f16(a0, b0, acc00, 0, 0, 0);
    acc01 = __builtin_amdgcn_mfma_f32_16x16x32_f16(a0, b1, acc01, 0, 0, 0);
    acc10 = __builtin_amdgcn_mfma_f32_16x16x32_f16(a1, b0, acc10, 0, 0, 0);
    acc11 = __builtin_amdgcn_mfma_f32_16x16x32_f16(a1, b1, acc11, 0, 0, 0);
  }

  const int rr = (lane >> 4) * 4;
#pragma unroll
  for (int r = 0; r < 4; r++) {
    C[(size_t)(bm + mbase +      rr + r) * N + bn + nbase +      l16] = acc00[r];
    C[(size_t)(bm + mbase +      rr + r) * N + bn + nbase + 16 + l16] = acc01[r];
    C[(size_t)(bm + mbase + 16 + rr + r) * N + bn + nbase +      l16] = acc10[r];
    C[(size_t)(bm + mbase + 16 + rr + r) * N + bn + nbase + 16 + l16] = acc11[r];
  }
}

// ---------------------------------------------------------------------------
// f32 [K][N] -> f16 [N][K] transpose-convert.
// ---------------------------------------------------------------------------
__global__ __launch_bounds__(256) void conv_T_f16(
    const float* __restrict__ src, f16* __restrict__ dst, int K, int N)
{
  __shared__ float tile[32][33];
  const int tj = blockIdx.x;
  const int ti = blockIdx.y;
  const int t = threadIdx.x;
  for (int idx = t; idx < 1024; idx += 256) {
    int r = idx >> 5, c = idx & 31;
    tile[r][c] = src[(size_t)(ti * 32 + r) * N + tj * 32 + c];
  }
  __syncthreads();
  for (int idx = t; idx < 1024; idx += 256) {
    int r = idx >> 5, c = idx & 31;
    dst[(size_t)(tj * 32 + r) * K + ti * 32 + c] = (f16)tile[c][r];
  }
}

// ---------------------------------------------------------------------------
// f32 [K][N] cols [n0,n0+32*gridDim.x) -> split f16 hi/lo [NC][K] transpose.
// ---------------------------------------------------------------------------
__global__ __launch_bounds__(256) void conv_T_split(
    const float* __restrict__ src, f16* __restrict__ hi, f16* __restrict__ lo,
    int K, int N, int n0)
{
  __shared__ float tile[32][33];
  const int tj = blockIdx.x;
  const int ti = blockIdx.y;
  const int t = threadIdx.x;
  for (int idx = t; idx < 1024; idx += 256) {
    int r = idx >> 5, c = idx & 31;
    tile[r][c] = src[(size_t)(ti * 32 + r) * N + n0 + tj * 32 + c];
  }
  __syncthreads();
  for (int idx = t; idx < 1024; idx += 256) {
    int r = idx >> 5, c = idx & 31;
    float x = tile[c][r];
    f16 h = (f16)x;
    hi[(size_t)(tj * 32 + r) * K + ti * 32 + c] = h;
    lo[(size_t)(tj * 32 + r) * K + ti * 32 + c] = (f16)(x - (float)h);
  }
}

// ---------------------------------------------------------------------------
// f32 -> (f16 hi, f16 lo) split, row-major.  hi = rne(x); lo = rne(x - hi).
// ---------------------------------------------------------------------------
__global__ __launch_bounds__(256) void split_f16(
    const float* __restrict__ src, f16* __restrict__ hi, f16* __restrict__ lo,
    int n4)
{
  int i = blockIdx.x * 256 + threadIdx.x;
  if (i >= n4) return;
  float4 v = ((const float4*)src)[i];
  float vv[4] = {v.x, v.y, v.z, v.w};
  f16x4 h, l;
#pragma unroll
  for (int j = 0; j < 4; j++) {
    f16 hh = (f16)vv[j];
    h[j] = hh;
    l[j] = (f16)(vv[j] - (float)hh);
  }
  ((f16x4*)hi)[i] = h;
  ((f16x4*)lo)[i] = l;
}

// ---------------------------------------------------------------------------
// Attention pass 1: softmax denominators L[q] via split-f16 32x32x16 MFMA.
// 1-D grid, kvh-pinned: bid%8 = kvh -> all blocks sharing a K strip land on
// one XCD (L2-resident K).  Big-q blocks first (low bid).
// ---------------------------------------------------------------------------
__global__ __launch_bounds__(256) void attn_l(
    const f16* __restrict__ Qh, const f16* __restrict__ Ql,
    const f16* __restrict__ Kh, const f16* __restrict__ Kl,
    float* __restrict__ Lrow)
{
  __shared__ __align__(16) f16 Khs[32 * 136];
  __shared__ __align__(16) f16 Kls[32 * 136];
  const int t    = threadIdx.x;
  const int lane = t & 63;
  const int wave = t >> 6;
  const int l31  = lane & 31;
  const int gp   = lane >> 5;
  const int bid  = (int)blockIdx.x;            // 512 blocks
  const int kvh  = bid & 7;
  const int h    = kvh * 4 + ((bid >> 3) & 3);
  const int q0   = (15 - (bid >> 5)) << 7;     // big q first
  const int qw   = q0 + wave * 32;
  const int qg   = qw + l31;

  f16x8 qhf[8], qlf[8];
  {
    const f16* qp  = Qh + (size_t)qg * HIDDEN + h * HEAD_DIM + 8 * gp;
    const f16* qp2 = Ql + (size_t)qg * HIDDEN + h * HEAD_DIM + 8 * gp;
#pragma unroll
    for (int c = 0; c < 8; c++) {
      qhf[c] = *(const f16x8*)(qp  + c * 16);
      qlf[c] = *(const f16x8*)(qp2 + c * 16);
    }
  }

  float Lacc = 0.f;
  const int ntiles = (q0 >> 5) + 4;
  for (int kt = 0; kt < ntiles; kt++) {
    const int k0 = kt << 5;
    __syncthreads();
    for (int i = t; i < 512; i += 256) {
      int r = i >> 4, c = i & 15;
      size_t g = (size_t)(k0 + r) * (N_KV * HEAD_DIM) + kvh * HEAD_DIM + c * 8;
      *(f16x8*)(Khs + r * 136 + c * 8) = *(const f16x8*)(Kh + g);
      *(f16x8*)(Kls + r * 136 + c * 8) = *(const f16x8*)(Kl + g);
    }
    __syncthreads();
    if (k0 > qw + 31) continue;   // after both barriers: barrier counts uniform

    f32x16 acc;
#pragma unroll
    for (int i = 0; i < 16; i++) acc[i] = 0.f;
#pragma unroll
    for (int c = 0; c < 8; c++) {
      f16x8 ah = *(const f16x8*)(Khs + l31 * 136 + c * 16 + 8 * gp);
      f16x8 al = *(const f16x8*)(Kls + l31 * 136 + c * 16 + 8 * gp);
      acc = __builtin_amdgcn_mfma_f32_32x32x16_f16(ah, qhf[c], acc, 0, 0, 0);
      acc = __builtin_amdgcn_mfma_f32_32x32x16_f16(ah, qlf[c], acc, 0, 0, 0);
      acc = __builtin_amdgcn_mfma_f32_32x32x16_f16(al, qhf[c], acc, 0, 0, 0);
    }
    float ws = 0.f;
#pragma unroll
    for (int r = 0; r < 16; r++) {
      int kg = k0 + (r & 3) + 8 * (r >> 2) + 4 * gp;
      float e = exp2f(acc[r] * C2EXP);
      ws += (kg <= qg) ? e : 0.f;
    }
    Lacc += ws;
  }

  float tot = Lacc + __shfl_xor(Lacc, 32);
  if (lane < 32) Lrow[h * S_LEN + qw + lane] = tot;
}

// ---------------------------------------------------------------------------
// Attention pass 2: O = softmax(QK^T) V via MFMA.  Same kvh-pinned 1-D grid.
// ---------------------------------------------------------------------------
__global__ __launch_bounds__(256) void attn_o(
    const f16* __restrict__ Qh, const f16* __restrict__ Kh,
    const f16* __restrict__ Vt, const float* __restrict__ Lrow,
    f16* __restrict__ attnb)
{
  __shared__ __align__(16) f16 Khs[32 * 136];
  const int t    = threadIdx.x;
  const int lane = t & 63;
  const int wave = t >> 6;
  const int l31  = lane & 31;
  const int gp   = lane >> 5;
  const int bid  = (int)blockIdx.x;            // 512 blocks
  const int kvh  = bid & 7;
  const int h    = kvh * 4 + ((bid >> 3) & 3);
  const int q0   = (15 - (bid >> 5)) << 7;     // big q first
  const int qw   = q0 + wave * 32;
  const int qg   = qw + l31;

  f16x8 qhf[8];
  {
    const f16* qp = Qh + (size_t)qg * HIDDEN + h * HEAD_DIM + 8 * gp;
#pragma unroll
    for (int c = 0; c < 8; c++) qhf[c] = *(const f16x8*)(qp + c * 16);
  }
  const float iL = 1.0f / Lrow[h * S_LEN + qg];

  f32x16 oacc[4];
#pragma unroll
  for (int m = 0; m < 4; m++)
#pragma unroll
    for (int i = 0; i < 16; i++) oacc[m][i] = 0.f;

  const int ntiles = (q0 >> 5) + 4;
  for (int kt = 0; kt < ntiles; kt++) {
    const int k0 = kt << 5;
    __syncthreads();
    for (int i = t; i < 512; i += 256) {
      int r = i >> 4, c = i & 15;
      size_t g = (size_t)(k0 + r) * (N_KV * HEAD_DIM) + kvh * HEAD_DIM + c * 8;
      *(f16x8*)(Khs + r * 136 + c * 8) = *(const f16x8*)(Kh + g);
    }
    __syncthreads();
    if (k0 > qw + 31) continue;

    f32x16 acc;
#pragma unroll
    for (int i = 0; i < 16; i++) acc[i] = 0.f;
#pragma unroll
    for (int c = 0; c < 8; c++) {
      f16x8 ah = *(const f16x8*)(Khs + l31 * 136 + c * 16 + 8 * gp);
      acc = __builtin_amdgcn_mfma_f32_32x32x16_f16(ah, qhf[c], acc, 0, 0, 0);
    }

    float wv[16];
#pragma unroll
    for (int r = 0; r < 16; r++) {
      int kg = k0 + (r & 3) + 8 * (r >> 2) + 4 * gp;
      wv[r] = (kg <= qg) ? exp2f(acc[r] * C2EXP) * iL : 0.f;
    }

    unsigned p[8], x[8];
#pragma unroll
    for (int j = 0; j < 8; j++)
      p[j] = __builtin_bit_cast(unsigned,
               __builtin_amdgcn_cvt_pkrtz(wv[2 * j], wv[2 * j + 1]));
#pragma unroll
    for (int j = 0; j < 8; j++)
      x[j] = (unsigned)__shfl_xor((int)p[j], 32);

    uint4v cc0, cc1;   // B-frag: row(q)=lane&31, k = gp*8 + j
    cc0[0] = gp ? x[2] : p[0]; cc0[1] = gp ? x[3] : p[1];
    cc0[2] = gp ? p[2] : x[0]; cc0[3] = gp ? p[3] : x[1];
    cc1[0] = gp ? x[6] : p[4]; cc1[1] = gp ? x[7] : p[5];
    cc1[2] = gp ? p[6] : x[4]; cc1[3] = gp ? p[7] : x[5];
    f16x8 pf0 = __builtin_bit_cast(f16x8, cc0);   // keys k0+0..15
    f16x8 pf1 = __builtin_bit_cast(f16x8, cc1);   // keys k0+16..31

#pragma unroll
    for (int mt = 0; mt < 4; mt++) {
      const f16* vp = Vt + (size_t)(kvh * HEAD_DIM + mt * 32 + l31) * S_LEN
                         + k0 + 8 * gp;
      f16x8 v0 = *(const f16x8*)(vp);
      f16x8 v1 = *(const f16x8*)(vp + 16);
      oacc[mt] = __builtin_amdgcn_mfma_f32_32x32x16_f16(v0, pf0, oacc[mt], 0, 0, 0);
      oacc[mt] = __builtin_amdgcn_mfma_f32_32x32x16_f16(v1, pf1, oacc[mt], 0, 0, 0);
    }
  }

  f16* ob = attnb + (size_t)qg * HIDDEN + h * HEAD_DIM;
#pragma unroll
  for (int mt = 0; mt < 4; mt++)
#pragma unroll
    for (int rq = 0; rq < 4; rq++) {
      int d = mt * 32 + 8 * rq + 4 * gp;
      f16x4 o;
      o[0] = (f16)oacc[mt][rq * 4 + 0];
      o[1] = (f16)oacc[mt][rq * 4 + 1];
      o[2] = (f16)oacc[mt][rq * 4 + 2];
      o[3] = (f16)oacc[mt][rq * 4 + 3];
      *(f16x4*)(ob + d) = o;
    }
}

// ---------------------------------------------------------------------------
// Attention pass 3: cs[h][key] = sum_q w[q,key]  (mask-critical, split-exact).
// RESTRUCTURED for memory traffic: block = 128 keys (4 waves x 32), each wave
// owns its 32-key strip and runs the FULL causal q-loop (stride 32) -> the 4
// waves stream the SAME Q rows (~3-iter skew) => 1 fetch/block not 4, and
// grid-x shrinks 58->15.  1-D grid bid = kbIdx*32 + h => bid%8 = h%8: all
// key-blocks of a head pinned to one XCD (head's Q strip L2-resident).
// Per-wave inner body identical to the verified round-1/2/4 kernel.
// Exactly one (block,wave) per key; one atomic per key.
// ---------------------------------------------------------------------------
__global__ __launch_bounds__(256) void attn_cs(
    const f16* __restrict__ Qh, const f16* __restrict__ Ql,
    const f16* __restrict__ Kh, const f16* __restrict__ Kl,
    const float* __restrict__ Lrow, float* __restrict__ cs)
{
  const int t    = threadIdx.x;
  const int lane = t & 63;
  const int wave = t >> 6;
  const int l31  = lane & 31;
  const int gp   = lane >> 5;
  const int bid  = (int)blockIdx.x;        // 15*32 = 480 blocks
  const int h    = bid & 31;               // bid%8 = h%8 -> XCD pin per head
  const int kvh  = h >> 2;
  const int kb   = ((bid >> 5) << 7) + wave * 32;   // this wave's 32 keys

  f16x8 kah[8], kal[8];
  {
    const f16* kp  = Kh + (size_t)(kb + l31) * (N_KV * HEAD_DIM) + kvh * HEAD_DIM + 8 * gp;
    const f16* kp2 = Kl + (size_t)(kb + l31) * (N_KV * HEAD_DIM) + kvh * HEAD_DIM + 8 * gp;
#pragma unroll
    for (int c = 0; c < 8; c++) {
      kah[c] = *(const f16x8*)(kp  + c * 16);
      kal[c] = *(const f16x8*)(kp2 + c * 16);
    }
  }

  float csa[16];
#pragma unroll
  for (int r = 0; r < 16; r++) csa[r] = 0.f;

  for (int q0 = kb; q0 < S_LEN; q0 += 32) {   // kb is a multiple of 32
    const int qg = q0 + l31;
    const float iL = 1.0f / Lrow[h * S_LEN + qg];
    const f16* qp  = Qh + (size_t)qg * HIDDEN + h * HEAD_DIM + 8 * gp;
    const f16* qp2 = Ql + (size_t)qg * HIDDEN + h * HEAD_DIM + 8 * gp;

    f32x16 acc;
#pragma unroll
    for (int i = 0; i < 16; i++) acc[i] = 0.f;
#pragma unroll
    for (int c = 0; c < 8; c++) {
      f16x8 bh = *(const f16x8*)(qp  + c * 16);
      f16x8 bl = *(const f16x8*)(qp2 + c * 16);
      acc = __builtin_amdgcn_mfma_f32_32x32x16_f16(kah[c], bh, acc, 0, 0, 0);
      acc = __builtin_amdgcn_mfma_f32_32x32x16_f16(kah[c], bl, acc, 0, 0, 0);
      acc = __builtin_amdgcn_mfma_f32_32x32x16_f16(kal[c], bh, acc, 0, 0, 0);
    }
#pragma unroll
    for (int r = 0; r < 16; r++) {
      int kg = kb + (r & 3) + 8 * (r >> 2) + 4 * gp;
      csa[r] += (kg <= qg) ? exp2f(acc[r] * C2EXP) * iL : 0.f;
    }
  }

#pragma unroll
  for (int st = 1; st < 32; st <<= 1)
#pragma unroll
    for (int r = 0; r < 16; r++) csa[r] += __shfl_xor(csa[r], st);

  if (l31 == 0) {
#pragma unroll
    for (int r = 0; r < 16; r++)
      atomicAdd(&cs[h * S_LEN + kb + (r & 3) + 8 * (r >> 2) + 4 * gp], csa[r]);
  }
}

// ---------------------------------------------------------------------------
// Exact top-HEAVY_K via O(n^2) ranking -- one candidate per thread, 9 x 32
// blocks.  Identical comparison + tie-break (jj < i) -> mask bit-identical.
// (verified round 4)
// ---------------------------------------------------------------------------
__global__ __launch_bounds__(256) void topk_mask_kernel(
    const float* __restrict__ cs, float* __restrict__ maskout)
{
  const int h = blockIdx.y;
  __shared__ float sv[NCAND];
  const float* s = cs + h * S_LEN;
  const int t = threadIdx.x;
  for (int i = t; i < NCAND; i += 256) sv[i] = s[i];
  __syncthreads();

  const int i = blockIdx.x * 256 + t;
  if (i >= MASK_LEN) return;
  float val = (i >= NCAND + 1) ? 1.0f : 0.0f;
  if (i < NCAND) {
    const float v = sv[i];
    int cnt = 0;
#pragma unroll 4
    for (int jj = 0; jj < NCAND; jj++) {
      float x = sv[jj];
      cnt += ((x > v) || (x == v && jj < i)) ? 1 : 0;
    }
    val = (cnt < HEAVY_K) ? 1.0f : 0.0f;
  }
  maskout[h * MASK_LEN + i] = val;
}

__global__ __launch_bounds__(256) void zero_kernel(float* __restrict__ p, int n)
{
  int i = blockIdx.x * 256 + threadIdx.x;
  if (i < n) p[i] = 0.f;
}

// ---------------------------------------------------------------------------
// In-place RoPE.
// ---------------------------------------------------------------------------
__global__ __launch_bounds__(256) void rope_kernel(
    float* __restrict__ buf, const int* __restrict__ pos_ids, int ncols)
{
  __shared__ float invf_s[64];
  if (threadIdx.x < 64)
    invf_s[threadIdx.x] =
        (float)(1.0 / pow(10000.0, (double)threadIdx.x * (1.0 / 64.0)));
  __syncthreads();

  int i = blockIdx.x * 256 + threadIdx.x;
  int half = ncols >> 1;
  int total = S_LEN * half;
  if (i >= total) return;
  int row = i / half;
  int rem = i - row * half;
  int hh = rem >> 6;
  int d  = rem & 63;
  float p = (float)pos_ids[row];
  float ang = p * invf_s[d];
  float c = cosf(ang);
  float s = sinf(ang);
  float* base = buf + (size_t)row * ncols + hh * HEAD_DIM;
  float x0 = base[d];
  float x1 = base[d + 64];
  base[d]      = x0 * c - x1 * s;
  base[d + 64] = x1 * c + x0 * s;
}

// ---------------------------------------------------------------------------
// Workspace layout (109,576,192 B total -- unchanged from round 2).
// ---------------------------------------------------------------------------
extern "C" void kernel_launch(void* const* d_in, const int* in_sizes, int n_in,
                              void* d_out, int out_size, void* d_ws, size_t ws_size,
                              hipStream_t stream)
{
  (void)in_sizes; (void)n_in; (void)out_size; (void)ws_size;
  const float* hs = (const float*)d_in[0];
  const int*  pos = (const int*)d_in[1];
  const float* Wq = (const float*)d_in[2];
  const float* Wk = (const float*)d_in[3];
  const float* Wv = (const float*)d_in[4];
  const float* Wo = (const float*)d_in[5];
  float* out = (float*)d_out;

  char* w = (char*)d_ws;
  float* Qraw  = (float*)(w);                          // 32 MiB
  f16*   WoT   = (f16*)  (w);                          // overlays Qraw
  f16*   WqTl  = (f16*)  (w + 33554432);               // 16 MiB (32..48)
  float* Kraw  = (float*)(w + 33554432);               // 8 MiB, after Wq gemms
  f16*   Vt    = (f16*)  (w + 33554432);               // 4 MiB, after K split
  float* Vraw  = (float*)(w + 41943040);               // 8 MiB
  float* Lrow  = (float*)(w + 50331648);
  float* cs    = (float*)(w + 50593792);
  f16*   hsh   = (f16*)  (w + 50855936);               // 16 MiB (48.5..64.5)
  f16*   attnb = (f16*)  (w + 50855936);               // overlays hsh
  f16*   hsl   = (f16*)  (w + 67633152);               // 16 MiB (64.5..80.5)
  f16*   Qh    = (f16*)  (w + 67633152);               // overlays hsl
  f16*   WqTh  = (f16*)  (w + 84410368);               // 16 MiB (80.5..96.5)
  f16*   WkTh  = (f16*)  (w + 84410368);               //  8 MiB
  f16*   WvT   = (f16*)  (w + 84410368);               //  8 MiB
  f16*   Ql    = (f16*)  (w + 84410368);               // overlays, after V gemm
  f16*   WkTl  = (f16*)  (w + 92798976);               //  8 MiB (88.5..96.5)
  f16*   Kh    = (f16*)  (w + 101187584);              //  4 MiB
  f16*   Kl    = (f16*)  (w + 105381888);              //  4 MiB -> end 104.5 MiB

  dim3 blk(256);

  // --- split hidden_states once (A-operand for Q, K, V gemms) ---
  split_f16<<<(S_LEN * HIDDEN / 4 + 255) / 256, blk, 0, stream>>>(
      hs, hsh, hsl, S_LEN * HIDDEN / 4);

  // --- Q = hs @ Wq, split-exact, two N=2048 chunks ---
  conv_T_split<<<dim3(2048 / 32, HIDDEN / 32), blk, 0, stream>>>(
      Wq, WqTh, WqTl, HIDDEN, HIDDEN, 0);
  gemm_split<<<dim3(2048 / 128, S_LEN / 128), blk, 0, stream>>>(
      hsh, hsl, WqTh, WqTl, Qraw, HIDDEN, HIDDEN);
  conv_T_split<<<dim3(2048 / 32, HIDDEN / 32), blk, 0, stream>>>(
      Wq, WqTh, WqTl, HIDDEN, HIDDEN, 2048);
  gemm_split<<<dim3(2048 / 128, S_LEN / 128), blk, 0, stream>>>(
      hsh, hsl, WqTh, WqTl, Qraw + 2048, HIDDEN, HIDDEN);

  // --- K = hs @ Wk, split-exact ---
  conv_T_split<<<dim3((N_KV * HEAD_DIM) / 32, HIDDEN / 32), blk, 0, stream>>>(
      Wk, WkTh, WkTl, HIDDEN, N_KV * HEAD_DIM, 0);
  gemm_split<<<dim3((N_KV * HEAD_DIM) / 128, S_LEN / 128), blk, 0, stream>>>(
      hsh, hsl, WkTh, WkTl, Kraw, HIDDEN, N_KV * HEAD_DIM);

  // --- V = hs @ Wv, f16 (tolerance path) ---
  conv_T_f16<<<dim3((N_KV * HEAD_DIM) / 32, HIDDEN / 32), blk, 0, stream>>>(
      Wv, WvT, HIDDEN, N_KV * HEAD_DIM);
  gemm_f16<<<dim3((N_KV * HEAD_DIM) / 64, S_LEN / 64), blk, 0, stream>>>(
      hsh, WvT, Vraw, S_LEN, N_KV * HEAD_DIM, HIDDEN);

  // --- RoPE (f32, in place) ---
  rope_kernel<<<(S_LEN * (HIDDEN / 2) + 255) / 256, blk, 0, stream>>>(
      Qraw, pos, HIDDEN);
  rope_kernel<<<(S_LEN * (N_KV * HEAD_DIM / 2) + 255) / 256, blk, 0, stream>>>(
      Kraw, pos, N_KV * HEAD_DIM);

  // --- splits for attention ---
  split_f16<<<(S_LEN * HIDDEN / 4 + 255) / 256, blk, 0, stream>>>(
      Qraw, Qh, Ql, S_LEN * HIDDEN / 4);
  split_f16<<<(S_LEN * N_KV * HEAD_DIM / 4 + 255) / 256, blk, 0, stream>>>(
      Kraw, Kh, Kl, S_LEN * N_KV * HEAD_DIM / 4);
  conv_T_f16<<<dim3((N_KV * HEAD_DIM) / 32, S_LEN / 32), blk, 0, stream>>>(
      Vraw, Vt, S_LEN, N_KV * HEAD_DIM);
  conv_T_f16<<<dim3(HIDDEN / 32, HIDDEN / 32), blk, 0, stream>>>(
      Wo, WoT, HIDDEN, HIDDEN);   // Qraw dead (split done) -> safe overlay

  // --- attention (1-D XCD-pinned grids) ---
  attn_l<<<dim3((S_LEN / 128) * N_HEADS), blk, 0, stream>>>(
      Qh, Ql, Kh, Kl, Lrow);
  attn_o<<<dim3((S_LEN / 128) * N_HEADS), blk, 0, stream>>>(
      Qh, Kh, Vt, Lrow, attnb);
  zero_kernel<<<(N_HEADS * S_LEN + 255) / 256, blk, 0, stream>>>(
      cs, N_HEADS * S_LEN);
  attn_cs<<<dim3(((NCAND + 127) / 128) * N_HEADS), blk, 0, stream>>>(
      Qh, Ql, Kh, Kl, Lrow, cs);
  topk_mask_kernel<<<dim3((MASK_LEN + 255) / 256, N_HEADS), blk, 0, stream>>>(
      cs, out + (size_t)S_LEN * HIDDEN);

  // --- output projection (128x128 tile) ---
  gemm_f16_128<<<dim3(HIDDEN / 128, S_LEN / 128), blk, 0, stream>>>(
      attnb, WoT, out, HIDDEN, HIDDEN);
}

// Round 6
// 1433.201 us; speedup vs baseline: 2.5489x; 1.0323x over previous
//
#include <hip/hip_runtime.h>
#include <math.h>

#define S_LEN   2048
#define HIDDEN  4096
#define N_HEADS 32
#define N_KV    8
#define HEAD_DIM 128
#define NCAND   1844      // S - RECENT
#define HEAVY_K 819
#define MASK_LEN 2049     // S + 1

typedef _Float16 f16;
using f32x4  = __attribute__((ext_vector_type(4))) float;
using f32x16 = __attribute__((ext_vector_type(16))) float;
using f16x8  = __attribute__((ext_vector_type(8))) _Float16;
using f16x4  = __attribute__((ext_vector_type(4))) _Float16;
using f16x2  = __attribute__((ext_vector_type(2))) _Float16;
using uint4v = __attribute__((ext_vector_type(4))) unsigned int;

// exp(s*SCALE) == exp2(s*C2); single fused constant, used identically in all
// three attention passes so L, w, cs stay mutually consistent.
#define C2EXP 0.12751879523486166f   // (1/sqrt(128)) * log2(e)

// ---------------------------------------------------------------------------
// Split-f16 MFMA GEMM (mask-critical path):
// C(f32)[M][ldc] = (Ah+Al)[M][K] * (Bh+Bl)[N][K]^T  via 3-term f16 MFMA
//   C ~= Ah*Bh + Ah*Bl + Al*Bh   (dropped Al*Bl term <= 2^-44 relative)
// Tile 128x128, BK=32, 4 waves x (4x4 of 16x16x32) = 48 MFMA : 16 ds_read
// per k-step.  LDS stride 40 halfs (80B: 16B-aligned rows, 2-way banks max).
// (verified rounds 1-5)
// ---------------------------------------------------------------------------
__global__ __launch_bounds__(256) void gemm_split(
    const f16* __restrict__ Ah, const f16* __restrict__ Al,
    const f16* __restrict__ Bh, const f16* __restrict__ Bl,
    float* __restrict__ C, int K, int ldc)
{
  __shared__ __align__(16) f16 Ash[128 * 40];
  __shared__ __align__(16) f16 Asl[128 * 40];
  __shared__ __align__(16) f16 Bsh[128 * 40];
  __shared__ __align__(16) f16 Bsl[128 * 40];
  const int t    = threadIdx.x;
  const int lane = t & 63;
  const int wave = t >> 6;
  const int mbase = (wave >> 1) * 64;
  const int nbase = (wave & 1) * 64;
  const int bm = blockIdx.y << 7;
  const int bn = blockIdx.x << 7;
  const int srow = t >> 1;          // 0..127
  const int scol = (t & 1) * 16;    // 0 | 16
  const int l16 = lane & 15;
  const int lk  = (lane >> 4) * 8;

  f32x4 acc[4][4];
#pragma unroll
  for (int i = 0; i < 4; i++)
#pragma unroll
    for (int j = 0; j < 4; j++) acc[i][j] = (f32x4){0.f, 0.f, 0.f, 0.f};

  for (int k0 = 0; k0 < K; k0 += 32) {
    const f16* gah = Ah + (size_t)(bm + srow) * K + k0 + scol;
    const f16* gal = Al + (size_t)(bm + srow) * K + k0 + scol;
    const f16* gbh = Bh + (size_t)(bn + srow) * K + k0 + scol;
    const f16* gbl = Bl + (size_t)(bn + srow) * K + k0 + scol;
    f16x8 vah0 = *(const f16x8*)(gah);
    f16x8 vah1 = *(const f16x8*)(gah + 8);
    f16x8 val0 = *(const f16x8*)(gal);
    f16x8 val1 = *(const f16x8*)(gal + 8);
    f16x8 vbh0 = *(const f16x8*)(gbh);
    f16x8 vbh1 = *(const f16x8*)(gbh + 8);
    f16x8 vbl0 = *(const f16x8*)(gbl);
    f16x8 vbl1 = *(const f16x8*)(gbl + 8);
    __syncthreads();
    *(f16x8*)(Ash + srow * 40 + scol)     = vah0;
    *(f16x8*)(Ash + srow * 40 + scol + 8) = vah1;
    *(f16x8*)(Asl + srow * 40 + scol)     = val0;
    *(f16x8*)(Asl + srow * 40 + scol + 8) = val1;
    *(f16x8*)(Bsh + srow * 40 + scol)     = vbh0;
    *(f16x8*)(Bsh + srow * 40 + scol + 8) = vbh1;
    *(f16x8*)(Bsl + srow * 40 + scol)     = vbl0;
    *(f16x8*)(Bsl + srow * 40 + scol + 8) = vbl1;
    __syncthreads();

    f16x8 afh[4], afl[4], bfh[4], bfl[4];
#pragma unroll
    for (int i = 0; i < 4; i++) {
      afh[i] = *(const f16x8*)(Ash + (mbase + i * 16 + l16) * 40 + lk);
      afl[i] = *(const f16x8*)(Asl + (mbase + i * 16 + l16) * 40 + lk);
      bfh[i] = *(const f16x8*)(Bsh + (nbase + i * 16 + l16) * 40 + lk);
      bfl[i] = *(const f16x8*)(Bsl + (nbase + i * 16 + l16) * 40 + lk);
    }
#pragma unroll
    for (int i = 0; i < 4; i++)
#pragma unroll
      for (int j = 0; j < 4; j++) {
        acc[i][j] = __builtin_amdgcn_mfma_f32_16x16x32_f16(afh[i], bfh[j], acc[i][j], 0, 0, 0);
        acc[i][j] = __builtin_amdgcn_mfma_f32_16x16x32_f16(afh[i], bfl[j], acc[i][j], 0, 0, 0);
        acc[i][j] = __builtin_amdgcn_mfma_f32_16x16x32_f16(afl[i], bfh[j], acc[i][j], 0, 0, 0);
      }
  }

  const int rr = (lane >> 4) * 4;
#pragma unroll
  for (int i = 0; i < 4; i++)
#pragma unroll
    for (int j = 0; j < 4; j++)
#pragma unroll
      for (int r = 0; r < 4; r++)
        C[(size_t)(bm + mbase + i * 16 + rr + r) * ldc + bn + nbase + j * 16 + l16]
            = acc[i][j][r];
}

// ---------------------------------------------------------------------------
// f16 MFMA GEMM, 128x128 tile (tolerance path, Wo): same skeleton as
// gemm_split with the lo-terms deleted -> 16 MFMA : 8 ds_read per k-step.
// C(f32)[M][ldc] = A[M][K] * BT[N][K]^T.  (verified rounds 4-5)
// ---------------------------------------------------------------------------
__global__ __launch_bounds__(256) void gemm_f16_128(
    const f16* __restrict__ A, const f16* __restrict__ BT,
    float* __restrict__ C, int K, int ldc)
{
  __shared__ __align__(16) f16 As[128 * 40];
  __shared__ __align__(16) f16 Bs[128 * 40];
  const int t    = threadIdx.x;
  const int lane = t & 63;
  const int wave = t >> 6;
  const int mbase = (wave >> 1) * 64;
  const int nbase = (wave & 1) * 64;
  const int bm = blockIdx.y << 7;
  const int bn = blockIdx.x << 7;
  const int srow = t >> 1;
  const int scol = (t & 1) * 16;
  const int l16 = lane & 15;
  const int lk  = (lane >> 4) * 8;

  f32x4 acc[4][4];
#pragma unroll
  for (int i = 0; i < 4; i++)
#pragma unroll
    for (int j = 0; j < 4; j++) acc[i][j] = (f32x4){0.f, 0.f, 0.f, 0.f};

  for (int k0 = 0; k0 < K; k0 += 32) {
    const f16* ga = A  + (size_t)(bm + srow) * K + k0 + scol;
    const f16* gb = BT + (size_t)(bn + srow) * K + k0 + scol;
    f16x8 va0 = *(const f16x8*)(ga);
    f16x8 va1 = *(const f16x8*)(ga + 8);
    f16x8 vb0 = *(const f16x8*)(gb);
    f16x8 vb1 = *(const f16x8*)(gb + 8);
    __syncthreads();
    *(f16x8*)(As + srow * 40 + scol)     = va0;
    *(f16x8*)(As + srow * 40 + scol + 8) = va1;
    *(f16x8*)(Bs + srow * 40 + scol)     = vb0;
    *(f16x8*)(Bs + srow * 40 + scol + 8) = vb1;
    __syncthreads();

    f16x8 af[4], bf[4];
#pragma unroll
    for (int i = 0; i < 4; i++) {
      af[i] = *(const f16x8*)(As + (mbase + i * 16 + l16) * 40 + lk);
      bf[i] = *(const f16x8*)(Bs + (nbase + i * 16 + l16) * 40 + lk);
    }
#pragma unroll
    for (int i = 0; i < 4; i++)
#pragma unroll
      for (int j = 0; j < 4; j++)
        acc[i][j] = __builtin_amdgcn_mfma_f32_16x16x32_f16(af[i], bf[j], acc[i][j], 0, 0, 0);
  }

  const int rr = (lane >> 4) * 4;
#pragma unroll
  for (int i = 0; i < 4; i++)
#pragma unroll
    for (int j = 0; j < 4; j++)
#pragma unroll
      for (int r = 0; r < 4; r++)
        C[(size_t)(bm + mbase + i * 16 + rr + r) * ldc + bn + nbase + j * 16 + l16]
            = acc[i][j][r];
}

// ---------------------------------------------------------------------------
// f16 MFMA GEMM 64x64 (V projection: N=1024 wants block count).
// ---------------------------------------------------------------------------
__global__ __launch_bounds__(256) void gemm_f16(
    const f16* __restrict__ A, const f16* __restrict__ BT,
    float* __restrict__ C, int M, int N, int K)
{
  __shared__ __align__(16) f16 As[64 * 40];
  __shared__ __align__(16) f16 Bs[64 * 40];
  const int t    = threadIdx.x;
  const int lane = t & 63;
  const int wave = t >> 6;
  const int mbase = (wave >> 1) * 32;
  const int nbase = (wave & 1) * 32;
  const int bm = blockIdx.y << 6;
  const int bn = blockIdx.x << 6;
  const int srow = t >> 2;
  const int scol = (t & 3) * 8;
  const int l16 = lane & 15;
  const int lk  = (lane >> 4) * 8;

  f32x4 acc00 = {0.f,0.f,0.f,0.f}, acc01 = {0.f,0.f,0.f,0.f};
  f32x4 acc10 = {0.f,0.f,0.f,0.f}, acc11 = {0.f,0.f,0.f,0.f};

  for (int k0 = 0; k0 < K; k0 += 32) {
    f16x8 av = *(const f16x8*)(A  + (size_t)(bm + srow) * K + k0 + scol);
    f16x8 bv = *(const f16x8*)(BT + (size_t)(bn + srow) * K + k0 + scol);
    __syncthreads();
    *(f16x8*)(As + srow * 40 + scol) = av;
    *(f16x8*)(Bs + srow * 40 + scol) = bv;
    __syncthreads();
    f16x8 a0 = *(const f16x8*)(As + (mbase + l16)      * 40 + lk);
    f16x8 a1 = *(const f16x8*)(As + (mbase + 16 + l16) * 40 + lk);
    f16x8 b0 = *(const f16x8*)(Bs + (nbase + l16)      * 40 + lk);
    f16x8 b1 = *(const f16x8*)(Bs + (nbase + 16 + l16) * 40 + lk);
    acc00 = __builtin_amdgcn_mfma_f32_16x16x32_f16(a0, b0, acc00, 0, 0, 0);
    acc01 = __builtin_amdgcn_mfma_f32_16x16x32_f16(a0, b1, acc01, 0, 0, 0);
    acc10 = __builtin_amdgcn_mfma_f32_16x16x32_f16(a1, b0, acc10, 0, 0, 0);
    acc11 = __builtin_amdgcn_mfma_f32_16x16x32_f16(a1, b1, acc11, 0, 0, 0);
  }

  const int rr = (lane >> 4) * 4;
#pragma unroll
  for (int r = 0; r < 4; r++) {
    C[(size_t)(bm + mbase +      rr + r) * N + bn + nbase +      l16] = acc00[r];
    C[(size_t)(bm + mbase +      rr + r) * N + bn + nbase + 16 + l16] = acc01[r];
    C[(size_t)(bm + mbase + 16 + rr + r) * N + bn + nbase +      l16] = acc10[r];
    C[(size_t)(bm + mbase + 16 + rr + r) * N + bn + nbase + 16 + l16] = acc11[r];
  }
}

// ---------------------------------------------------------------------------
// f32 [K][N] -> f16 [N][K] transpose-convert.
// ---------------------------------------------------------------------------
__global__ __launch_bounds__(256) void conv_T_f16(
    const float* __restrict__ src, f16* __restrict__ dst, int K, int N)
{
  __shared__ float tile[32][33];
  const int tj = blockIdx.x;
  const int ti = blockIdx.y;
  const int t = threadIdx.x;
  for (int idx = t; idx < 1024; idx += 256) {
    int r = idx >> 5, c = idx & 31;
    tile[r][c] = src[(size_t)(ti * 32 + r) * N + tj * 32 + c];
  }
  __syncthreads();
  for (int idx = t; idx < 1024; idx += 256) {
    int r = idx >> 5, c = idx & 31;
    dst[(size_t)(tj * 32 + r) * K + ti * 32 + c] = (f16)tile[c][r];
  }
}

// ---------------------------------------------------------------------------
// f32 [K][N] cols [n0,n0+32*gridDim.x) -> split f16 hi/lo [NC][K] transpose.
// ---------------------------------------------------------------------------
__global__ __launch_bounds__(256) void conv_T_split(
    const float* __restrict__ src, f16* __restrict__ hi, f16* __restrict__ lo,
    int K, int N, int n0)
{
  __shared__ float tile[32][33];
  const int tj = blockIdx.x;
  const int ti = blockIdx.y;
  const int t = threadIdx.x;
  for (int idx = t; idx < 1024; idx += 256) {
    int r = idx >> 5, c = idx & 31;
    tile[r][c] = src[(size_t)(ti * 32 + r) * N + n0 + tj * 32 + c];
  }
  __syncthreads();
  for (int idx = t; idx < 1024; idx += 256) {
    int r = idx >> 5, c = idx & 31;
    float x = tile[c][r];
    f16 h = (f16)x;
    hi[(size_t)(tj * 32 + r) * K + ti * 32 + c] = h;
    lo[(size_t)(tj * 32 + r) * K + ti * 32 + c] = (f16)(x - (float)h);
  }
}

// ---------------------------------------------------------------------------
// f32 -> (f16 hi, f16 lo) split, row-major.  hi = rne(x); lo = rne(x - hi).
// ---------------------------------------------------------------------------
__global__ __launch_bounds__(256) void split_f16(
    const float* __restrict__ src, f16* __restrict__ hi, f16* __restrict__ lo,
    int n4)
{
  int i = blockIdx.x * 256 + threadIdx.x;
  if (i >= n4) return;
  float4 v = ((const float4*)src)[i];
  float vv[4] = {v.x, v.y, v.z, v.w};
  f16x4 h, l;
#pragma unroll
  for (int j = 0; j < 4; j++) {
    f16 hh = (f16)vv[j];
    h[j] = hh;
    l[j] = (f16)(vv[j] - (float)hh);
  }
  ((f16x4*)hi)[i] = h;
  ((f16x4*)lo)[i] = l;
}

// ---------------------------------------------------------------------------
// Attention pass 1: softmax denominators L[q] via split-f16 32x32x16 MFMA.
// 1-D grid, kvh-pinned: bid%8 = kvh -> all blocks sharing a K strip land on
// one XCD (L2-resident K).  Big-q blocks first (low bid).  (verified round 5)
// ---------------------------------------------------------------------------
__global__ __launch_bounds__(256) void attn_l(
    const f16* __restrict__ Qh, const f16* __restrict__ Ql,
    const f16* __restrict__ Kh, const f16* __restrict__ Kl,
    float* __restrict__ Lrow)
{
  __shared__ __align__(16) f16 Khs[32 * 136];
  __shared__ __align__(16) f16 Kls[32 * 136];
  const int t    = threadIdx.x;
  const int lane = t & 63;
  const int wave = t >> 6;
  const int l31  = lane & 31;
  const int gp   = lane >> 5;
  const int bid  = (int)blockIdx.x;            // 512 blocks
  const int kvh  = bid & 7;
  const int h    = kvh * 4 + ((bid >> 3) & 3);
  const int q0   = (15 - (bid >> 5)) << 7;     // big q first
  const int qw   = q0 + wave * 32;
  const int qg   = qw + l31;

  f16x8 qhf[8], qlf[8];
  {
    const f16* qp  = Qh + (size_t)qg * HIDDEN + h * HEAD_DIM + 8 * gp;
    const f16* qp2 = Ql + (size_t)qg * HIDDEN + h * HEAD_DIM + 8 * gp;
#pragma unroll
    for (int c = 0; c < 8; c++) {
      qhf[c] = *(const f16x8*)(qp  + c * 16);
      qlf[c] = *(const f16x8*)(qp2 + c * 16);
    }
  }

  float Lacc = 0.f;
  const int ntiles = (q0 >> 5) + 4;
  for (int kt = 0; kt < ntiles; kt++) {
    const int k0 = kt << 5;
    __syncthreads();
    for (int i = t; i < 512; i += 256) {
      int r = i >> 4, c = i & 15;
      size_t g = (size_t)(k0 + r) * (N_KV * HEAD_DIM) + kvh * HEAD_DIM + c * 8;
      *(f16x8*)(Khs + r * 136 + c * 8) = *(const f16x8*)(Kh + g);
      *(f16x8*)(Kls + r * 136 + c * 8) = *(const f16x8*)(Kl + g);
    }
    __syncthreads();
    if (k0 > qw + 31) continue;   // after both barriers: barrier counts uniform

    f32x16 acc;
#pragma unroll
    for (int i = 0; i < 16; i++) acc[i] = 0.f;
#pragma unroll
    for (int c = 0; c < 8; c++) {
      f16x8 ah = *(const f16x8*)(Khs + l31 * 136 + c * 16 + 8 * gp);
      f16x8 al = *(const f16x8*)(Kls + l31 * 136 + c * 16 + 8 * gp);
      acc = __builtin_amdgcn_mfma_f32_32x32x16_f16(ah, qhf[c], acc, 0, 0, 0);
      acc = __builtin_amdgcn_mfma_f32_32x32x16_f16(ah, qlf[c], acc, 0, 0, 0);
      acc = __builtin_amdgcn_mfma_f32_32x32x16_f16(al, qhf[c], acc, 0, 0, 0);
    }
    float ws = 0.f;
#pragma unroll
    for (int r = 0; r < 16; r++) {
      int kg = k0 + (r & 3) + 8 * (r >> 2) + 4 * gp;
      float e = exp2f(acc[r] * C2EXP);
      ws += (kg <= qg) ? e : 0.f;
    }
    Lacc += ws;
  }

  float tot = Lacc + __shfl_xor(Lacc, 32);
  if (lane < 32) Lrow[h * S_LEN + qw + lane] = tot;
}

// ---------------------------------------------------------------------------
// Attention pass 2: O = softmax(QK^T) V via MFMA.  Same kvh-pinned 1-D grid.
// (verified round 5)
// ---------------------------------------------------------------------------
__global__ __launch_bounds__(256) void attn_o(
    const f16* __restrict__ Qh, const f16* __restrict__ Kh,
    const f16* __restrict__ Vt, const float* __restrict__ Lrow,
    f16* __restrict__ attnb)
{
  __shared__ __align__(16) f16 Khs[32 * 136];
  const int t    = threadIdx.x;
  const int lane = t & 63;
  const int wave = t >> 6;
  const int l31  = lane & 31;
  const int gp   = lane >> 5;
  const int bid  = (int)blockIdx.x;            // 512 blocks
  const int kvh  = bid & 7;
  const int h    = kvh * 4 + ((bid >> 3) & 3);
  const int q0   = (15 - (bid >> 5)) << 7;     // big q first
  const int qw   = q0 + wave * 32;
  const int qg   = qw + l31;

  f16x8 qhf[8];
  {
    const f16* qp = Qh + (size_t)qg * HIDDEN + h * HEAD_DIM + 8 * gp;
#pragma unroll
    for (int c = 0; c < 8; c++) qhf[c] = *(const f16x8*)(qp + c * 16);
  }
  const float iL = 1.0f / Lrow[h * S_LEN + qg];

  f32x16 oacc[4];
#pragma unroll
  for (int m = 0; m < 4; m++)
#pragma unroll
    for (int i = 0; i < 16; i++) oacc[m][i] = 0.f;

  const int ntiles = (q0 >> 5) + 4;
  for (int kt = 0; kt < ntiles; kt++) {
    const int k0 = kt << 5;
    __syncthreads();
    for (int i = t; i < 512; i += 256) {
      int r = i >> 4, c = i & 15;
      size_t g = (size_t)(k0 + r) * (N_KV * HEAD_DIM) + kvh * HEAD_DIM + c * 8;
      *(f16x8*)(Khs + r * 136 + c * 8) = *(const f16x8*)(Kh + g);
    }
    __syncthreads();
    if (k0 > qw + 31) continue;

    f32x16 acc;
#pragma unroll
    for (int i = 0; i < 16; i++) acc[i] = 0.f;
#pragma unroll
    for (int c = 0; c < 8; c++) {
      f16x8 ah = *(const f16x8*)(Khs + l31 * 136 + c * 16 + 8 * gp);
      acc = __builtin_amdgcn_mfma_f32_32x32x16_f16(ah, qhf[c], acc, 0, 0, 0);
    }

    float wv[16];
#pragma unroll
    for (int r = 0; r < 16; r++) {
      int kg = k0 + (r & 3) + 8 * (r >> 2) + 4 * gp;
      wv[r] = (kg <= qg) ? exp2f(acc[r] * C2EXP) * iL : 0.f;
    }

    unsigned p[8], x[8];
#pragma unroll
    for (int j = 0; j < 8; j++)
      p[j] = __builtin_bit_cast(unsigned,
               __builtin_amdgcn_cvt_pkrtz(wv[2 * j], wv[2 * j + 1]));
#pragma unroll
    for (int j = 0; j < 8; j++)
      x[j] = (unsigned)__shfl_xor((int)p[j], 32);

    uint4v cc0, cc1;   // B-frag: row(q)=lane&31, k = gp*8 + j
    cc0[0] = gp ? x[2] : p[0]; cc0[1] = gp ? x[3] : p[1];
    cc0[2] = gp ? p[2] : x[0]; cc0[3] = gp ? p[3] : x[1];
    cc1[0] = gp ? x[6] : p[4]; cc1[1] = gp ? x[7] : p[5];
    cc1[2] = gp ? p[6] : x[4]; cc1[3] = gp ? p[7] : x[5];
    f16x8 pf0 = __builtin_bit_cast(f16x8, cc0);   // keys k0+0..15
    f16x8 pf1 = __builtin_bit_cast(f16x8, cc1);   // keys k0+16..31

#pragma unroll
    for (int mt = 0; mt < 4; mt++) {
      const f16* vp = Vt + (size_t)(kvh * HEAD_DIM + mt * 32 + l31) * S_LEN
                         + k0 + 8 * gp;
      f16x8 v0 = *(const f16x8*)(vp);
      f16x8 v1 = *(const f16x8*)(vp + 16);
      oacc[mt] = __builtin_amdgcn_mfma_f32_32x32x16_f16(v0, pf0, oacc[mt], 0, 0, 0);
      oacc[mt] = __builtin_amdgcn_mfma_f32_32x32x16_f16(v1, pf1, oacc[mt], 0, 0, 0);
    }
  }

  f16* ob = attnb + (size_t)qg * HIDDEN + h * HEAD_DIM;
#pragma unroll
  for (int mt = 0; mt < 4; mt++)
#pragma unroll
    for (int rq = 0; rq < 4; rq++) {
      int d = mt * 32 + 8 * rq + 4 * gp;
      f16x4 o;
      o[0] = (f16)oacc[mt][rq * 4 + 0];
      o[1] = (f16)oacc[mt][rq * 4 + 1];
      o[2] = (f16)oacc[mt][rq * 4 + 2];
      o[3] = (f16)oacc[mt][rq * 4 + 3];
      *(f16x4*)(ob + d) = o;
    }
}

// ---------------------------------------------------------------------------
// Attention pass 3: cs[h][key] = sum_q w[q,key]  (mask-critical, split-exact).
// v3, LATENCY-FOCUSED: round-5's v2 cut HBM 12x but stayed at 201us --
// occupancy 12% (480 blocks) left the 24-MFMA serial chain exposed.  Now
// block = ONE 32-key strip; the 4 waves split the causal q-range mod 4
// (q0 = kb + wave*32, step 128) -- the round-1-verified interleave -- giving
// 58x32 = 1856 blocks (4x the waves).  Per-wave inner body, K-frag hoist,
// butterfly, and 4-atomics-per-key epilogue are byte-identical to verified
// rounds.  XCD pinning kept: bid%8 = h%8 -> head's Q strip L2-resident.
// Natural dispatch order runs long (small-kb) blocks first.
// ---------------------------------------------------------------------------
__global__ __launch_bounds__(256) void attn_cs(
    const f16* __restrict__ Qh, const f16* __restrict__ Ql,
    const f16* __restrict__ Kh, const f16* __restrict__ Kl,
    const float* __restrict__ Lrow, float* __restrict__ cs)
{
  const int t    = threadIdx.x;
  const int lane = t & 63;
  const int wave = t >> 6;
  const int l31  = lane & 31;
  const int gp   = lane >> 5;
  const int bid  = (int)blockIdx.x;        // 58*32 = 1856 blocks
  const int h    = bid & 31;               // bid%8 = h%8 -> XCD pin per head
  const int kvh  = h >> 2;
  const int kb   = (bid >> 5) << 5;        // this block's 32-key strip

  f16x8 kah[8], kal[8];
  {
    const f16* kp  = Kh + (size_t)(kb + l31) * (N_KV * HEAD_DIM) + kvh * HEAD_DIM + 8 * gp;
    const f16* kp2 = Kl + (size_t)(kb + l31) * (N_KV * HEAD_DIM) + kvh * HEAD_DIM + 8 * gp;
#pragma unroll
    for (int c = 0; c < 8; c++) {
      kah[c] = *(const f16x8*)(kp  + c * 16);
      kal[c] = *(const f16x8*)(kp2 + c * 16);
    }
  }

  float csa[16];
#pragma unroll
  for (int r = 0; r < 16; r++) csa[r] = 0.f;

  // wave w handles q-tiles j == w (mod 4), j from kb/32: union covers all,
  // no overlap.  kb is a multiple of 32 so q >= kb >= all keys in strip.
  for (int q0 = kb + wave * 32; q0 < S_LEN; q0 += 128) {
    const int qg = q0 + l31;
    const float iL = 1.0f / Lrow[h * S_LEN + qg];
    const f16* qp  = Qh + (size_t)qg * HIDDEN + h * HEAD_DIM + 8 * gp;
    const f16* qp2 = Ql + (size_t)qg * HIDDEN + h * HEAD_DIM + 8 * gp;

    f32x16 acc;
#pragma unroll
    for (int i = 0; i < 16; i++) acc[i] = 0.f;
#pragma unroll
    for (int c = 0; c < 8; c++) {
      f16x8 bh = *(const f16x8*)(qp  + c * 16);
      f16x8 bl = *(const f16x8*)(qp2 + c * 16);
      acc = __builtin_amdgcn_mfma_f32_32x32x16_f16(kah[c], bh, acc, 0, 0, 0);
      acc = __builtin_amdgcn_mfma_f32_32x32x16_f16(kah[c], bl, acc, 0, 0, 0);
      acc = __builtin_amdgcn_mfma_f32_32x32x16_f16(kal[c], bh, acc, 0, 0, 0);
    }
#pragma unroll
    for (int r = 0; r < 16; r++) {
      int kg = kb + (r & 3) + 8 * (r >> 2) + 4 * gp;
      csa[r] += (kg <= qg) ? exp2f(acc[r] * C2EXP) * iL : 0.f;
    }
  }

#pragma unroll
  for (int st = 1; st < 32; st <<= 1)
#pragma unroll
    for (int r = 0; r < 16; r++) csa[r] += __shfl_xor(csa[r], st);

  if (l31 == 0) {
#pragma unroll
    for (int r = 0; r < 16; r++)
      atomicAdd(&cs[h * S_LEN + kb + (r & 3) + 8 * (r >> 2) + 4 * gp], csa[r]);
  }
}

// ---------------------------------------------------------------------------
// Exact top-HEAVY_K via O(n^2) ranking -- one candidate per thread, 9 x 32
// blocks.  Identical comparison + tie-break (jj < i) -> mask bit-identical.
// (verified rounds 4-5)
// ---------------------------------------------------------------------------
__global__ __launch_bounds__(256) void topk_mask_kernel(
    const float* __restrict__ cs, float* __restrict__ maskout)
{
  const int h = blockIdx.y;
  __shared__ float sv[NCAND];
  const float* s = cs + h * S_LEN;
  const int t = threadIdx.x;
  for (int i = t; i < NCAND; i += 256) sv[i] = s[i];
  __syncthreads();

  const int i = blockIdx.x * 256 + t;
  if (i >= MASK_LEN) return;
  float val = (i >= NCAND + 1) ? 1.0f : 0.0f;
  if (i < NCAND) {
    const float v = sv[i];
    int cnt = 0;
#pragma unroll 4
    for (int jj = 0; jj < NCAND; jj++) {
      float x = sv[jj];
      cnt += ((x > v) || (x == v && jj < i)) ? 1 : 0;
    }
    val = (cnt < HEAVY_K) ? 1.0f : 0.0f;
  }
  maskout[h * MASK_LEN + i] = val;
}

__global__ __launch_bounds__(256) void zero_kernel(float* __restrict__ p, int n)
{
  int i = blockIdx.x * 256 + threadIdx.x;
  if (i < n) p[i] = 0.f;
}

// ---------------------------------------------------------------------------
// In-place RoPE.
// ---------------------------------------------------------------------------
__global__ __launch_bounds__(256) void rope_kernel(
    float* __restrict__ buf, const int* __restrict__ pos_ids, int ncols)
{
  __shared__ float invf_s[64];
  if (threadIdx.x < 64)
    invf_s[threadIdx.x] =
        (float)(1.0 / pow(10000.0, (double)threadIdx.x * (1.0 / 64.0)));
  __syncthreads();

  int i = blockIdx.x * 256 + threadIdx.x;
  int half = ncols >> 1;
  int total = S_LEN * half;
  if (i >= total) return;
  int row = i / half;
  int rem = i - row * half;
  int hh = rem >> 6;
  int d  = rem & 63;
  float p = (float)pos_ids[row];
  float ang = p * invf_s[d];
  float c = cosf(ang);
  float s = sinf(ang);
  float* base = buf + (size_t)row * ncols + hh * HEAD_DIM;
  float x0 = base[d];
  float x1 = base[d + 64];
  base[d]      = x0 * c - x1 * s;
  base[d + 64] = x1 * c + x0 * s;
}

// ---------------------------------------------------------------------------
// Workspace layout (109,576,192 B total -- unchanged from round 2).
// ---------------------------------------------------------------------------
extern "C" void kernel_launch(void* const* d_in, const int* in_sizes, int n_in,
                              void* d_out, int out_size, void* d_ws, size_t ws_size,
                              hipStream_t stream)
{
  (void)in_sizes; (void)n_in; (void)out_size; (void)ws_size;
  const float* hs = (const float*)d_in[0];
  const int*  pos = (const int*)d_in[1];
  const float* Wq = (const float*)d_in[2];
  const float* Wk = (const float*)d_in[3];
  const float* Wv = (const float*)d_in[4];
  const float* Wo = (const float*)d_in[5];
  float* out = (float*)d_out;

  char* w = (char*)d_ws;
  float* Qraw  = (float*)(w);                          // 32 MiB
  f16*   WoT   = (f16*)  (w);                          // overlays Qraw
  f16*   WqTl  = (f16*)  (w + 33554432);               // 16 MiB (32..48)
  float* Kraw  = (float*)(w + 33554432);               // 8 MiB, after Wq gemms
  f16*   Vt    = (f16*)  (w + 33554432);               // 4 MiB, after K split
  float* Vraw  = (float*)(w + 41943040);               // 8 MiB
  float* Lrow  = (float*)(w + 50331648);
  float* cs    = (float*)(w + 50593792);
  f16*   hsh   = (f16*)  (w + 50855936);               // 16 MiB (48.5..64.5)
  f16*   attnb = (f16*)  (w + 50855936);               // overlays hsh
  f16*   hsl   = (f16*)  (w + 67633152);               // 16 MiB (64.5..80.5)
  f16*   Qh    = (f16*)  (w + 67633152);               // overlays hsl
  f16*   WqTh  = (f16*)  (w + 84410368);               // 16 MiB (80.5..96.5)
  f16*   WkTh  = (f16*)  (w + 84410368);               //  8 MiB
  f16*   WvT   = (f16*)  (w + 84410368);               //  8 MiB
  f16*   Ql    = (f16*)  (w + 84410368);               // overlays, after V gemm
  f16*   WkTl  = (f16*)  (w + 92798976);               //  8 MiB (88.5..96.5)
  f16*   Kh    = (f16*)  (w + 101187584);              //  4 MiB
  f16*   Kl    = (f16*)  (w + 105381888);              //  4 MiB -> end 104.5 MiB

  dim3 blk(256);

  // --- split hidden_states once (A-operand for Q, K, V gemms) ---
  split_f16<<<(S_LEN * HIDDEN / 4 + 255) / 256, blk, 0, stream>>>(
      hs, hsh, hsl, S_LEN * HIDDEN / 4);

  // --- Q = hs @ Wq, split-exact, two N=2048 chunks ---
  conv_T_split<<<dim3(2048 / 32, HIDDEN / 32), blk, 0, stream>>>(
      Wq, WqTh, WqTl, HIDDEN, HIDDEN, 0);
  gemm_split<<<dim3(2048 / 128, S_LEN / 128), blk, 0, stream>>>(
      hsh, hsl, WqTh, WqTl, Qraw, HIDDEN, HIDDEN);
  conv_T_split<<<dim3(2048 / 32, HIDDEN / 32), blk, 0, stream>>>(
      Wq, WqTh, WqTl, HIDDEN, HIDDEN, 2048);
  gemm_split<<<dim3(2048 / 128, S_LEN / 128), blk, 0, stream>>>(
      hsh, hsl, WqTh, WqTl, Qraw + 2048, HIDDEN, HIDDEN);

  // --- K = hs @ Wk, split-exact ---
  conv_T_split<<<dim3((N_KV * HEAD_DIM) / 32, HIDDEN / 32), blk, 0, stream>>>(
      Wk, WkTh, WkTl, HIDDEN, N_KV * HEAD_DIM, 0);
  gemm_split<<<dim3((N_KV * HEAD_DIM) / 128, S_LEN / 128), blk, 0, stream>>>(
      hsh, hsl, WkTh, WkTl, Kraw, HIDDEN, N_KV * HEAD_DIM);

  // --- V = hs @ Wv, f16 (tolerance path) ---
  conv_T_f16<<<dim3((N_KV * HEAD_DIM) / 32, HIDDEN / 32), blk, 0, stream>>>(
      Wv, WvT, HIDDEN, N_KV * HEAD_DIM);
  gemm_f16<<<dim3((N_KV * HEAD_DIM) / 64, S_LEN / 64), blk, 0, stream>>>(
      hsh, WvT, Vraw, S_LEN, N_KV * HEAD_DIM, HIDDEN);

  // --- RoPE (f32, in place) ---
  rope_kernel<<<(S_LEN * (HIDDEN / 2) + 255) / 256, blk, 0, stream>>>(
      Qraw, pos, HIDDEN);
  rope_kernel<<<(S_LEN * (N_KV * HEAD_DIM / 2) + 255) / 256, blk, 0, stream>>>(
      Kraw, pos, N_KV * HEAD_DIM);

  // --- splits for attention ---
  split_f16<<<(S_LEN * HIDDEN / 4 + 255) / 256, blk, 0, stream>>>(
      Qraw, Qh, Ql, S_LEN * HIDDEN / 4);
  split_f16<<<(S_LEN * N_KV * HEAD_DIM / 4 + 255) / 256, blk, 0, stream>>>(
      Kraw, Kh, Kl, S_LEN * N_KV * HEAD_DIM / 4);
  conv_T_f16<<<dim3((N_KV * HEAD_DIM) / 32, S_LEN / 32), blk, 0, stream>>>(
      Vraw, Vt, S_LEN, N_KV * HEAD_DIM);
  conv_T_f16<<<dim3(HIDDEN / 32, HIDDEN / 32), blk, 0, stream>>>(
      Wo, WoT, HIDDEN, HIDDEN);   // Qraw dead (split done) -> safe overlay

  // --- attention (1-D XCD-pinned grids) ---
  attn_l<<<dim3((S_LEN / 128) * N_HEADS), blk, 0, stream>>>(
      Qh, Ql, Kh, Kl, Lrow);
  attn_o<<<dim3((S_LEN / 128) * N_HEADS), blk, 0, stream>>>(
      Qh, Kh, Vt, Lrow, attnb);
  zero_kernel<<<(N_HEADS * S_LEN + 255) / 256, blk, 0, stream>>>(
      cs, N_HEADS * S_LEN);
  attn_cs<<<dim3(((NCAND + 31) / 32) * N_HEADS), blk, 0, stream>>>(
      Qh, Ql, Kh, Kl, Lrow, cs);
  topk_mask_kernel<<<dim3((MASK_LEN + 255) / 256, N_HEADS), blk, 0, stream>>>(
      cs, out + (size_t)S_LEN * HIDDEN);

  // --- output projection (128x128 tile) ---
  gemm_f16_128<<<dim3(HIDDEN / 128, S_LEN / 128), blk, 0, stream>>>(
      attnb, WoT, out, HIDDEN, HIDDEN);
}

// Round 7
// 1320.060 us; speedup vs baseline: 2.7674x; 1.0857x over previous
//
#include <hip/hip_runtime.h>
#include <math.h>

#define S_LEN   2048
#define HIDDEN  4096
#define N_HEADS 32
#define N_KV    8
#define HEAD_DIM 128
#define NCAND   1844      // S - RECENT
#define HEAVY_K 819
#define MASK_LEN 2049     // S + 1

typedef _Float16 f16;
using f32x4  = __attribute__((ext_vector_type(4))) float;
using f32x16 = __attribute__((ext_vector_type(16))) float;
using f16x8  = __attribute__((ext_vector_type(8))) _Float16;
using f16x4  = __attribute__((ext_vector_type(4))) _Float16;
using f16x2  = __attribute__((ext_vector_type(2))) _Float16;
using uint4v = __attribute__((ext_vector_type(4))) unsigned int;

// exp(s*SCALE) == exp2(s*C2); single fused constant, used identically in all
// three attention passes so L, w, cs stay mutually consistent.
#define C2EXP 0.12751879523486166f   // (1/sqrt(128)) * log2(e)

// ---------------------------------------------------------------------------
// Split-f16 MFMA GEMM (mask-critical path), v2: tile 128x64.
// C(f32)[M][ldc] = (Ah+Al)[M][K] * (Bh+Bl)[N][K]^T  via 3-term f16 MFMA.
// Round-6 rocprof: the 128x128 version at M=N=2048 gave 256 blocks = exactly
// 1 block/CU (occupancy 11.5%) -> k-loop vmcnt(0) stall fully exposed.
// 128x64 doubles the grid (2 blocks/CU) so a co-resident block hides the
// staging latency.  Per-C-element accumulation sequence (ah*bh, ah*bl, al*bh
// over ascending k by one wave) is BIT-IDENTICAL to the verified 128x128
// kernel -- only wave->tile ownership changes.  LDS 30 KB.
// A staging = verified t>>1 pattern; B staging = verified 64^2-gemm t>>2
// pattern; frag reads = verified stride-40 pattern.
// ---------------------------------------------------------------------------
__global__ __launch_bounds__(256) void gemm_split(
    const f16* __restrict__ Ah, const f16* __restrict__ Al,
    const f16* __restrict__ Bh, const f16* __restrict__ Bl,
    float* __restrict__ C, int K, int ldc)
{
  __shared__ __align__(16) f16 Ash[128 * 40];
  __shared__ __align__(16) f16 Asl[128 * 40];
  __shared__ __align__(16) f16 Bsh[64 * 40];
  __shared__ __align__(16) f16 Bsl[64 * 40];
  const int t    = threadIdx.x;
  const int lane = t & 63;
  const int wave = t >> 6;
  const int mbase = (wave >> 1) * 64;   // 2 waves along M
  const int nbase = (wave & 1) * 32;    // 2 waves along N
  const int bm = blockIdx.y << 7;
  const int bn = blockIdx.x << 6;
  const int arow = t >> 1;              // 0..127
  const int acol = (t & 1) * 16;        // 0 | 16
  const int brow = t >> 2;              // 0..63
  const int bcol = (t & 3) * 8;         // 0,8,16,24
  const int l16 = lane & 15;
  const int lk  = (lane >> 4) * 8;

  f32x4 acc[4][2];
#pragma unroll
  for (int i = 0; i < 4; i++)
#pragma unroll
    for (int j = 0; j < 2; j++) acc[i][j] = (f32x4){0.f, 0.f, 0.f, 0.f};

  for (int k0 = 0; k0 < K; k0 += 32) {
    const f16* gah = Ah + (size_t)(bm + arow) * K + k0 + acol;
    const f16* gal = Al + (size_t)(bm + arow) * K + k0 + acol;
    const f16* gbh = Bh + (size_t)(bn + brow) * K + k0 + bcol;
    const f16* gbl = Bl + (size_t)(bn + brow) * K + k0 + bcol;
    f16x8 vah0 = *(const f16x8*)(gah);
    f16x8 vah1 = *(const f16x8*)(gah + 8);
    f16x8 val0 = *(const f16x8*)(gal);
    f16x8 val1 = *(const f16x8*)(gal + 8);
    f16x8 vbh = *(const f16x8*)(gbh);
    f16x8 vbl = *(const f16x8*)(gbl);
    __syncthreads();
    *(f16x8*)(Ash + arow * 40 + acol)     = vah0;
    *(f16x8*)(Ash + arow * 40 + acol + 8) = vah1;
    *(f16x8*)(Asl + arow * 40 + acol)     = val0;
    *(f16x8*)(Asl + arow * 40 + acol + 8) = val1;
    *(f16x8*)(Bsh + brow * 40 + bcol) = vbh;
    *(f16x8*)(Bsl + brow * 40 + bcol) = vbl;
    __syncthreads();

    f16x8 afh[4], afl[4], bfh[2], bfl[2];
#pragma unroll
    for (int i = 0; i < 4; i++) {
      afh[i] = *(const f16x8*)(Ash + (mbase + i * 16 + l16) * 40 + lk);
      afl[i] = *(const f16x8*)(Asl + (mbase + i * 16 + l16) * 40 + lk);
    }
#pragma unroll
    for (int j = 0; j < 2; j++) {
      bfh[j] = *(const f16x8*)(Bsh + (nbase + j * 16 + l16) * 40 + lk);
      bfl[j] = *(const f16x8*)(Bsl + (nbase + j * 16 + l16) * 40 + lk);
    }
#pragma unroll
    for (int i = 0; i < 4; i++)
#pragma unroll
      for (int j = 0; j < 2; j++) {
        acc[i][j] = __builtin_amdgcn_mfma_f32_16x16x32_f16(afh[i], bfh[j], acc[i][j], 0, 0, 0);
        acc[i][j] = __builtin_amdgcn_mfma_f32_16x16x32_f16(afh[i], bfl[j], acc[i][j], 0, 0, 0);
        acc[i][j] = __builtin_amdgcn_mfma_f32_16x16x32_f16(afl[i], bfh[j], acc[i][j], 0, 0, 0);
      }
  }

  const int rr = (lane >> 4) * 4;
#pragma unroll
  for (int i = 0; i < 4; i++)
#pragma unroll
    for (int j = 0; j < 2; j++)
#pragma unroll
      for (int r = 0; r < 4; r++)
        C[(size_t)(bm + mbase + i * 16 + rr + r) * ldc + bn + nbase + j * 16 + l16]
            = acc[i][j][r];
}

// ---------------------------------------------------------------------------
// f16 MFMA GEMM, 128x128 tile (tolerance path, Wo): 16 MFMA : 8 ds_read per
// k-step.  C(f32)[M][ldc] = A[M][K] * BT[N][K]^T.  Grid 512 = 2/CU (fine).
// (verified rounds 4-6)
// ---------------------------------------------------------------------------
__global__ __launch_bounds__(256) void gemm_f16_128(
    const f16* __restrict__ A, const f16* __restrict__ BT,
    float* __restrict__ C, int K, int ldc)
{
  __shared__ __align__(16) f16 As[128 * 40];
  __shared__ __align__(16) f16 Bs[128 * 40];
  const int t    = threadIdx.x;
  const int lane = t & 63;
  const int wave = t >> 6;
  const int mbase = (wave >> 1) * 64;
  const int nbase = (wave & 1) * 64;
  const int bm = blockIdx.y << 7;
  const int bn = blockIdx.x << 7;
  const int srow = t >> 1;
  const int scol = (t & 1) * 16;
  const int l16 = lane & 15;
  const int lk  = (lane >> 4) * 8;

  f32x4 acc[4][4];
#pragma unroll
  for (int i = 0; i < 4; i++)
#pragma unroll
    for (int j = 0; j < 4; j++) acc[i][j] = (f32x4){0.f, 0.f, 0.f, 0.f};

  for (int k0 = 0; k0 < K; k0 += 32) {
    const f16* ga = A  + (size_t)(bm + srow) * K + k0 + scol;
    const f16* gb = BT + (size_t)(bn + srow) * K + k0 + scol;
    f16x8 va0 = *(const f16x8*)(ga);
    f16x8 va1 = *(const f16x8*)(ga + 8);
    f16x8 vb0 = *(const f16x8*)(gb);
    f16x8 vb1 = *(const f16x8*)(gb + 8);
    __syncthreads();
    *(f16x8*)(As + srow * 40 + scol)     = va0;
    *(f16x8*)(As + srow * 40 + scol + 8) = va1;
    *(f16x8*)(Bs + srow * 40 + scol)     = vb0;
    *(f16x8*)(Bs + srow * 40 + scol + 8) = vb1;
    __syncthreads();

    f16x8 af[4], bf[4];
#pragma unroll
    for (int i = 0; i < 4; i++) {
      af[i] = *(const f16x8*)(As + (mbase + i * 16 + l16) * 40 + lk);
      bf[i] = *(const f16x8*)(Bs + (nbase + i * 16 + l16) * 40 + lk);
    }
#pragma unroll
    for (int i = 0; i < 4; i++)
#pragma unroll
      for (int j = 0; j < 4; j++)
        acc[i][j] = __builtin_amdgcn_mfma_f32_16x16x32_f16(af[i], bf[j], acc[i][j], 0, 0, 0);
  }

  const int rr = (lane >> 4) * 4;
#pragma unroll
  for (int i = 0; i < 4; i++)
#pragma unroll
    for (int j = 0; j < 4; j++)
#pragma unroll
      for (int r = 0; r < 4; r++)
        C[(size_t)(bm + mbase + i * 16 + rr + r) * ldc + bn + nbase + j * 16 + l16]
            = acc[i][j][r];
}

// ---------------------------------------------------------------------------
// f16 MFMA GEMM 64x64 (V projection: N=1024 wants block count).
// ---------------------------------------------------------------------------
__global__ __launch_bounds__(256) void gemm_f16(
    const f16* __restrict__ A, const f16* __restrict__ BT,
    float* __restrict__ C, int M, int N, int K)
{
  __shared__ __align__(16) f16 As[64 * 40];
  __shared__ __align__(16) f16 Bs[64 * 40];
  const int t    = threadIdx.x;
  const int lane = t & 63;
  const int wave = t >> 6;
  const int mbase = (wave >> 1) * 32;
  const int nbase = (wave & 1) * 32;
  const int bm = blockIdx.y << 6;
  const int bn = blockIdx.x << 6;
  const int srow = t >> 2;
  const int scol = (t & 3) * 8;
  const int l16 = lane & 15;
  const int lk  = (lane >> 4) * 8;

  f32x4 acc00 = {0.f,0.f,0.f,0.f}, acc01 = {0.f,0.f,0.f,0.f};
  f32x4 acc10 = {0.f,0.f,0.f,0.f}, acc11 = {0.f,0.f,0.f,0.f};

  for (int k0 = 0; k0 < K; k0 += 32) {
    f16x8 av = *(const f16x8*)(A  + (size_t)(bm + srow) * K + k0 + scol);
    f16x8 bv = *(const f16x8*)(BT + (size_t)(bn + srow) * K + k0 + scol);
    __syncthreads();
    *(f16x8*)(As + srow * 40 + scol) = av;
    *(f16x8*)(Bs + srow * 40 + scol) = bv;
    __syncthreads();
    f16x8 a0 = *(const f16x8*)(As + (mbase + l16)      * 40 + lk);
    f16x8 a1 = *(const f16x8*)(As + (mbase + 16 + l16) * 40 + lk);
    f16x8 b0 = *(const f16x8*)(Bs + (nbase + l16)      * 40 + lk);
    f16x8 b1 = *(const f16x8*)(Bs + (nbase + 16 + l16) * 40 + lk);
    acc00 = __builtin_amdgcn_mfma_f32_16x16x32_f16(a0, b0, acc00, 0, 0, 0);
    acc01 = __builtin_amdgcn_mfma_f32_16x16x32_f16(a0, b1, acc01, 0, 0, 0);
    acc10 = __builtin_amdgcn_mfma_f32_16x16x32_f16(a1, b0, acc10, 0, 0, 0);
    acc11 = __builtin_amdgcn_mfma_f32_16x16x32_f16(a1, b1, acc11, 0, 0, 0);
  }

  const int rr = (lane >> 4) * 4;
#pragma unroll
  for (int r = 0; r < 4; r++) {
    C[(size_t)(bm + mbase +      rr + r) * N + bn + nbase +      l16] = acc00[r];
    C[(size_t)(bm + mbase +      rr + r) * N + bn + nbase + 16 + l16] = acc01[r];
    C[(size_t)(bm + mbase + 16 + rr + r) * N + bn + nbase +      l16] = acc10[r];
    C[(size_t)(bm + mbase + 16 + rr + r) * N + bn + nbase + 16 + l16] = acc11[r];
  }
}

// ---------------------------------------------------------------------------
// f32 [K][N] -> f16 [N][K] transpose-convert.
// ---------------------------------------------------------------------------
__global__ __launch_bounds__(256) void conv_T_f16(
    const float* __restrict__ src, f16* __restrict__ dst, int K, int N)
{
  __shared__ float tile[32][33];
  const int tj = blockIdx.x;
  const int ti = blockIdx.y;
  const int t = threadIdx.x;
  for (int idx = t; idx < 1024; idx += 256) {
    int r = idx >> 5, c = idx & 31;
    tile[r][c] = src[(size_t)(ti * 32 + r) * N + tj * 32 + c];
  }
  __syncthreads();
  for (int idx = t; idx < 1024; idx += 256) {
    int r = idx >> 5, c = idx & 31;
    dst[(size_t)(tj * 32 + r) * K + ti * 32 + c] = (f16)tile[c][r];
  }
}

// ---------------------------------------------------------------------------
// f32 [K][N] cols [n0,n0+32*gridDim.x) -> split f16 hi/lo [NC][K] transpose.
// ---------------------------------------------------------------------------
__global__ __launch_bounds__(256) void conv_T_split(
    const float* __restrict__ src, f16* __restrict__ hi, f16* __restrict__ lo,
    int K, int N, int n0)
{
  __shared__ float tile[32][33];
  const int tj = blockIdx.x;
  const int ti = blockIdx.y;
  const int t = threadIdx.x;
  for (int idx = t; idx < 1024; idx += 256) {
    int r = idx >> 5, c = idx & 31;
    tile[r][c] = src[(size_t)(ti * 32 + r) * N + n0 + tj * 32 + c];
  }
  __syncthreads();
  for (int idx = t; idx < 1024; idx += 256) {
    int r = idx >> 5, c = idx & 31;
    float x = tile[c][r];
    f16 h = (f16)x;
    hi[(size_t)(tj * 32 + r) * K + ti * 32 + c] = h;
    lo[(size_t)(tj * 32 + r) * K + ti * 32 + c] = (f16)(x - (float)h);
  }
}

// ---------------------------------------------------------------------------
// f32 -> (f16 hi, f16 lo) split, row-major.  hi = rne(x); lo = rne(x - hi).
// ---------------------------------------------------------------------------
__global__ __launch_bounds__(256) void split_f16(
    const float* __restrict__ src, f16* __restrict__ hi, f16* __restrict__ lo,
    int n4)
{
  int i = blockIdx.x * 256 + threadIdx.x;
  if (i >= n4) return;
  float4 v = ((const float4*)src)[i];
  float vv[4] = {v.x, v.y, v.z, v.w};
  f16x4 h, l;
#pragma unroll
  for (int j = 0; j < 4; j++) {
    f16 hh = (f16)vv[j];
    h[j] = hh;
    l[j] = (f16)(vv[j] - (float)hh);
  }
  ((f16x4*)hi)[i] = h;
  ((f16x4*)lo)[i] = l;
}

// ---------------------------------------------------------------------------
// Attention pass 1: softmax denominators L[q] via split-f16 32x32x16 MFMA.
// 1-D grid, kvh-pinned: bid%8 = kvh -> all blocks sharing a K strip land on
// one XCD (L2-resident K).  Big-q blocks first (low bid).  (verified r5-6)
// ---------------------------------------------------------------------------
__global__ __launch_bounds__(256) void attn_l(
    const f16* __restrict__ Qh, const f16* __restrict__ Ql,
    const f16* __restrict__ Kh, const f16* __restrict__ Kl,
    float* __restrict__ Lrow)
{
  __shared__ __align__(16) f16 Khs[32 * 136];
  __shared__ __align__(16) f16 Kls[32 * 136];
  const int t    = threadIdx.x;
  const int lane = t & 63;
  const int wave = t >> 6;
  const int l31  = lane & 31;
  const int gp   = lane >> 5;
  const int bid  = (int)blockIdx.x;            // 512 blocks
  const int kvh  = bid & 7;
  const int h    = kvh * 4 + ((bid >> 3) & 3);
  const int q0   = (15 - (bid >> 5)) << 7;     // big q first
  const int qw   = q0 + wave * 32;
  const int qg   = qw + l31;

  f16x8 qhf[8], qlf[8];
  {
    const f16* qp  = Qh + (size_t)qg * HIDDEN + h * HEAD_DIM + 8 * gp;
    const f16* qp2 = Ql + (size_t)qg * HIDDEN + h * HEAD_DIM + 8 * gp;
#pragma unroll
    for (int c = 0; c < 8; c++) {
      qhf[c] = *(const f16x8*)(qp  + c * 16);
      qlf[c] = *(const f16x8*)(qp2 + c * 16);
    }
  }

  float Lacc = 0.f;
  const int ntiles = (q0 >> 5) + 4;
  for (int kt = 0; kt < ntiles; kt++) {
    const int k0 = kt << 5;
    __syncthreads();
    for (int i = t; i < 512; i += 256) {
      int r = i >> 4, c = i & 15;
      size_t g = (size_t)(k0 + r) * (N_KV * HEAD_DIM) + kvh * HEAD_DIM + c * 8;
      *(f16x8*)(Khs + r * 136 + c * 8) = *(const f16x8*)(Kh + g);
      *(f16x8*)(Kls + r * 136 + c * 8) = *(const f16x8*)(Kl + g);
    }
    __syncthreads();
    if (k0 > qw + 31) continue;   // after both barriers: barrier counts uniform

    f32x16 acc;
#pragma unroll
    for (int i = 0; i < 16; i++) acc[i] = 0.f;
#pragma unroll
    for (int c = 0; c < 8; c++) {
      f16x8 ah = *(const f16x8*)(Khs + l31 * 136 + c * 16 + 8 * gp);
      f16x8 al = *(const f16x8*)(Kls + l31 * 136 + c * 16 + 8 * gp);
      acc = __builtin_amdgcn_mfma_f32_32x32x16_f16(ah, qhf[c], acc, 0, 0, 0);
      acc = __builtin_amdgcn_mfma_f32_32x32x16_f16(ah, qlf[c], acc, 0, 0, 0);
      acc = __builtin_amdgcn_mfma_f32_32x32x16_f16(al, qhf[c], acc, 0, 0, 0);
    }
    float ws = 0.f;
#pragma unroll
    for (int r = 0; r < 16; r++) {
      int kg = k0 + (r & 3) + 8 * (r >> 2) + 4 * gp;
      float e = exp2f(acc[r] * C2EXP);
      ws += (kg <= qg) ? e : 0.f;
    }
    Lacc += ws;
  }

  float tot = Lacc + __shfl_xor(Lacc, 32);
  if (lane < 32) Lrow[h * S_LEN + qw + lane] = tot;
}

// ---------------------------------------------------------------------------
// Attention pass 2: O = softmax(QK^T) V via MFMA.  Same kvh-pinned 1-D grid.
// (verified rounds 5-6)
// ---------------------------------------------------------------------------
__global__ __launch_bounds__(256) void attn_o(
    const f16* __restrict__ Qh, const f16* __restrict__ Kh,
    const f16* __restrict__ Vt, const float* __restrict__ Lrow,
    f16* __restrict__ attnb)
{
  __shared__ __align__(16) f16 Khs[32 * 136];
  const int t    = threadIdx.x;
  const int lane = t & 63;
  const int wave = t >> 6;
  const int l31  = lane & 31;
  const int gp   = lane >> 5;
  const int bid  = (int)blockIdx.x;            // 512 blocks
  const int kvh  = bid & 7;
  const int h    = kvh * 4 + ((bid >> 3) & 3);
  const int q0   = (15 - (bid >> 5)) << 7;     // big q first
  const int qw   = q0 + wave * 32;
  const int qg   = qw + l31;

  f16x8 qhf[8];
  {
    const f16* qp = Qh + (size_t)qg * HIDDEN + h * HEAD_DIM + 8 * gp;
#pragma unroll
    for (int c = 0; c < 8; c++) qhf[c] = *(const f16x8*)(qp + c * 16);
  }
  const float iL = 1.0f / Lrow[h * S_LEN + qg];

  f32x16 oacc[4];
#pragma unroll
  for (int m = 0; m < 4; m++)
#pragma unroll
    for (int i = 0; i < 16; i++) oacc[m][i] = 0.f;

  const int ntiles = (q0 >> 5) + 4;
  for (int kt = 0; kt < ntiles; kt++) {
    const int k0 = kt << 5;
    __syncthreads();
    for (int i = t; i < 512; i += 256) {
      int r = i >> 4, c = i & 15;
      size_t g = (size_t)(k0 + r) * (N_KV * HEAD_DIM) + kvh * HEAD_DIM + c * 8;
      *(f16x8*)(Khs + r * 136 + c * 8) = *(const f16x8*)(Kh + g);
    }
    __syncthreads();
    if (k0 > qw + 31) continue;

    f32x16 acc;
#pragma unroll
    for (int i = 0; i < 16; i++) acc[i] = 0.f;
#pragma unroll
    for (int c = 0; c < 8; c++) {
      f16x8 ah = *(const f16x8*)(Khs + l31 * 136 + c * 16 + 8 * gp);
      acc = __builtin_amdgcn_mfma_f32_32x32x16_f16(ah, qhf[c], acc, 0, 0, 0);
    }

    float wv[16];
#pragma unroll
    for (int r = 0; r < 16; r++) {
      int kg = k0 + (r & 3) + 8 * (r >> 2) + 4 * gp;
      wv[r] = (kg <= qg) ? exp2f(acc[r] * C2EXP) * iL : 0.f;
    }

    unsigned p[8], x[8];
#pragma unroll
    for (int j = 0; j < 8; j++)
      p[j] = __builtin_bit_cast(unsigned,
               __builtin_amdgcn_cvt_pkrtz(wv[2 * j], wv[2 * j + 1]));
#pragma unroll
    for (int j = 0; j < 8; j++)
      x[j] = (unsigned)__shfl_xor((int)p[j], 32);

    uint4v cc0, cc1;   // B-frag: row(q)=lane&31, k = gp*8 + j
    cc0[0] = gp ? x[2] : p[0]; cc0[1] = gp ? x[3] : p[1];
    cc0[2] = gp ? p[2] : x[0]; cc0[3] = gp ? p[3] : x[1];
    cc1[0] = gp ? x[6] : p[4]; cc1[1] = gp ? x[7] : p[5];
    cc1[2] = gp ? p[6] : x[4]; cc1[3] = gp ? p[7] : x[5];
    f16x8 pf0 = __builtin_bit_cast(f16x8, cc0);   // keys k0+0..15
    f16x8 pf1 = __builtin_bit_cast(f16x8, cc1);   // keys k0+16..31

#pragma unroll
    for (int mt = 0; mt < 4; mt++) {
      const f16* vp = Vt + (size_t)(kvh * HEAD_DIM + mt * 32 + l31) * S_LEN
                         + k0 + 8 * gp;
      f16x8 v0 = *(const f16x8*)(vp);
      f16x8 v1 = *(const f16x8*)(vp + 16);
      oacc[mt] = __builtin_amdgcn_mfma_f32_32x32x16_f16(v0, pf0, oacc[mt], 0, 0, 0);
      oacc[mt] = __builtin_amdgcn_mfma_f32_32x32x16_f16(v1, pf1, oacc[mt], 0, 0, 0);
    }
  }

  f16* ob = attnb + (size_t)qg * HIDDEN + h * HEAD_DIM;
#pragma unroll
  for (int mt = 0; mt < 4; mt++)
#pragma unroll
    for (int rq = 0; rq < 4; rq++) {
      int d = mt * 32 + 8 * rq + 4 * gp;
      f16x4 o;
      o[0] = (f16)oacc[mt][rq * 4 + 0];
      o[1] = (f16)oacc[mt][rq * 4 + 1];
      o[2] = (f16)oacc[mt][rq * 4 + 2];
      o[3] = (f16)oacc[mt][rq * 4 + 3];
      *(f16x4*)(ob + d) = o;
    }
}

// ---------------------------------------------------------------------------
// Attention pass 3: cs[h][key] = sum_q w[q,key]  (mask-critical, split-exact).
// v3 (verified round 6): block = ONE 32-key strip; 4 waves split the causal
// q-range mod 4 -> 1856 blocks.  XCD pin: bid%8 = h%8.
// ---------------------------------------------------------------------------
__global__ __launch_bounds__(256) void attn_cs(
    const f16* __restrict__ Qh, const f16* __restrict__ Ql,
    const f16* __restrict__ Kh, const f16* __restrict__ Kl,
    const float* __restrict__ Lrow, float* __restrict__ cs)
{
  const int t    = threadIdx.x;
  const int lane = t & 63;
  const int wave = t >> 6;
  const int l31  = lane & 31;
  const int gp   = lane >> 5;
  const int bid  = (int)blockIdx.x;        // 58*32 = 1856 blocks
  const int h    = bid & 31;               // bid%8 = h%8 -> XCD pin per head
  const int kvh  = h >> 2;
  const int kb   = (bid >> 5) << 5;        // this block's 32-key strip

  f16x8 kah[8], kal[8];
  {
    const f16* kp  = Kh + (size_t)(kb + l31) * (N_KV * HEAD_DIM) + kvh * HEAD_DIM + 8 * gp;
    const f16* kp2 = Kl + (size_t)(kb + l31) * (N_KV * HEAD_DIM) + kvh * HEAD_DIM + 8 * gp;
#pragma unroll
    for (int c = 0; c < 8; c++) {
      kah[c] = *(const f16x8*)(kp  + c * 16);
      kal[c] = *(const f16x8*)(kp2 + c * 16);
    }
  }

  float csa[16];
#pragma unroll
  for (int r = 0; r < 16; r++) csa[r] = 0.f;

  for (int q0 = kb + wave * 32; q0 < S_LEN; q0 += 128) {
    const int qg = q0 + l31;
    const float iL = 1.0f / Lrow[h * S_LEN + qg];
    const f16* qp  = Qh + (size_t)qg * HIDDEN + h * HEAD_DIM + 8 * gp;
    const f16* qp2 = Ql + (size_t)qg * HIDDEN + h * HEAD_DIM + 8 * gp;

    f32x16 acc;
#pragma unroll
    for (int i = 0; i < 16; i++) acc[i] = 0.f;
#pragma unroll
    for (int c = 0; c < 8; c++) {
      f16x8 bh = *(const f16x8*)(qp  + c * 16);
      f16x8 bl = *(const f16x8*)(qp2 + c * 16);
      acc = __builtin_amdgcn_mfma_f32_32x32x16_f16(kah[c], bh, acc, 0, 0, 0);
      acc = __builtin_amdgcn_mfma_f32_32x32x16_f16(kah[c], bl, acc, 0, 0, 0);
      acc = __builtin_amdgcn_mfma_f32_32x32x16_f16(kal[c], bh, acc, 0, 0, 0);
    }
#pragma unroll
    for (int r = 0; r < 16; r++) {
      int kg = kb + (r & 3) + 8 * (r >> 2) + 4 * gp;
      csa[r] += (kg <= qg) ? exp2f(acc[r] * C2EXP) * iL : 0.f;
    }
  }

#pragma unroll
  for (int st = 1; st < 32; st <<= 1)
#pragma unroll
    for (int r = 0; r < 16; r++) csa[r] += __shfl_xor(csa[r], st);

  if (l31 == 0) {
#pragma unroll
    for (int r = 0; r < 16; r++)
      atomicAdd(&cs[h * S_LEN + kb + (r & 3) + 8 * (r >> 2) + 4 * gp], csa[r]);
  }
}

// ---------------------------------------------------------------------------
// Exact top-HEAVY_K via O(n^2) ranking -- one candidate per thread, 9 x 32
// blocks.  Identical comparison + tie-break (jj < i) -> mask bit-identical.
// (verified rounds 4-6)
// ---------------------------------------------------------------------------
__global__ __launch_bounds__(256) void topk_mask_kernel(
    const float* __restrict__ cs, float* __restrict__ maskout)
{
  const int h = blockIdx.y;
  __shared__ float sv[NCAND];
  const float* s = cs + h * S_LEN;
  const int t = threadIdx.x;
  for (int i = t; i < NCAND; i += 256) sv[i] = s[i];
  __syncthreads();

  const int i = blockIdx.x * 256 + t;
  if (i >= MASK_LEN) return;
  float val = (i >= NCAND + 1) ? 1.0f : 0.0f;
  if (i < NCAND) {
    const float v = sv[i];
    int cnt = 0;
#pragma unroll 4
    for (int jj = 0; jj < NCAND; jj++) {
      float x = sv[jj];
      cnt += ((x > v) || (x == v && jj < i)) ? 1 : 0;
    }
    val = (cnt < HEAVY_K) ? 1.0f : 0.0f;
  }
  maskout[h * MASK_LEN + i] = val;
}

__global__ __launch_bounds__(256) void zero_kernel(float* __restrict__ p, int n)
{
  int i = blockIdx.x * 256 + threadIdx.x;
  if (i < n) p[i] = 0.f;
}

// ---------------------------------------------------------------------------
// In-place RoPE.
// ---------------------------------------------------------------------------
__global__ __launch_bounds__(256) void rope_kernel(
    float* __restrict__ buf, const int* __restrict__ pos_ids, int ncols)
{
  __shared__ float invf_s[64];
  if (threadIdx.x < 64)
    invf_s[threadIdx.x] =
        (float)(1.0 / pow(10000.0, (double)threadIdx.x * (1.0 / 64.0)));
  __syncthreads();

  int i = blockIdx.x * 256 + threadIdx.x;
  int half = ncols >> 1;
  int total = S_LEN * half;
  if (i >= total) return;
  int row = i / half;
  int rem = i - row * half;
  int hh = rem >> 6;
  int d  = rem & 63;
  float p = (float)pos_ids[row];
  float ang = p * invf_s[d];
  float c = cosf(ang);
  float s = sinf(ang);
  float* base = buf + (size_t)row * ncols + hh * HEAD_DIM;
  float x0 = base[d];
  float x1 = base[d + 64];
  base[d]      = x0 * c - x1 * s;
  base[d + 64] = x1 * c + x0 * s;
}

// ---------------------------------------------------------------------------
// Workspace layout (109,576,192 B total -- unchanged from round 2).
// ---------------------------------------------------------------------------
extern "C" void kernel_launch(void* const* d_in, const int* in_sizes, int n_in,
                              void* d_out, int out_size, void* d_ws, size_t ws_size,
                              hipStream_t stream)
{
  (void)in_sizes; (void)n_in; (void)out_size; (void)ws_size;
  const float* hs = (const float*)d_in[0];
  const int*  pos = (const int*)d_in[1];
  const float* Wq = (const float*)d_in[2];
  const float* Wk = (const float*)d_in[3];
  const float* Wv = (const float*)d_in[4];
  const float* Wo = (const float*)d_in[5];
  float* out = (float*)d_out;

  char* w = (char*)d_ws;
  float* Qraw  = (float*)(w);                          // 32 MiB
  f16*   WoT   = (f16*)  (w);                          // overlays Qraw
  f16*   WqTl  = (f16*)  (w + 33554432);               // 16 MiB (32..48)
  float* Kraw  = (float*)(w + 33554432);               // 8 MiB, after Wq gemms
  f16*   Vt    = (f16*)  (w + 33554432);               // 4 MiB, after K split
  float* Vraw  = (float*)(w + 41943040);               // 8 MiB
  float* Lrow  = (float*)(w + 50331648);
  float* cs    = (float*)(w + 50593792);
  f16*   hsh   = (f16*)  (w + 50855936);               // 16 MiB (48.5..64.5)
  f16*   attnb = (f16*)  (w + 50855936);               // overlays hsh
  f16*   hsl   = (f16*)  (w + 67633152);               // 16 MiB (64.5..80.5)
  f16*   Qh    = (f16*)  (w + 67633152);               // overlays hsl
  f16*   WqTh  = (f16*)  (w + 84410368);               // 16 MiB (80.5..96.5)
  f16*   WkTh  = (f16*)  (w + 84410368);               //  8 MiB
  f16*   WvT   = (f16*)  (w + 84410368);               //  8 MiB
  f16*   Ql    = (f16*)  (w + 84410368);               // overlays, after V gemm
  f16*   WkTl  = (f16*)  (w + 92798976);               //  8 MiB (88.5..96.5)
  f16*   Kh    = (f16*)  (w + 101187584);              //  4 MiB
  f16*   Kl    = (f16*)  (w + 105381888);              //  4 MiB -> end 104.5 MiB

  dim3 blk(256);

  // --- split hidden_states once (A-operand for Q, K, V gemms) ---
  split_f16<<<(S_LEN * HIDDEN / 4 + 255) / 256, blk, 0, stream>>>(
      hs, hsh, hsl, S_LEN * HIDDEN / 4);

  // --- Q = hs @ Wq, split-exact, two N=2048 chunks (128x64 tiles: 512 blk) ---
  conv_T_split<<<dim3(2048 / 32, HIDDEN / 32), blk, 0, stream>>>(
      Wq, WqTh, WqTl, HIDDEN, HIDDEN, 0);
  gemm_split<<<dim3(2048 / 64, S_LEN / 128), blk, 0, stream>>>(
      hsh, hsl, WqTh, WqTl, Qraw, HIDDEN, HIDDEN);
  conv_T_split<<<dim3(2048 / 32, HIDDEN / 32), blk, 0, stream>>>(
      Wq, WqTh, WqTl, HIDDEN, HIDDEN, 2048);
  gemm_split<<<dim3(2048 / 64, S_LEN / 128), blk, 0, stream>>>(
      hsh, hsl, WqTh, WqTl, Qraw + 2048, HIDDEN, HIDDEN);

  // --- K = hs @ Wk, split-exact (128x64 tiles: 256 blocks) ---
  conv_T_split<<<dim3((N_KV * HEAD_DIM) / 32, HIDDEN / 32), blk, 0, stream>>>(
      Wk, WkTh, WkTl, HIDDEN, N_KV * HEAD_DIM, 0);
  gemm_split<<<dim3((N_KV * HEAD_DIM) / 64, S_LEN / 128), blk, 0, stream>>>(
      hsh, hsl, WkTh, WkTl, Kraw, HIDDEN, N_KV * HEAD_DIM);

  // --- V = hs @ Wv, f16 (tolerance path) ---
  conv_T_f16<<<dim3((N_KV * HEAD_DIM) / 32, HIDDEN / 32), blk, 0, stream>>>(
      Wv, WvT, HIDDEN, N_KV * HEAD_DIM);
  gemm_f16<<<dim3((N_KV * HEAD_DIM) / 64, S_LEN / 64), blk, 0, stream>>>(
      hsh, WvT, Vraw, S_LEN, N_KV * HEAD_DIM, HIDDEN);

  // --- RoPE (f32, in place) ---
  rope_kernel<<<(S_LEN * (HIDDEN / 2) + 255) / 256, blk, 0, stream>>>(
      Qraw, pos, HIDDEN);
  rope_kernel<<<(S_LEN * (N_KV * HEAD_DIM / 2) + 255) / 256, blk, 0, stream>>>(
      Kraw, pos, N_KV * HEAD_DIM);

  // --- splits for attention ---
  split_f16<<<(S_LEN * HIDDEN / 4 + 255) / 256, blk, 0, stream>>>(
      Qraw, Qh, Ql, S_LEN * HIDDEN / 4);
  split_f16<<<(S_LEN * N_KV * HEAD_DIM / 4 + 255) / 256, blk, 0, stream>>>(
      Kraw, Kh, Kl, S_LEN * N_KV * HEAD_DIM / 4);
  conv_T_f16<<<dim3((N_KV * HEAD_DIM) / 32, S_LEN / 32), blk, 0, stream>>>(
      Vraw, Vt, S_LEN, N_KV * HEAD_DIM);
  conv_T_f16<<<dim3(HIDDEN / 32, HIDDEN / 32), blk, 0, stream>>>(
      Wo, WoT, HIDDEN, HIDDEN);   // Qraw dead (split done) -> safe overlay

  // --- attention (1-D XCD-pinned grids) ---
  attn_l<<<dim3((S_LEN / 128) * N_HEADS), blk, 0, stream>>>(
      Qh, Ql, Kh, Kl, Lrow);
  attn_o<<<dim3((S_LEN / 128) * N_HEADS), blk, 0, stream>>>(
      Qh, Kh, Vt, Lrow, attnb);
  zero_kernel<<<(N_HEADS * S_LEN + 255) / 256, blk, 0, stream>>>(
      cs, N_HEADS * S_LEN);
  attn_cs<<<dim3(((NCAND + 31) / 32) * N_HEADS), blk, 0, stream>>>(
      Qh, Ql, Kh, Kl, Lrow, cs);
  topk_mask_kernel<<<dim3((MASK_LEN + 255) / 256, N_HEADS), blk, 0, stream>>>(
      cs, out + (size_t)S_LEN * HIDDEN);

  // --- output projection (128x128 tile) ---
  gemm_f16_128<<<dim3(HIDDEN / 128, S_LEN / 128), blk, 0, stream>>>(
      attnb, WoT, out, HIDDEN, HIDDEN);
}

// Round 8
// 1291.866 us; speedup vs baseline: 2.8278x; 1.0218x over previous
//
#include <hip/hip_runtime.h>
#include <math.h>

#define S_LEN   2048
#define HIDDEN  4096
#define N_HEADS 32
#define N_KV    8
#define HEAD_DIM 128
#define NCAND   1844      // S - RECENT
#define HEAVY_K 819
#define MASK_LEN 2049     // S + 1

typedef _Float16 f16;
using f32x4  = __attribute__((ext_vector_type(4))) float;
using f32x16 = __attribute__((ext_vector_type(16))) float;
using f16x8  = __attribute__((ext_vector_type(8))) _Float16;
using f16x4  = __attribute__((ext_vector_type(4))) _Float16;
using f16x2  = __attribute__((ext_vector_type(2))) _Float16;
using uint4v = __attribute__((ext_vector_type(4))) unsigned int;

// exp(s*SCALE) == exp2(s*C2); single fused constant, used identically in all
// three attention passes so L, w, cs stay mutually consistent.
#define C2EXP 0.12751879523486166f   // (1/sqrt(128)) * log2(e)

// ---------------------------------------------------------------------------
// Split-f16 MFMA GEMM (mask-critical path), 128x64 tile (verified round 7).
// C(f32)[M][ldc] = (Ah+Al)[M][K] * (Bh+Bl)[N][K]^T  via 3-term f16 MFMA.
// ---------------------------------------------------------------------------
__global__ __launch_bounds__(256) void gemm_split(
    const f16* __restrict__ Ah, const f16* __restrict__ Al,
    const f16* __restrict__ Bh, const f16* __restrict__ Bl,
    float* __restrict__ C, int K, int ldc)
{
  __shared__ __align__(16) f16 Ash[128 * 40];
  __shared__ __align__(16) f16 Asl[128 * 40];
  __shared__ __align__(16) f16 Bsh[64 * 40];
  __shared__ __align__(16) f16 Bsl[64 * 40];
  const int t    = threadIdx.x;
  const int lane = t & 63;
  const int wave = t >> 6;
  const int mbase = (wave >> 1) * 64;   // 2 waves along M
  const int nbase = (wave & 1) * 32;    // 2 waves along N
  const int bm = blockIdx.y << 7;
  const int bn = blockIdx.x << 6;
  const int arow = t >> 1;              // 0..127
  const int acol = (t & 1) * 16;        // 0 | 16
  const int brow = t >> 2;              // 0..63
  const int bcol = (t & 3) * 8;         // 0,8,16,24
  const int l16 = lane & 15;
  const int lk  = (lane >> 4) * 8;

  f32x4 acc[4][2];
#pragma unroll
  for (int i = 0; i < 4; i++)
#pragma unroll
    for (int j = 0; j < 2; j++) acc[i][j] = (f32x4){0.f, 0.f, 0.f, 0.f};

  for (int k0 = 0; k0 < K; k0 += 32) {
    const f16* gah = Ah + (size_t)(bm + arow) * K + k0 + acol;
    const f16* gal = Al + (size_t)(bm + arow) * K + k0 + acol;
    const f16* gbh = Bh + (size_t)(bn + brow) * K + k0 + bcol;
    const f16* gbl = Bl + (size_t)(bn + brow) * K + k0 + bcol;
    f16x8 vah0 = *(const f16x8*)(gah);
    f16x8 vah1 = *(const f16x8*)(gah + 8);
    f16x8 val0 = *(const f16x8*)(gal);
    f16x8 val1 = *(const f16x8*)(gal + 8);
    f16x8 vbh = *(const f16x8*)(gbh);
    f16x8 vbl = *(const f16x8*)(gbl);
    __syncthreads();
    *(f16x8*)(Ash + arow * 40 + acol)     = vah0;
    *(f16x8*)(Ash + arow * 40 + acol + 8) = vah1;
    *(f16x8*)(Asl + arow * 40 + acol)     = val0;
    *(f16x8*)(Asl + arow * 40 + acol + 8) = val1;
    *(f16x8*)(Bsh + brow * 40 + bcol) = vbh;
    *(f16x8*)(Bsl + brow * 40 + bcol) = vbl;
    __syncthreads();

    f16x8 afh[4], afl[4], bfh[2], bfl[2];
#pragma unroll
    for (int i = 0; i < 4; i++) {
      afh[i] = *(const f16x8*)(Ash + (mbase + i * 16 + l16) * 40 + lk);
      afl[i] = *(const f16x8*)(Asl + (mbase + i * 16 + l16) * 40 + lk);
    }
#pragma unroll
    for (int j = 0; j < 2; j++) {
      bfh[j] = *(const f16x8*)(Bsh + (nbase + j * 16 + l16) * 40 + lk);
      bfl[j] = *(const f16x8*)(Bsl + (nbase + j * 16 + l16) * 40 + lk);
    }
#pragma unroll
    for (int i = 0; i < 4; i++)
#pragma unroll
      for (int j = 0; j < 2; j++) {
        acc[i][j] = __builtin_amdgcn_mfma_f32_16x16x32_f16(afh[i], bfh[j], acc[i][j], 0, 0, 0);
        acc[i][j] = __builtin_amdgcn_mfma_f32_16x16x32_f16(afh[i], bfl[j], acc[i][j], 0, 0, 0);
        acc[i][j] = __builtin_amdgcn_mfma_f32_16x16x32_f16(afl[i], bfh[j], acc[i][j], 0, 0, 0);
      }
  }

  const int rr = (lane >> 4) * 4;
#pragma unroll
  for (int i = 0; i < 4; i++)
#pragma unroll
    for (int j = 0; j < 2; j++)
#pragma unroll
      for (int r = 0; r < 4; r++)
        C[(size_t)(bm + mbase + i * 16 + rr + r) * ldc + bn + nbase + j * 16 + l16]
            = acc[i][j][r];
}

// ---------------------------------------------------------------------------
// f16 MFMA GEMM, 128x128 tile (tolerance path, Wo).  (verified rounds 4-7)
// ---------------------------------------------------------------------------
__global__ __launch_bounds__(256) void gemm_f16_128(
    const f16* __restrict__ A, const f16* __restrict__ BT,
    float* __restrict__ C, int K, int ldc)
{
  __shared__ __align__(16) f16 As[128 * 40];
  __shared__ __align__(16) f16 Bs[128 * 40];
  const int t    = threadIdx.x;
  const int lane = t & 63;
  const int wave = t >> 6;
  const int mbase = (wave >> 1) * 64;
  const int nbase = (wave & 1) * 64;
  const int bm = blockIdx.y << 7;
  const int bn = blockIdx.x << 7;
  const int srow = t >> 1;
  const int scol = (t & 1) * 16;
  const int l16 = lane & 15;
  const int lk  = (lane >> 4) * 8;

  f32x4 acc[4][4];
#pragma unroll
  for (int i = 0; i < 4; i++)
#pragma unroll
    for (int j = 0; j < 4; j++) acc[i][j] = (f32x4){0.f, 0.f, 0.f, 0.f};

  for (int k0 = 0; k0 < K; k0 += 32) {
    const f16* ga = A  + (size_t)(bm + srow) * K + k0 + scol;
    const f16* gb = BT + (size_t)(bn + srow) * K + k0 + scol;
    f16x8 va0 = *(const f16x8*)(ga);
    f16x8 va1 = *(const f16x8*)(ga + 8);
    f16x8 vb0 = *(const f16x8*)(gb);
    f16x8 vb1 = *(const f16x8*)(gb + 8);
    __syncthreads();
    *(f16x8*)(As + srow * 40 + scol)     = va0;
    *(f16x8*)(As + srow * 40 + scol + 8) = va1;
    *(f16x8*)(Bs + srow * 40 + scol)     = vb0;
    *(f16x8*)(Bs + srow * 40 + scol + 8) = vb1;
    __syncthreads();

    f16x8 af[4], bf[4];
#pragma unroll
    for (int i = 0; i < 4; i++) {
      af[i] = *(const f16x8*)(As + (mbase + i * 16 + l16) * 40 + lk);
      bf[i] = *(const f16x8*)(Bs + (nbase + i * 16 + l16) * 40 + lk);
    }
#pragma unroll
    for (int i = 0; i < 4; i++)
#pragma unroll
      for (int j = 0; j < 4; j++)
        acc[i][j] = __builtin_amdgcn_mfma_f32_16x16x32_f16(af[i], bf[j], acc[i][j], 0, 0, 0);
  }

  const int rr = (lane >> 4) * 4;
#pragma unroll
  for (int i = 0; i < 4; i++)
#pragma unroll
    for (int j = 0; j < 4; j++)
#pragma unroll
      for (int r = 0; r < 4; r++)
        C[(size_t)(bm + mbase + i * 16 + rr + r) * ldc + bn + nbase + j * 16 + l16]
            = acc[i][j][r];
}

// ---------------------------------------------------------------------------
// f16 MFMA GEMM 64x64 (V projection: N=1024 wants block count).
// ---------------------------------------------------------------------------
__global__ __launch_bounds__(256) void gemm_f16(
    const f16* __restrict__ A, const f16* __restrict__ BT,
    float* __restrict__ C, int M, int N, int K)
{
  __shared__ __align__(16) f16 As[64 * 40];
  __shared__ __align__(16) f16 Bs[64 * 40];
  const int t    = threadIdx.x;
  const int lane = t & 63;
  const int wave = t >> 6;
  const int mbase = (wave >> 1) * 32;
  const int nbase = (wave & 1) * 32;
  const int bm = blockIdx.y << 6;
  const int bn = blockIdx.x << 6;
  const int srow = t >> 2;
  const int scol = (t & 3) * 8;
  const int l16 = lane & 15;
  const int lk  = (lane >> 4) * 8;

  f32x4 acc00 = {0.f,0.f,0.f,0.f}, acc01 = {0.f,0.f,0.f,0.f};
  f32x4 acc10 = {0.f,0.f,0.f,0.f}, acc11 = {0.f,0.f,0.f,0.f};

  for (int k0 = 0; k0 < K; k0 += 32) {
    f16x8 av = *(const f16x8*)(A  + (size_t)(bm + srow) * K + k0 + scol);
    f16x8 bv = *(const f16x8*)(BT + (size_t)(bn + srow) * K + k0 + scol);
    __syncthreads();
    *(f16x8*)(As + srow * 40 + scol) = av;
    *(f16x8*)(Bs + srow * 40 + scol) = bv;
    __syncthreads();
    f16x8 a0 = *(const f16x8*)(As + (mbase + l16)      * 40 + lk);
    f16x8 a1 = *(const f16x8*)(As + (mbase + 16 + l16) * 40 + lk);
    f16x8 b0 = *(const f16x8*)(Bs + (nbase + l16)      * 40 + lk);
    f16x8 b1 = *(const f16x8*)(Bs + (nbase + 16 + l16) * 40 + lk);
    acc00 = __builtin_amdgcn_mfma_f32_16x16x32_f16(a0, b0, acc00, 0, 0, 0);
    acc01 = __builtin_amdgcn_mfma_f32_16x16x32_f16(a0, b1, acc01, 0, 0, 0);
    acc10 = __builtin_amdgcn_mfma_f32_16x16x32_f16(a1, b0, acc10, 0, 0, 0);
    acc11 = __builtin_amdgcn_mfma_f32_16x16x32_f16(a1, b1, acc11, 0, 0, 0);
  }

  const int rr = (lane >> 4) * 4;
#pragma unroll
  for (int r = 0; r < 4; r++) {
    C[(size_t)(bm + mbase +      rr + r) * N + bn + nbase +      l16] = acc00[r];
    C[(size_t)(bm + mbase +      rr + r) * N + bn + nbase + 16 + l16] = acc01[r];
    C[(size_t)(bm + mbase + 16 + rr + r) * N + bn + nbase +      l16] = acc10[r];
    C[(size_t)(bm + mbase + 16 + rr + r) * N + bn + nbase + 16 + l16] = acc11[r];
  }
}

// ---------------------------------------------------------------------------
// f32 [K][N] -> f16 [N][K] transpose-convert.
// ---------------------------------------------------------------------------
__global__ __launch_bounds__(256) void conv_T_f16(
    const float* __restrict__ src, f16* __restrict__ dst, int K, int N)
{
  __shared__ float tile[32][33];
  const int tj = blockIdx.x;
  const int ti = blockIdx.y;
  const int t = threadIdx.x;
  for (int idx = t; idx < 1024; idx += 256) {
    int r = idx >> 5, c = idx & 31;
    tile[r][c] = src[(size_t)(ti * 32 + r) * N + tj * 32 + c];
  }
  __syncthreads();
  for (int idx = t; idx < 1024; idx += 256) {
    int r = idx >> 5, c = idx & 31;
    dst[(size_t)(tj * 32 + r) * K + ti * 32 + c] = (f16)tile[c][r];
  }
}

// ---------------------------------------------------------------------------
// f32 [K][N] cols [n0,n0+32*gridDim.x) -> split f16 hi/lo [NC][K] transpose.
// ---------------------------------------------------------------------------
__global__ __launch_bounds__(256) void conv_T_split(
    const float* __restrict__ src, f16* __restrict__ hi, f16* __restrict__ lo,
    int K, int N, int n0)
{
  __shared__ float tile[32][33];
  const int tj = blockIdx.x;
  const int ti = blockIdx.y;
  const int t = threadIdx.x;
  for (int idx = t; idx < 1024; idx += 256) {
    int r = idx >> 5, c = idx & 31;
    tile[r][c] = src[(size_t)(ti * 32 + r) * N + n0 + tj * 32 + c];
  }
  __syncthreads();
  for (int idx = t; idx < 1024; idx += 256) {
    int r = idx >> 5, c = idx & 31;
    float x = tile[c][r];
    f16 h = (f16)x;
    hi[(size_t)(tj * 32 + r) * K + ti * 32 + c] = h;
    lo[(size_t)(tj * 32 + r) * K + ti * 32 + c] = (f16)(x - (float)h);
  }
}

// ---------------------------------------------------------------------------
// f32 -> (f16 hi, f16 lo) split, row-major.  hi = rne(x); lo = rne(x - hi).
// ---------------------------------------------------------------------------
__global__ __launch_bounds__(256) void split_f16(
    const float* __restrict__ src, f16* __restrict__ hi, f16* __restrict__ lo,
    int n4)
{
  int i = blockIdx.x * 256 + threadIdx.x;
  if (i >= n4) return;
  float4 v = ((const float4*)src)[i];
  float vv[4] = {v.x, v.y, v.z, v.w};
  f16x4 h, l;
#pragma unroll
  for (int j = 0; j < 4; j++) {
    f16 hh = (f16)vv[j];
    h[j] = hh;
    l[j] = (f16)(vv[j] - (float)hh);
  }
  ((f16x4*)hi)[i] = h;
  ((f16x4*)lo)[i] = l;
}

// ---------------------------------------------------------------------------
// Attention pass 1: softmax denominators L[q] via split-f16 32x32x16 MFMA.
// kvh-pinned 1-D grid.  BALANCED q-tile pairing (round 8): with 2 blocks/CU,
// CU c gets tiles (15-c') then (c') -> combined cost 68 tile-units CONSTANT
// (old 15-c',7-c' mapping gave 100-8c', a 2:1 CU imbalance -> 12.5% occ).
// ---------------------------------------------------------------------------
__global__ __launch_bounds__(256) void attn_l(
    const f16* __restrict__ Qh, const f16* __restrict__ Ql,
    const f16* __restrict__ Kh, const f16* __restrict__ Kl,
    float* __restrict__ Lrow)
{
  __shared__ __align__(16) f16 Khs[32 * 136];
  __shared__ __align__(16) f16 Kls[32 * 136];
  const int t    = threadIdx.x;
  const int lane = t & 63;
  const int wave = t >> 6;
  const int l31  = lane & 31;
  const int gp   = lane >> 5;
  const int bid  = (int)blockIdx.x;            // 512 blocks
  const int kvh  = bid & 7;
  const int h    = kvh * 4 + ((bid >> 3) & 3);
  const int hi5  = bid >> 5;                   // 0..15
  const int qt   = hi5 < 8 ? 15 - hi5 : hi5 - 8;   // balanced pairing
  const int q0   = qt << 7;
  const int qw   = q0 + wave * 32;
  const int qg   = qw + l31;

  f16x8 qhf[8], qlf[8];
  {
    const f16* qp  = Qh + (size_t)qg * HIDDEN + h * HEAD_DIM + 8 * gp;
    const f16* qp2 = Ql + (size_t)qg * HIDDEN + h * HEAD_DIM + 8 * gp;
#pragma unroll
    for (int c = 0; c < 8; c++) {
      qhf[c] = *(const f16x8*)(qp  + c * 16);
      qlf[c] = *(const f16x8*)(qp2 + c * 16);
    }
  }

  float Lacc = 0.f;
  const int ntiles = (q0 >> 5) + 4;
  for (int kt = 0; kt < ntiles; kt++) {
    const int k0 = kt << 5;
    __syncthreads();
    for (int i = t; i < 512; i += 256) {
      int r = i >> 4, c = i & 15;
      size_t g = (size_t)(k0 + r) * (N_KV * HEAD_DIM) + kvh * HEAD_DIM + c * 8;
      *(f16x8*)(Khs + r * 136 + c * 8) = *(const f16x8*)(Kh + g);
      *(f16x8*)(Kls + r * 136 + c * 8) = *(const f16x8*)(Kl + g);
    }
    __syncthreads();
    if (k0 > qw + 31) continue;   // after both barriers: barrier counts uniform

    f32x16 acc;
#pragma unroll
    for (int i = 0; i < 16; i++) acc[i] = 0.f;
#pragma unroll
    for (int c = 0; c < 8; c++) {
      f16x8 ah = *(const f16x8*)(Khs + l31 * 136 + c * 16 + 8 * gp);
      f16x8 al = *(const f16x8*)(Kls + l31 * 136 + c * 16 + 8 * gp);
      acc = __builtin_amdgcn_mfma_f32_32x32x16_f16(ah, qhf[c], acc, 0, 0, 0);
      acc = __builtin_amdgcn_mfma_f32_32x32x16_f16(ah, qlf[c], acc, 0, 0, 0);
      acc = __builtin_amdgcn_mfma_f32_32x32x16_f16(al, qhf[c], acc, 0, 0, 0);
    }
    float ws = 0.f;
#pragma unroll
    for (int r = 0; r < 16; r++) {
      int kg = k0 + (r & 3) + 8 * (r >> 2) + 4 * gp;
      float e = exp2f(acc[r] * C2EXP);
      ws += (kg <= qg) ? e : 0.f;
    }
    Lacc += ws;
  }

  float tot = Lacc + __shfl_xor(Lacc, 32);
  if (lane < 32) Lrow[h * S_LEN + qw + lane] = tot;
}

// ---------------------------------------------------------------------------
// Attention pass 2: O = softmax(QK^T) V via MFMA.  Round-8 changes:
// (1) balanced q-tile pairing (see attn_l); (2) Vt fragment loads HOISTED to
// right after the causal skip -- they depend only on k0, so issuing them
// before the QK MFMA + exp + pack chain (~100 instrs) hides their L2 latency
// instead of stalling the PV MFMAs.  Math bit-identical to rounds 5-7.
// ---------------------------------------------------------------------------
__global__ __launch_bounds__(256) void attn_o(
    const f16* __restrict__ Qh, const f16* __restrict__ Kh,
    const f16* __restrict__ Vt, const float* __restrict__ Lrow,
    f16* __restrict__ attnb)
{
  __shared__ __align__(16) f16 Khs[32 * 136];
  const int t    = threadIdx.x;
  const int lane = t & 63;
  const int wave = t >> 6;
  const int l31  = lane & 31;
  const int gp   = lane >> 5;
  const int bid  = (int)blockIdx.x;            // 512 blocks
  const int kvh  = bid & 7;
  const int h    = kvh * 4 + ((bid >> 3) & 3);
  const int hi5  = bid >> 5;                   // 0..15
  const int qt   = hi5 < 8 ? 15 - hi5 : hi5 - 8;   // balanced pairing
  const int q0   = qt << 7;
  const int qw   = q0 + wave * 32;
  const int qg   = qw + l31;

  f16x8 qhf[8];
  {
    const f16* qp = Qh + (size_t)qg * HIDDEN + h * HEAD_DIM + 8 * gp;
#pragma unroll
    for (int c = 0; c < 8; c++) qhf[c] = *(const f16x8*)(qp + c * 16);
  }
  const float iL = 1.0f / Lrow[h * S_LEN + qg];

  f32x16 oacc[4];
#pragma unroll
  for (int m = 0; m < 4; m++)
#pragma unroll
    for (int i = 0; i < 16; i++) oacc[m][i] = 0.f;

  const int ntiles = (q0 >> 5) + 4;
  for (int kt = 0; kt < ntiles; kt++) {
    const int k0 = kt << 5;
    __syncthreads();
    for (int i = t; i < 512; i += 256) {
      int r = i >> 4, c = i & 15;
      size_t g = (size_t)(k0 + r) * (N_KV * HEAD_DIM) + kvh * HEAD_DIM + c * 8;
      *(f16x8*)(Khs + r * 136 + c * 8) = *(const f16x8*)(Kh + g);
    }
    __syncthreads();
    if (k0 > qw + 31) continue;

    // --- Vt prefetch: independent of QK/exp/pack, issue FIRST (hides L2) ---
    f16x8 vr0[4], vr1[4];
#pragma unroll
    for (int mt = 0; mt < 4; mt++) {
      const f16* vp = Vt + (size_t)(kvh * HEAD_DIM + mt * 32 + l31) * S_LEN
                         + k0 + 8 * gp;
      vr0[mt] = *(const f16x8*)(vp);
      vr1[mt] = *(const f16x8*)(vp + 16);
    }

    f32x16 acc;
#pragma unroll
    for (int i = 0; i < 16; i++) acc[i] = 0.f;
#pragma unroll
    for (int c = 0; c < 8; c++) {
      f16x8 ah = *(const f16x8*)(Khs + l31 * 136 + c * 16 + 8 * gp);
      acc = __builtin_amdgcn_mfma_f32_32x32x16_f16(ah, qhf[c], acc, 0, 0, 0);
    }

    float wv[16];
#pragma unroll
    for (int r = 0; r < 16; r++) {
      int kg = k0 + (r & 3) + 8 * (r >> 2) + 4 * gp;
      wv[r] = (kg <= qg) ? exp2f(acc[r] * C2EXP) * iL : 0.f;
    }

    unsigned p[8], x[8];
#pragma unroll
    for (int j = 0; j < 8; j++)
      p[j] = __builtin_bit_cast(unsigned,
               __builtin_amdgcn_cvt_pkrtz(wv[2 * j], wv[2 * j + 1]));
#pragma unroll
    for (int j = 0; j < 8; j++)
      x[j] = (unsigned)__shfl_xor((int)p[j], 32);

    uint4v cc0, cc1;   // B-frag: row(q)=lane&31, k = gp*8 + j
    cc0[0] = gp ? x[2] : p[0]; cc0[1] = gp ? x[3] : p[1];
    cc0[2] = gp ? p[2] : x[0]; cc0[3] = gp ? p[3] : x[1];
    cc1[0] = gp ? x[6] : p[4]; cc1[1] = gp ? x[7] : p[5];
    cc1[2] = gp ? p[6] : x[4]; cc1[3] = gp ? p[7] : x[5];
    f16x8 pf0 = __builtin_bit_cast(f16x8, cc0);   // keys k0+0..15
    f16x8 pf1 = __builtin_bit_cast(f16x8, cc1);   // keys k0+16..31

#pragma unroll
    for (int mt = 0; mt < 4; mt++) {
      oacc[mt] = __builtin_amdgcn_mfma_f32_32x32x16_f16(vr0[mt], pf0, oacc[mt], 0, 0, 0);
      oacc[mt] = __builtin_amdgcn_mfma_f32_32x32x16_f16(vr1[mt], pf1, oacc[mt], 0, 0, 0);
    }
  }

  f16* ob = attnb + (size_t)qg * HIDDEN + h * HEAD_DIM;
#pragma unroll
  for (int mt = 0; mt < 4; mt++)
#pragma unroll
    for (int rq = 0; rq < 4; rq++) {
      int d = mt * 32 + 8 * rq + 4 * gp;
      f16x4 o;
      o[0] = (f16)oacc[mt][rq * 4 + 0];
      o[1] = (f16)oacc[mt][rq * 4 + 1];
      o[2] = (f16)oacc[mt][rq * 4 + 2];
      o[3] = (f16)oacc[mt][rq * 4 + 3];
      *(f16x4*)(ob + d) = o;
    }
}

// ---------------------------------------------------------------------------
// Attention pass 3: cs[h][key] = sum_q w[q,key]  (mask-critical, split-exact).
// v3 (verified rounds 6-7): block = ONE 32-key strip; 4 waves split the
// causal q-range mod 4 -> 1856 blocks.  XCD pin: bid%8 = h%8.
// ---------------------------------------------------------------------------
__global__ __launch_bounds__(256) void attn_cs(
    const f16* __restrict__ Qh, const f16* __restrict__ Ql,
    const f16* __restrict__ Kh, const f16* __restrict__ Kl,
    const float* __restrict__ Lrow, float* __restrict__ cs)
{
  const int t    = threadIdx.x;
  const int lane = t & 63;
  const int wave = t >> 6;
  const int l31  = lane & 31;
  const int gp   = lane >> 5;
  const int bid  = (int)blockIdx.x;        // 58*32 = 1856 blocks
  const int h    = bid & 31;               // bid%8 = h%8 -> XCD pin per head
  const int kvh  = h >> 2;
  const int kb   = (bid >> 5) << 5;        // this block's 32-key strip

  f16x8 kah[8], kal[8];
  {
    const f16* kp  = Kh + (size_t)(kb + l31) * (N_KV * HEAD_DIM) + kvh * HEAD_DIM + 8 * gp;
    const f16* kp2 = Kl + (size_t)(kb + l31) * (N_KV * HEAD_DIM) + kvh * HEAD_DIM + 8 * gp;
#pragma unroll
    for (int c = 0; c < 8; c++) {
      kah[c] = *(const f16x8*)(kp  + c * 16);
      kal[c] = *(const f16x8*)(kp2 + c * 16);
    }
  }

  float csa[16];
#pragma unroll
  for (int r = 0; r < 16; r++) csa[r] = 0.f;

  for (int q0 = kb + wave * 32; q0 < S_LEN; q0 += 128) {
    const int qg = q0 + l31;
    const float iL = 1.0f / Lrow[h * S_LEN + qg];
    const f16* qp  = Qh + (size_t)qg * HIDDEN + h * HEAD_DIM + 8 * gp;
    const f16* qp2 = Ql + (size_t)qg * HIDDEN + h * HEAD_DIM + 8 * gp;

    f32x16 acc;
#pragma unroll
    for (int i = 0; i < 16; i++) acc[i] = 0.f;
#pragma unroll
    for (int c = 0; c < 8; c++) {
      f16x8 bh = *(const f16x8*)(qp  + c * 16);
      f16x8 bl = *(const f16x8*)(qp2 + c * 16);
      acc = __builtin_amdgcn_mfma_f32_32x32x16_f16(kah[c], bh, acc, 0, 0, 0);
      acc = __builtin_amdgcn_mfma_f32_32x32x16_f16(kah[c], bl, acc, 0, 0, 0);
      acc = __builtin_amdgcn_mfma_f32_32x32x16_f16(kal[c], bh, acc, 0, 0, 0);
    }
#pragma unroll
    for (int r = 0; r < 16; r++) {
      int kg = kb + (r & 3) + 8 * (r >> 2) + 4 * gp;
      csa[r] += (kg <= qg) ? exp2f(acc[r] * C2EXP) * iL : 0.f;
    }
  }

#pragma unroll
  for (int st = 1; st < 32; st <<= 1)
#pragma unroll
    for (int r = 0; r < 16; r++) csa[r] += __shfl_xor(csa[r], st);

  if (l31 == 0) {
#pragma unroll
    for (int r = 0; r < 16; r++)
      atomicAdd(&cs[h * S_LEN + kb + (r & 3) + 8 * (r >> 2) + 4 * gp], csa[r]);
  }
}

// ---------------------------------------------------------------------------
// Exact top-HEAVY_K via O(n^2) ranking -- one candidate per thread, 9 x 32
// blocks.  Identical comparison + tie-break (jj < i) -> mask bit-identical.
// (verified rounds 4-7)
// ---------------------------------------------------------------------------
__global__ __launch_bounds__(256) void topk_mask_kernel(
    const float* __restrict__ cs, float* __restrict__ maskout)
{
  const int h = blockIdx.y;
  __shared__ float sv[NCAND];
  const float* s = cs + h * S_LEN;
  const int t = threadIdx.x;
  for (int i = t; i < NCAND; i += 256) sv[i] = s[i];
  __syncthreads();

  const int i = blockIdx.x * 256 + t;
  if (i >= MASK_LEN) return;
  float val = (i >= NCAND + 1) ? 1.0f : 0.0f;
  if (i < NCAND) {
    const float v = sv[i];
    int cnt = 0;
#pragma unroll 4
    for (int jj = 0; jj < NCAND; jj++) {
      float x = sv[jj];
      cnt += ((x > v) || (x == v && jj < i)) ? 1 : 0;
    }
    val = (cnt < HEAVY_K) ? 1.0f : 0.0f;
  }
  maskout[h * MASK_LEN + i] = val;
}

__global__ __launch_bounds__(256) void zero_kernel(float* __restrict__ p, int n)
{
  int i = blockIdx.x * 256 + threadIdx.x;
  if (i < n) p[i] = 0.f;
}

// ---------------------------------------------------------------------------
// In-place RoPE.
// ---------------------------------------------------------------------------
__global__ __launch_bounds__(256) void rope_kernel(
    float* __restrict__ buf, const int* __restrict__ pos_ids, int ncols)
{
  __shared__ float invf_s[64];
  if (threadIdx.x < 64)
    invf_s[threadIdx.x] =
        (float)(1.0 / pow(10000.0, (double)threadIdx.x * (1.0 / 64.0)));
  __syncthreads();

  int i = blockIdx.x * 256 + threadIdx.x;
  int half = ncols >> 1;
  int total = S_LEN * half;
  if (i >= total) return;
  int row = i / half;
  int rem = i - row * half;
  int hh = rem >> 6;
  int d  = rem & 63;
  float p = (float)pos_ids[row];
  float ang = p * invf_s[d];
  float c = cosf(ang);
  float s = sinf(ang);
  float* base = buf + (size_t)row * ncols + hh * HEAD_DIM;
  float x0 = base[d];
  float x1 = base[d + 64];
  base[d]      = x0 * c - x1 * s;
  base[d + 64] = x1 * c + x0 * s;
}

// ---------------------------------------------------------------------------
// Workspace layout (109,576,192 B total -- unchanged from round 2).
// ---------------------------------------------------------------------------
extern "C" void kernel_launch(void* const* d_in, const int* in_sizes, int n_in,
                              void* d_out, int out_size, void* d_ws, size_t ws_size,
                              hipStream_t stream)
{
  (void)in_sizes; (void)n_in; (void)out_size; (void)ws_size;
  const float* hs = (const float*)d_in[0];
  const int*  pos = (const int*)d_in[1];
  const float* Wq = (const float*)d_in[2];
  const float* Wk = (const float*)d_in[3];
  const float* Wv = (const float*)d_in[4];
  const float* Wo = (const float*)d_in[5];
  float* out = (float*)d_out;

  char* w = (char*)d_ws;
  float* Qraw  = (float*)(w);                          // 32 MiB
  f16*   WoT   = (f16*)  (w);                          // overlays Qraw
  f16*   WqTl  = (f16*)  (w + 33554432);               // 16 MiB (32..48)
  float* Kraw  = (float*)(w + 33554432);               // 8 MiB, after Wq gemms
  f16*   Vt    = (f16*)  (w + 33554432);               // 4 MiB, after K split
  float* Vraw  = (float*)(w + 41943040);               // 8 MiB
  float* Lrow  = (float*)(w + 50331648);
  float* cs    = (float*)(w + 50593792);
  f16*   hsh   = (f16*)  (w + 50855936);               // 16 MiB (48.5..64.5)
  f16*   attnb = (f16*)  (w + 50855936);               // overlays hsh
  f16*   hsl   = (f16*)  (w + 67633152);               // 16 MiB (64.5..80.5)
  f16*   Qh    = (f16*)  (w + 67633152);               // overlays hsl
  f16*   WqTh  = (f16*)  (w + 84410368);               // 16 MiB (80.5..96.5)
  f16*   WkTh  = (f16*)  (w + 84410368);               //  8 MiB
  f16*   WvT   = (f16*)  (w + 84410368);               //  8 MiB
  f16*   Ql    = (f16*)  (w + 84410368);               // overlays, after V gemm
  f16*   WkTl  = (f16*)  (w + 92798976);               //  8 MiB (88.5..96.5)
  f16*   Kh    = (f16*)  (w + 101187584);              //  4 MiB
  f16*   Kl    = (f16*)  (w + 105381888);              //  4 MiB -> end 104.5 MiB

  dim3 blk(256);

  // --- split hidden_states once (A-operand for Q, K, V gemms) ---
  split_f16<<<(S_LEN * HIDDEN / 4 + 255) / 256, blk, 0, stream>>>(
      hs, hsh, hsl, S_LEN * HIDDEN / 4);

  // --- Q = hs @ Wq, split-exact, two N=2048 chunks (128x64 tiles: 512 blk) ---
  conv_T_split<<<dim3(2048 / 32, HIDDEN / 32), blk, 0, stream>>>(
      Wq, WqTh, WqTl, HIDDEN, HIDDEN, 0);
  gemm_split<<<dim3(2048 / 64, S_LEN / 128), blk, 0, stream>>>(
      hsh, hsl, WqTh, WqTl, Qraw, HIDDEN, HIDDEN);
  conv_T_split<<<dim3(2048 / 32, HIDDEN / 32), blk, 0, stream>>>(
      Wq, WqTh, WqTl, HIDDEN, HIDDEN, 2048);
  gemm_split<<<dim3(2048 / 64, S_LEN / 128), blk, 0, stream>>>(
      hsh, hsl, WqTh, WqTl, Qraw + 2048, HIDDEN, HIDDEN);

  // --- K = hs @ Wk, split-exact (128x64 tiles: 256 blocks) ---
  conv_T_split<<<dim3((N_KV * HEAD_DIM) / 32, HIDDEN / 32), blk, 0, stream>>>(
      Wk, WkTh, WkTl, HIDDEN, N_KV * HEAD_DIM, 0);
  gemm_split<<<dim3((N_KV * HEAD_DIM) / 64, S_LEN / 128), blk, 0, stream>>>(
      hsh, hsl, WkTh, WkTl, Kraw, HIDDEN, N_KV * HEAD_DIM);

  // --- V = hs @ Wv, f16 (tolerance path) ---
  conv_T_f16<<<dim3((N_KV * HEAD_DIM) / 32, HIDDEN / 32), blk, 0, stream>>>(
      Wv, WvT, HIDDEN, N_KV * HEAD_DIM);
  gemm_f16<<<dim3((N_KV * HEAD_DIM) / 64, S_LEN / 64), blk, 0, stream>>>(
      hsh, WvT, Vraw, S_LEN, N_KV * HEAD_DIM, HIDDEN);

  // --- RoPE (f32, in place) ---
  rope_kernel<<<(S_LEN * (HIDDEN / 2) + 255) / 256, blk, 0, stream>>>(
      Qraw, pos, HIDDEN);
  rope_kernel<<<(S_LEN * (N_KV * HEAD_DIM / 2) + 255) / 256, blk, 0, stream>>>(
      Kraw, pos, N_KV * HEAD_DIM);

  // --- splits for attention ---
  split_f16<<<(S_LEN * HIDDEN / 4 + 255) / 256, blk, 0, stream>>>(
      Qraw, Qh, Ql, S_LEN * HIDDEN / 4);
  split_f16<<<(S_LEN * N_KV * HEAD_DIM / 4 + 255) / 256, blk, 0, stream>>>(
      Kraw, Kh, Kl, S_LEN * N_KV * HEAD_DIM / 4);
  conv_T_f16<<<dim3((N_KV * HEAD_DIM) / 32, S_LEN / 32), blk, 0, stream>>>(
      Vraw, Vt, S_LEN, N_KV * HEAD_DIM);
  conv_T_f16<<<dim3(HIDDEN / 32, HIDDEN / 32), blk, 0, stream>>>(
      Wo, WoT, HIDDEN, HIDDEN);   // Qraw dead (split done) -> safe overlay

  // --- attention (1-D XCD-pinned grids, balanced pairing) ---
  attn_l<<<dim3((S_LEN / 128) * N_HEADS), blk, 0, stream>>>(
      Qh, Ql, Kh, Kl, Lrow);
  attn_o<<<dim3((S_LEN / 128) * N_HEADS), blk, 0, stream>>>(
      Qh, Kh, Vt, Lrow, attnb);
  zero_kernel<<<(N_HEADS * S_LEN + 255) / 256, blk, 0, stream>>>(
      cs, N_HEADS * S_LEN);
  attn_cs<<<dim3(((NCAND + 31) / 32) * N_HEADS), blk, 0, stream>>>(
      Qh, Ql, Kh, Kl, Lrow, cs);
  topk_mask_kernel<<<dim3((MASK_LEN + 255) / 256, N_HEADS), blk, 0, stream>>>(
      cs, out + (size_t)S_LEN * HIDDEN);

  // --- output projection (128x128 tile) ---
  gemm_f16_128<<<dim3(HIDDEN / 128, S_LEN / 128), blk, 0, stream>>>(
      attnb, WoT, out, HIDDEN, HIDDEN);
}